// Round 1
// baseline (2655.049 us; speedup 1.0000x reference)
//
#include <hip/hip_runtime.h>
#include <hip/hip_bf16.h>
#include <math.h>

#define LN_EPS 1e-5f

// ---------------------------------------------------------------------------
// K1: per-patch conv1+pool -> conv2+pool -> expansion(36->64)+ReLU
// grid: 4096 blocks (one per patch), 256 threads
// writes u[patch][32][64]  (patch-major, 4096 x 2048 floats)
// ---------------------------------------------------------------------------
__global__ __launch_bounds__(256) void k_conv(
    const float* __restrict__ t,
    const float* __restrict__ c1w, const float* __restrict__ c1b,
    const float* __restrict__ c2w, const float* __restrict__ c2b,
    const float* __restrict__ ew,  const float* __restrict__ eb,
    float* __restrict__ u)
{
    __shared__ float s_c2w[32 * 32 * 9];   // 36.9 KB
    __shared__ float s_c1w[32 * 9];
    __shared__ float s_c1b[32];
    __shared__ float s_c2b[32];
    __shared__ float s_ew[36 * 64];        // 9.2 KB
    __shared__ float s_eb[64];
    __shared__ float s_x[32 * 32];         // 4 KB
    __shared__ float s_p1[32 * 15 * 15];   // 28.8 KB
    __shared__ float s_s2[32 * 36];        // 4.6 KB

    const int p   = blockIdx.x;
    const int tid = threadIdx.x;

    // stage weights
    for (int i = tid; i < 32 * 32 * 9; i += 256) s_c2w[i] = c2w[i];
    for (int i = tid; i < 32 * 9; i += 256)      s_c1w[i] = c1w[i];
    for (int i = tid; i < 36 * 64; i += 256)     s_ew[i]  = ew[i];
    if (tid < 32) { s_c1b[tid] = c1b[tid]; s_c2b[tid] = c2b[tid]; }
    if (tid < 64) s_eb[tid] = eb[tid];

    // stage 32x32 patch, already scaled by 1/255
    const int b = p >> 4, tile = p & 15, tr = tile >> 2, tc = tile & 3;
    const float* tp = t + (size_t)b * 128 * 128 + (size_t)tr * 32 * 128 + tc * 32;
    for (int i = tid; i < 1024; i += 256) {
        int r = i >> 5, c = i & 31;
        s_x[i] = tp[r * 128 + c] * (1.0f / 255.0f);
    }
    __syncthreads();

    // conv1 (1->32ch, 3x3, 32->30) + maxpool2 (30->15)
    for (int idx = tid; idx < 32 * 15 * 15; idx += 256) {
        int oc  = idx / 225;
        int rem = idx - oc * 225;
        int pi  = rem / 15;
        int pj  = rem - pi * 15;
        const float* w = &s_c1w[oc * 9];
        const float w0 = w[0], w1 = w[1], w2 = w[2], w3 = w[3], w4 = w[4],
                    w5 = w[5], w6 = w[6], w7 = w[7], w8 = w[8];
        const float bias = s_c1b[oc];
        float mx = -3.0e38f;
        #pragma unroll
        for (int a = 0; a < 2; a++) {
            #pragma unroll
            for (int bb = 0; bb < 2; bb++) {
                const int ci = 2 * pi + a, cj = 2 * pj + bb;
                const float* xr = &s_x[ci * 32 + cj];
                float acc = bias
                          + xr[0]  * w0 + xr[1]  * w1 + xr[2]  * w2
                          + xr[32] * w3 + xr[33] * w4 + xr[34] * w5
                          + xr[64] * w6 + xr[65] * w7 + xr[66] * w8;
                mx = fmaxf(mx, acc);
            }
        }
        s_p1[idx] = mx;
    }
    __syncthreads();

    // conv2 (32->32ch, 3x3, 15->13) + maxpool2 (13->6, drops row/col 12)
    for (int idx = tid; idx < 32 * 36; idx += 256) {
        int oc  = idx / 36;
        int rem = idx - oc * 36;
        int pi  = rem / 6;
        int pj  = rem - pi * 6;
        float mx = -3.0e38f;
        #pragma unroll
        for (int a = 0; a < 2; a++) {
            #pragma unroll
            for (int bb = 0; bb < 2; bb++) {
                const int ci = 2 * pi + a, cj = 2 * pj + bb;
                float acc = s_c2b[oc];
                for (int ic = 0; ic < 32; ic++) {
                    const float* xr = &s_p1[ic * 225 + ci * 15 + cj];
                    const float* wr = &s_c2w[(oc * 32 + ic) * 9];
                    acc += xr[0]  * wr[0] + xr[1]  * wr[1] + xr[2]  * wr[2]
                         + xr[15] * wr[3] + xr[16] * wr[4] + xr[17] * wr[5]
                         + xr[30] * wr[6] + xr[31] * wr[7] + xr[32] * wr[8];
                }
                mx = fmaxf(mx, acc);
            }
        }
        s_s2[idx] = mx;
    }
    __syncthreads();

    // expansion: relu( s2(32x36) @ ew(36x64) + eb )
    float* up = u + (size_t)p * 2048;
    for (int idx = tid; idx < 2048; idx += 256) {
        const int s = idx >> 6, e = idx & 63;
        float acc = s_eb[e];
        const float* sr = &s_s2[s * 36];
        #pragma unroll
        for (int f = 0; f < 36; f++) acc += sr[f] * s_ew[f * 64 + e];
        up[idx] = fmaxf(acc, 0.0f);
    }
}

// ---------------------------------------------------------------------------
// K2: per-patch 4-head attention (seq=32, d=64, head=16) + o-proj + residual
//     + LayerNorm(64). Writes u2[b2][m][s*64+e]  (256 x 16 x 2048 floats).
// grid: 4096 blocks, 256 threads
// ---------------------------------------------------------------------------
__global__ __launch_bounds__(256) void k_attn(
    const float* __restrict__ u,
    const float* __restrict__ wq, const float* __restrict__ bq,
    const float* __restrict__ wk, const float* __restrict__ bk,
    const float* __restrict__ wv, const float* __restrict__ bv,
    const float* __restrict__ wo, const float* __restrict__ bo,
    const float* __restrict__ g1, const float* __restrict__ b1,
    float* __restrict__ u2)
{
    __shared__ float s_u[32 * 64];
    __shared__ float s_q[4][32][16];
    __shared__ float s_k[4][32][16];
    __shared__ float s_v[4][32][16];
    __shared__ float s_sc[4][32][32];
    __shared__ float s_o[32 * 64];

    const int g   = blockIdx.x;
    const int m   = g >> 8;
    const int b2  = g & 255;
    const int tid = threadIdx.x;

    const float* up = u + (size_t)g * 2048;
    for (int i = tid; i < 2048; i += 256) s_u[i] = up[i];
    __syncthreads();

    // q,k,v projections: q[h][s][f] = sum_d u[s][d]*wq[m][h][d][f] + bq[m][h][f]
    const float* wqm = wq + (size_t)m * 4096;
    const float* wkm = wk + (size_t)m * 4096;
    const float* wvm = wv + (size_t)m * 4096;
    const float* bqm = bq + m * 64;
    const float* bkm = bk + m * 64;
    const float* bvm = bv + m * 64;
    for (int i = tid; i < 2048; i += 256) {
        const int h = i >> 9;
        const int s = (i >> 4) & 31;
        const int f = i & 15;
        float aq = bqm[h * 16 + f];
        float ak = bkm[h * 16 + f];
        float av = bvm[h * 16 + f];
        const float* ur = &s_u[s * 64];
        for (int d = 0; d < 64; d++) {
            const float x = ur[d];
            const int wi = (h * 64 + d) * 16 + f;
            aq += x * wqm[wi];
            ak += x * wkm[wi];
            av += x * wvm[wi];
        }
        s_q[h][s][f] = aq;
        s_k[h][s][f] = ak;
        s_v[h][s][f] = av;
    }
    __syncthreads();

    // scores + softmax over t (rows = (h,s), 128 of them)
    if (tid < 128) {
        const int h = tid >> 5, s = tid & 31;
        float row[32];
        float mx = -3.0e38f;
        for (int tt = 0; tt < 32; tt++) {
            float acc = 0.0f;
            #pragma unroll
            for (int f = 0; f < 16; f++) acc += s_q[h][s][f] * s_k[h][tt][f];
            acc *= 0.25f;  // 1/sqrt(16)
            row[tt] = acc;
            mx = fmaxf(mx, acc);
        }
        float sum = 0.0f;
        for (int tt = 0; tt < 32; tt++) {
            const float e = expf(row[tt] - mx);
            row[tt] = e;
            sum += e;
        }
        const float inv = 1.0f / sum;
        for (int tt = 0; tt < 32; tt++) s_sc[h][s][tt] = row[tt] * inv;
    }
    __syncthreads();

    // o[s][h*16+f] = sum_t a[h][s][t]*v[h][t][f]
    for (int i = tid; i < 2048; i += 256) {
        const int s = i >> 6, d = i & 63, h = d >> 4, f = d & 15;
        float acc = 0.0f;
        for (int tt = 0; tt < 32; tt++) acc += s_sc[h][s][tt] * s_v[h][tt][f];
        s_o[i] = acc;
    }
    __syncthreads();

    // o-proj + residual + LayerNorm(64); one wave per row s
    const float* wom = wo + (size_t)m * 4096;
    const float* bom = bo + m * 64;
    const int lane = tid & 63;
    const int wv_  = tid >> 6;
    float* outp = u2 + (size_t)b2 * 32768 + (size_t)m * 2048;
    for (int s = wv_; s < 32; s += 4) {
        float acc = bom[lane];
        const float* orow = &s_o[s * 64];
        for (int d = 0; d < 64; d++) acc += orow[d] * wom[d * 64 + lane];
        const float r = s_u[s * 64 + lane] + acc;
        float sum = r;
        #pragma unroll
        for (int off = 32; off; off >>= 1) sum += __shfl_xor(sum, off);
        const float mean = sum * (1.0f / 64.0f);
        const float dd = r - mean;
        float vs = dd * dd;
        #pragma unroll
        for (int off = 32; off; off >>= 1) vs += __shfl_xor(vs, off);
        const float var = vs * (1.0f / 64.0f);
        outp[s * 64 + lane] = dd * rsqrtf(var + LN_EPS) * g1[lane] + b1[lane];
    }
}

// ---------------------------------------------------------------------------
// K3: XL stage reduced to two successive LN(2x) over 2048 (att out discarded)
// grid: 4096 rows (b2*16+m), 256 threads
// ---------------------------------------------------------------------------
__global__ __launch_bounds__(256) void k_xln(
    const float* __restrict__ in,
    const float* __restrict__ gg, const float* __restrict__ bb,
    float* __restrict__ out)
{
    __shared__ float ws4[4];
    const int row = blockIdx.x;
    const int tid = threadIdx.x;
    const int lane = tid & 63, w = tid >> 6;
    const float* x = in + (size_t)row * 2048;

    float v[8];
    #pragma unroll
    for (int i = 0; i < 8; i++) v[i] = 2.0f * x[tid + i * 256];

    #pragma unroll
    for (int L = 0; L < 2; L++) {
        float s = 0.0f;
        #pragma unroll
        for (int i = 0; i < 8; i++) s += v[i];
        #pragma unroll
        for (int off = 32; off; off >>= 1) s += __shfl_xor(s, off);
        if (lane == 0) ws4[w] = s;
        __syncthreads();
        const float mean = (ws4[0] + ws4[1] + ws4[2] + ws4[3]) * (1.0f / 2048.0f);
        __syncthreads();

        float q = 0.0f;
        #pragma unroll
        for (int i = 0; i < 8; i++) { const float d = v[i] - mean; q += d * d; }
        #pragma unroll
        for (int off = 32; off; off >>= 1) q += __shfl_xor(q, off);
        if (lane == 0) ws4[w] = q;
        __syncthreads();
        const float inv = rsqrtf((ws4[0] + ws4[1] + ws4[2] + ws4[3]) * (1.0f / 2048.0f) + LN_EPS);
        __syncthreads();

        #pragma unroll
        for (int i = 0; i < 8; i++) {
            const int col = tid + i * 256;
            const float y = (v[i] - mean) * inv * gg[L * 2048 + col] + bb[L * 2048 + col];
            v[i] = (L == 0) ? 2.0f * y : y;
        }
    }
    float* o = out + (size_t)row * 2048;
    #pragma unroll
    for (int i = 0; i < 8; i++) o[tid + i * 256] = v[i];
}

// ---------------------------------------------------------------------------
// K4: fl1 split-K GEMM: (256 x 32768) @ (32768 x 512) -> partials
// grid: (8 n-tiles, 4 m-tiles, 8 k-splits), 256 threads, BM=BN=64, BK=32
// ---------------------------------------------------------------------------
__global__ __launch_bounds__(256) void k_fl1(
    const float* __restrict__ A,    // (256, 32768)
    const float* __restrict__ W,    // (32768, 512)
    float* __restrict__ part)       // (8, 256, 512)
{
    __shared__ float As[32][64];
    __shared__ float Bs[32][64];
    const int nb = blockIdx.x, mb = blockIdx.y, kb = blockIdx.z;
    const int tid = threadIdx.x;
    const int tx = tid & 15, ty = tid >> 4;

    float acc[4][4];
    #pragma unroll
    for (int i = 0; i < 4; i++)
        #pragma unroll
        for (int j = 0; j < 4; j++) acc[i][j] = 0.0f;

    const int k0base = kb * 4096;
    for (int k0 = k0base; k0 < k0base + 4096; k0 += 32) {
        for (int i = tid; i < 64 * 32; i += 256) {
            const int r = i >> 5, c = i & 31;
            As[c][r] = A[(size_t)(mb * 64 + r) * 32768 + k0 + c];
        }
        for (int i = tid; i < 32 * 64; i += 256) {
            const int r = i >> 6, c = i & 63;
            Bs[r][c] = W[(size_t)(k0 + r) * 512 + nb * 64 + c];
        }
        __syncthreads();
        #pragma unroll
        for (int k = 0; k < 32; k++) {
            float a0 = As[k][ty * 4 + 0], a1 = As[k][ty * 4 + 1],
                  a2 = As[k][ty * 4 + 2], a3 = As[k][ty * 4 + 3];
            float b0 = Bs[k][tx * 4 + 0], b1 = Bs[k][tx * 4 + 1],
                  b2 = Bs[k][tx * 4 + 2], b3 = Bs[k][tx * 4 + 3];
            acc[0][0] += a0 * b0; acc[0][1] += a0 * b1; acc[0][2] += a0 * b2; acc[0][3] += a0 * b3;
            acc[1][0] += a1 * b0; acc[1][1] += a1 * b1; acc[1][2] += a1 * b2; acc[1][3] += a1 * b3;
            acc[2][0] += a2 * b0; acc[2][1] += a2 * b1; acc[2][2] += a2 * b2; acc[2][3] += a2 * b3;
            acc[3][0] += a3 * b0; acc[3][1] += a3 * b1; acc[3][2] += a3 * b2; acc[3][3] += a3 * b3;
        }
        __syncthreads();
    }
    #pragma unroll
    for (int i = 0; i < 4; i++)
        #pragma unroll
        for (int j = 0; j < 4; j++)
            part[((size_t)kb * 256 + mb * 64 + ty * 4 + i) * 512 + nb * 64 + tx * 4 + j] = acc[i][j];
}

// K4b: reduce partials + bias + relu -> out1 (256 x 512)
__global__ __launch_bounds__(256) void k_fl1red(
    const float* __restrict__ part, const float* __restrict__ bias,
    float* __restrict__ out1)
{
    const int i = blockIdx.x * 256 + threadIdx.x;  // < 131072
    const int n = i & 511;
    float s = bias[n];
    #pragma unroll
    for (int ks = 0; ks < 8; ks++) s += part[(size_t)ks * 131072 + i];
    out1[i] = fmaxf(s, 0.0f);
}

// K5: fl2: (256 x 512) @ (512 x 128) + bias, relu. one block per row.
__global__ __launch_bounds__(128) void k_fl2(
    const float* __restrict__ u1, const float* __restrict__ w,
    const float* __restrict__ b, float* __restrict__ out2)
{
    __shared__ float s_u[512];
    const int r = blockIdx.x, tid = threadIdx.x;
    for (int i = tid; i < 512; i += 128) s_u[i] = u1[r * 512 + i];
    __syncthreads();
    float acc = b[tid];
    for (int k = 0; k < 512; k++) acc += s_u[k] * w[k * 128 + tid];
    out2[r * 128 + tid] = fmaxf(acc, 0.0f);
}

// K6: fl3: (256 x 128) @ (128 x 25) + bias. one block per row.
__global__ __launch_bounds__(128) void k_fl3(
    const float* __restrict__ u2_, const float* __restrict__ w,
    const float* __restrict__ b, float* __restrict__ out)
{
    __shared__ float s_u[128];
    const int r = blockIdx.x, tid = threadIdx.x;
    s_u[tid] = u2_[r * 128 + tid];
    __syncthreads();
    if (tid < 25) {
        float acc = b[tid];
        for (int k = 0; k < 128; k++) acc += s_u[k] * w[k * 25 + tid];
        out[r * 25 + tid] = acc;
    }
}

// ---------------------------------------------------------------------------
extern "C" void kernel_launch(void* const* d_in, const int* in_sizes, int n_in,
                              void* d_out, int out_size, void* d_ws, size_t ws_size,
                              hipStream_t stream)
{
    const float* t      = (const float*)d_in[0];
    const float* c1w    = (const float*)d_in[1];
    const float* c1b    = (const float*)d_in[2];
    const float* c2w    = (const float*)d_in[3];
    const float* c2b    = (const float*)d_in[4];
    const float* ew     = (const float*)d_in[5];
    const float* eb     = (const float*)d_in[6];
    const float* mh_wq  = (const float*)d_in[7];
    const float* mh_bq  = (const float*)d_in[8];
    const float* mh_wk  = (const float*)d_in[9];
    const float* mh_bk  = (const float*)d_in[10];
    const float* mh_wv  = (const float*)d_in[11];
    const float* mh_bv  = (const float*)d_in[12];
    const float* mh_wo  = (const float*)d_in[13];
    const float* mh_bo  = (const float*)d_in[14];
    const float* ln1_g  = (const float*)d_in[15];
    const float* ln1_b  = (const float*)d_in[16];
    // d_in[17..24]: XL attention weights -- dead code in the reference, unused
    const float* xln_g  = (const float*)d_in[25];
    const float* xln_b  = (const float*)d_in[26];
    const float* fl1_w  = (const float*)d_in[27];
    const float* fl1_b  = (const float*)d_in[28];
    const float* fl2_w  = (const float*)d_in[29];
    const float* fl2_b  = (const float*)d_in[30];
    const float* fl3_w  = (const float*)d_in[31];
    const float* fl3_b  = (const float*)d_in[32];
    (void)in_sizes; (void)n_in; (void)out_size; (void)ws_size;

    float* U    = (float*)d_ws;          // 8388608 floats (4096 x 2048)
    float* U2   = U + 8388608;           // 8388608 floats (256 x 32768)
    float* LN   = U;                     // reuse: U dead after k_attn
    float* PART = U2;                    // reuse: U2 dead after k_xln
    float* OUT1 = U2 + 1048576;          // 131072 floats
    float* OUT2 = OUT1 + 131072;         // 32768 floats
    float* out  = (float*)d_out;         // 256 x 25

    k_conv<<<4096, 256, 0, stream>>>(t, c1w, c1b, c2w, c2b, ew, eb, U);
    k_attn<<<4096, 256, 0, stream>>>(U, mh_wq, mh_bq, mh_wk, mh_bk, mh_wv, mh_bv,
                                     mh_wo, mh_bo, ln1_g, ln1_b, U2);
    k_xln<<<4096, 256, 0, stream>>>(U2, xln_g, xln_b, LN);
    k_fl1<<<dim3(8, 4, 8), 256, 0, stream>>>(LN, fl1_w, PART);
    k_fl1red<<<512, 256, 0, stream>>>(PART, fl1_b, OUT1);
    k_fl2<<<256, 128, 0, stream>>>(OUT1, fl2_w, fl2_b, OUT2);
    k_fl3<<<256, 128, 0, stream>>>(OUT2, fl3_w, fl3_b, out);
}

// Round 2
// 1128.121 us; speedup vs baseline: 2.3535x; 2.3535x over previous
//
#include <hip/hip_runtime.h>
#include <hip/hip_bf16.h>
#include <math.h>

#define LN_EPS 1e-5f

// ---------------------------------------------------------------------------
// K1: per-patch conv1+pool -> conv2+pool -> expansion(36->64)+ReLU
// grid: 4096 blocks (one per patch), 256 threads
// Register-blocked; swizzled p1 LDS layout; 56.8 KB LDS -> 2 blocks/CU.
// writes u[patch][32][64]  (patch-major, 4096 x 2048 floats)
// ---------------------------------------------------------------------------
__global__ __launch_bounds__(256, 2) void k_conv(
    const float* __restrict__ t,
    const float* __restrict__ c1w, const float* __restrict__ c1b,
    const float* __restrict__ c2w, const float* __restrict__ c2b,
    const float* __restrict__ ew,  const float* __restrict__ eb,
    float* __restrict__ u)
{
    // overlay region: s_x (phase A) | s_cw half (phase B) | s_ew (phase C)
    __shared__ __align__(16) float s_R[16 * 32 * 12];       // 24576 B
    __shared__ __align__(16) float s_p1[225 * 32];          // 28800 B, swizzled
    __shared__ __align__(16) float s_s2[32 * 36];           // 4608 B
    __shared__ float s_c2b[32];

    float* s_x  = s_R;   // [32][33]
    float* s_cw = s_R;   // [16][32][12]
    float* s_ew = s_R;   // [36][64]

    const int p   = blockIdx.x;
    const int tid = threadIdx.x;

    // ---- stage input patch (scaled) + c2b ----
    const int b = p >> 4, tile = p & 15, tr = tile >> 2, tc = tile & 3;
    const float* tp = t + (size_t)b * 128 * 128 + (size_t)tr * 32 * 128 + tc * 32;
    for (int i = tid; i < 1024; i += 256) {
        const int r = i >> 5, c = i & 31;
        s_x[r * 33 + c] = tp[r * 128 + c] * (1.0f / 255.0f);
    }
    if (tid < 32) s_c2b[tid] = c2b[tid];
    __syncthreads();

    // ---- phase A: conv1 (1->32, 3x3) + pool -> p1[pos][ic] swizzled ----
    if (tid < 225) {
        const int pi = tid / 15, pj = tid % 15;
        float xw[16];
        #pragma unroll
        for (int r = 0; r < 4; ++r)
            #pragma unroll
            for (int c = 0; c < 4; ++c)
                xw[r * 4 + c] = s_x[(2 * pi + r) * 33 + (2 * pj + c)];
        const int swz = (tid & 7) << 2;
        for (int oc0 = 0; oc0 < 32; oc0 += 4) {
            float4 pq;
            float* pqf = (float*)&pq;
            #pragma unroll
            for (int o = 0; o < 4; ++o) {
                const int oc = oc0 + o;          // uniform -> scalar loads
                float w[9];
                #pragma unroll
                for (int j = 0; j < 9; ++j) w[j] = c1w[oc * 9 + j];
                float mx = -3.0e38f;
                #pragma unroll
                for (int a = 0; a < 2; ++a)
                    #pragma unroll
                    for (int bb = 0; bb < 2; ++bb) {
                        float s = xw[(a + 0) * 4 + bb + 0] * w[0]
                                + xw[(a + 0) * 4 + bb + 1] * w[1]
                                + xw[(a + 0) * 4 + bb + 2] * w[2]
                                + xw[(a + 1) * 4 + bb + 0] * w[3]
                                + xw[(a + 1) * 4 + bb + 1] * w[4]
                                + xw[(a + 1) * 4 + bb + 2] * w[5]
                                + xw[(a + 2) * 4 + bb + 0] * w[6]
                                + xw[(a + 2) * 4 + bb + 1] * w[7]
                                + xw[(a + 2) * 4 + bb + 2] * w[8];
                        mx = fmaxf(mx, s);
                    }
                pqf[o] = mx + c1b[oc];
            }
            *(float4*)&s_p1[tid * 32 + (oc0 ^ swz)] = pq;
        }
    }
    __syncthreads();

    // ---- phase B: conv2 (32->32, 3x3) + pool, two 16-oc passes ----
    const int pos = (tid < 144) ? (tid % 36) : 0;
    const int ocg = (tid < 144) ? (tid / 36) : 0;   // 4 groups of 4 oc
    const int ppi = pos / 6, ppj = pos % 6;
    int wbase[16];
    #pragma unroll
    for (int r = 0; r < 4; ++r)
        #pragma unroll
        for (int c = 0; c < 4; ++c) {
            const int wpos = (2 * ppi + r) * 15 + (2 * ppj + c);
            wbase[r * 4 + c] = wpos * 32 + ((wpos & 7) << 2);
        }

    for (int pass = 0; pass < 2; ++pass) {
        // stage 16-oc half of c2w as [16][32][12] (pad 9->12 for b128)
        for (int i = tid; i < 16 * 32 * 12; i += 256) {
            const int ol  = i / 384;
            const int rem = i - ol * 384;
            const int ic  = rem / 12;
            const int j   = rem - ic * 12;
            s_cw[i] = (j < 9) ? c2w[((pass * 16 + ol) * 32 + ic) * 9 + j] : 0.0f;
        }
        __syncthreads();

        if (tid < 144) {
            float acc[16];
            #pragma unroll
            for (int i = 0; i < 16; ++i) acc[i] = 0.0f;

            for (int ic0 = 0; ic0 < 32; ic0 += 4) {
                float xv[64];
                #pragma unroll
                for (int w = 0; w < 16; ++w)
                    *(float4*)&xv[w * 4] = *(const float4*)&s_p1[wbase[w] ^ ic0];
                #pragma unroll
                for (int o = 0; o < 4; ++o) {
                    const float* wp = &s_cw[((ocg * 4 + o) * 32 + ic0) * 12];
                    #pragma unroll
                    for (int ic = 0; ic < 4; ++ic) {
                        const float4 wA = *(const float4*)&wp[ic * 12];
                        const float4 wB = *(const float4*)&wp[ic * 12 + 4];
                        const float  w8 = wp[ic * 12 + 8];
                        #pragma unroll
                        for (int a = 0; a < 2; ++a)
                            #pragma unroll
                            for (int bb = 0; bb < 2; ++bb) {
                                const float s =
                                    xv[((a + 0) * 4 + bb + 0) * 4 + ic] * wA.x +
                                    xv[((a + 0) * 4 + bb + 1) * 4 + ic] * wA.y +
                                    xv[((a + 0) * 4 + bb + 2) * 4 + ic] * wA.z +
                                    xv[((a + 1) * 4 + bb + 0) * 4 + ic] * wA.w +
                                    xv[((a + 1) * 4 + bb + 1) * 4 + ic] * wB.x +
                                    xv[((a + 1) * 4 + bb + 2) * 4 + ic] * wB.y +
                                    xv[((a + 2) * 4 + bb + 0) * 4 + ic] * wB.z +
                                    xv[((a + 2) * 4 + bb + 1) * 4 + ic] * wB.w +
                                    xv[((a + 2) * 4 + bb + 2) * 4 + ic] * w8;
                                acc[o * 4 + a * 2 + bb] += s;
                            }
                    }
                }
            }
            #pragma unroll
            for (int o = 0; o < 4; ++o) {
                const int oc = pass * 16 + ocg * 4 + o;
                const float mx = fmaxf(fmaxf(acc[o * 4 + 0], acc[o * 4 + 1]),
                                       fmaxf(acc[o * 4 + 2], acc[o * 4 + 3]));
                s_s2[oc * 36 + pos] = mx + s_c2b[oc];
            }
        }
        __syncthreads();
    }

    // ---- phase C: expansion relu(s2(32x36) @ ew(36x64) + eb) ----
    for (int i = tid; i < 36 * 64; i += 256) s_ew[i] = ew[i];
    __syncthreads();

    {
        const int s  = tid >> 3;
        const int e0 = (tid & 7) * 8;
        float acc8[8];
        *(float4*)&acc8[0] = *(const float4*)&eb[e0];
        *(float4*)&acc8[4] = *(const float4*)&eb[e0 + 4];
        for (int f = 0; f < 36; ++f) {
            const float sv = s_s2[s * 36 + f];
            const float4 w0 = *(const float4*)&s_ew[f * 64 + e0];
            const float4 w1 = *(const float4*)&s_ew[f * 64 + e0 + 4];
            acc8[0] += sv * w0.x; acc8[1] += sv * w0.y;
            acc8[2] += sv * w0.z; acc8[3] += sv * w0.w;
            acc8[4] += sv * w1.x; acc8[5] += sv * w1.y;
            acc8[6] += sv * w1.z; acc8[7] += sv * w1.w;
        }
        float4 o0, o1;
        o0.x = fmaxf(acc8[0], 0.0f); o0.y = fmaxf(acc8[1], 0.0f);
        o0.z = fmaxf(acc8[2], 0.0f); o0.w = fmaxf(acc8[3], 0.0f);
        o1.x = fmaxf(acc8[4], 0.0f); o1.y = fmaxf(acc8[5], 0.0f);
        o1.z = fmaxf(acc8[6], 0.0f); o1.w = fmaxf(acc8[7], 0.0f);
        float* up = u + (size_t)p * 2048 + s * 64 + e0;
        *(float4*)up       = o0;
        *(float4*)(up + 4) = o1;
    }
}

// ---------------------------------------------------------------------------
// K2: per-patch 4-head attention (seq=32, d=64, head=16) + o-proj + residual
//     + LayerNorm(64). Padded LDS strides; register-blocked projections.
// grid: 4096 blocks, 256 threads
// ---------------------------------------------------------------------------
#define FMA4(A, W) { A.x += xx * W.x; A.y += xx * W.y; A.z += xx * W.z; A.w += xx * W.w; }

__global__ __launch_bounds__(256, 2) void k_attn(
    const float* __restrict__ u,
    const float* __restrict__ wq, const float* __restrict__ bq,
    const float* __restrict__ wk, const float* __restrict__ bk,
    const float* __restrict__ wv, const float* __restrict__ bv,
    const float* __restrict__ wo, const float* __restrict__ bo,
    const float* __restrict__ g1, const float* __restrict__ b1,
    float* __restrict__ u2)
{
    __shared__ __align__(16) float s_u[32 * 65];        // 8320 B
    __shared__ __align__(16) float s_q[4 * 32 * 20];    // 10240 B
    __shared__ __align__(16) float s_k[4 * 32 * 20];
    __shared__ __align__(16) float s_v[4 * 32 * 20];
    __shared__ __align__(16) float s_sc[4 * 32 * 33];   // 16896 B
    __shared__ __align__(16) float s_o[32 * 65];

    const int g   = blockIdx.x;
    const int m   = g >> 8;
    const int b2  = g & 255;
    const int tid = threadIdx.x;

    const float* up = u + (size_t)g * 2048;
    for (int i = tid; i < 2048; i += 256) {
        const int s = i >> 6, d = i & 63;
        s_u[s * 65 + d] = up[i];
    }
    __syncthreads();

    // ---- projections: thread = (h, s, f-half of 8) ----
    {
        const int f0 = (tid & 1) * 8;
        const int s  = (tid >> 1) & 31;
        const int h  = tid >> 6;
        const float* wqm = wq + (size_t)m * 4096 + h * 1024 + f0;
        const float* wkm = wk + (size_t)m * 4096 + h * 1024 + f0;
        const float* wvm = wv + (size_t)m * 4096 + h * 1024 + f0;
        float4 aq0 = *(const float4*)&bq[m * 64 + h * 16 + f0];
        float4 aq1 = *(const float4*)&bq[m * 64 + h * 16 + f0 + 4];
        float4 ak0 = *(const float4*)&bk[m * 64 + h * 16 + f0];
        float4 ak1 = *(const float4*)&bk[m * 64 + h * 16 + f0 + 4];
        float4 av0 = *(const float4*)&bv[m * 64 + h * 16 + f0];
        float4 av1 = *(const float4*)&bv[m * 64 + h * 16 + f0 + 4];
        for (int d = 0; d < 64; ++d) {
            const float xx = s_u[s * 65 + d];
            const float4 wq0 = *(const float4*)&wqm[d * 16];
            const float4 wq1 = *(const float4*)&wqm[d * 16 + 4];
            const float4 wk0 = *(const float4*)&wkm[d * 16];
            const float4 wk1 = *(const float4*)&wkm[d * 16 + 4];
            const float4 wv0 = *(const float4*)&wvm[d * 16];
            const float4 wv1 = *(const float4*)&wvm[d * 16 + 4];
            FMA4(aq0, wq0); FMA4(aq1, wq1);
            FMA4(ak0, wk0); FMA4(ak1, wk1);
            FMA4(av0, wv0); FMA4(av1, wv1);
        }
        const int base = (h * 32 + s) * 20 + f0;
        *(float4*)&s_q[base] = aq0; *(float4*)&s_q[base + 4] = aq1;
        *(float4*)&s_k[base] = ak0; *(float4*)&s_k[base + 4] = ak1;
        *(float4*)&s_v[base] = av0; *(float4*)&s_v[base + 4] = av1;
    }
    __syncthreads();

    // ---- scores + softmax: thread = (h, s), 128 active ----
    if (tid < 128) {
        const int h = tid >> 5, s = tid & 31;
        const int qb = (h * 32 + s) * 20;
        const float4 q0 = *(const float4*)&s_q[qb];
        const float4 q1 = *(const float4*)&s_q[qb + 4];
        const float4 q2 = *(const float4*)&s_q[qb + 8];
        const float4 q3 = *(const float4*)&s_q[qb + 12];
        float row[32];
        float mx = -3.0e38f;
        for (int tt = 0; tt < 32; ++tt) {
            const int kb = (h * 32 + tt) * 20;
            const float4 k0 = *(const float4*)&s_k[kb];
            const float4 k1 = *(const float4*)&s_k[kb + 4];
            const float4 k2 = *(const float4*)&s_k[kb + 8];
            const float4 k3 = *(const float4*)&s_k[kb + 12];
            float acc = q0.x * k0.x + q0.y * k0.y + q0.z * k0.z + q0.w * k0.w
                      + q1.x * k1.x + q1.y * k1.y + q1.z * k1.z + q1.w * k1.w
                      + q2.x * k2.x + q2.y * k2.y + q2.z * k2.z + q2.w * k2.w
                      + q3.x * k3.x + q3.y * k3.y + q3.z * k3.z + q3.w * k3.w;
            acc *= 0.25f;
            row[tt] = acc;
            mx = fmaxf(mx, acc);
        }
        float sum = 0.0f;
        for (int tt = 0; tt < 32; ++tt) {
            const float e = expf(row[tt] - mx);
            row[tt] = e;
            sum += e;
        }
        const float inv = 1.0f / sum;
        const int sb = (h * 32 + s) * 33;
        for (int tt = 0; tt < 32; ++tt) s_sc[sb + tt] = row[tt] * inv;
    }
    __syncthreads();

    // ---- o = a @ v: thread = (s, d-octet) ----
    {
        const int s  = tid >> 3;
        const int d0 = (tid & 7) * 8;
        const int h  = d0 >> 4;
        const int f0 = d0 & 15;
        float4 a0 = {0, 0, 0, 0}, a1 = {0, 0, 0, 0};
        const int sb = (h * 32 + s) * 33;
        for (int tt = 0; tt < 32; ++tt) {
            const float xx = s_sc[sb + tt];
            const int vb = (h * 32 + tt) * 20 + f0;
            const float4 v0 = *(const float4*)&s_v[vb];
            const float4 v1 = *(const float4*)&s_v[vb + 4];
            FMA4(a0, v0); FMA4(a1, v1);
        }
        *(float4*)&s_o[s * 65 + d0]     = a0;
        *(float4*)&s_o[s * 65 + d0 + 4] = a1;
    }
    __syncthreads();

    // ---- o-proj + residual + LayerNorm(64); one wave per row ----
    {
        const float* wom = wo + (size_t)m * 4096;
        const float* bom = bo + m * 64;
        const int lane = tid & 63;
        const int wv_  = tid >> 6;
        float* outp = u2 + (size_t)b2 * 32768 + (size_t)m * 2048;
        for (int s = wv_; s < 32; s += 4) {
            float acc = bom[lane];
            for (int d = 0; d < 64; ++d)
                acc += s_o[s * 65 + d] * wom[d * 64 + lane];
            const float r = s_u[s * 65 + lane] + acc;
            float sum = r;
            #pragma unroll
            for (int off = 32; off; off >>= 1) sum += __shfl_xor(sum, off);
            const float mean = sum * (1.0f / 64.0f);
            const float dd = r - mean;
            float vs = dd * dd;
            #pragma unroll
            for (int off = 32; off; off >>= 1) vs += __shfl_xor(vs, off);
            const float var = vs * (1.0f / 64.0f);
            outp[s * 64 + lane] = dd * rsqrtf(var + LN_EPS) * g1[lane] + b1[lane];
        }
    }
}

// ---------------------------------------------------------------------------
// K3: XL stage reduced to two successive LN(2x) over 2048 (att out discarded)
// ---------------------------------------------------------------------------
__global__ __launch_bounds__(256) void k_xln(
    const float* __restrict__ in,
    const float* __restrict__ gg, const float* __restrict__ bb,
    float* __restrict__ out)
{
    __shared__ float ws4[4];
    const int row = blockIdx.x;
    const int tid = threadIdx.x;
    const int lane = tid & 63, w = tid >> 6;
    const float* x = in + (size_t)row * 2048;

    float v[8];
    #pragma unroll
    for (int i = 0; i < 8; i++) v[i] = 2.0f * x[tid + i * 256];

    #pragma unroll
    for (int L = 0; L < 2; L++) {
        float s = 0.0f;
        #pragma unroll
        for (int i = 0; i < 8; i++) s += v[i];
        #pragma unroll
        for (int off = 32; off; off >>= 1) s += __shfl_xor(s, off);
        if (lane == 0) ws4[w] = s;
        __syncthreads();
        const float mean = (ws4[0] + ws4[1] + ws4[2] + ws4[3]) * (1.0f / 2048.0f);
        __syncthreads();

        float q = 0.0f;
        #pragma unroll
        for (int i = 0; i < 8; i++) { const float d = v[i] - mean; q += d * d; }
        #pragma unroll
        for (int off = 32; off; off >>= 1) q += __shfl_xor(q, off);
        if (lane == 0) ws4[w] = q;
        __syncthreads();
        const float inv = rsqrtf((ws4[0] + ws4[1] + ws4[2] + ws4[3]) * (1.0f / 2048.0f) + LN_EPS);
        __syncthreads();

        #pragma unroll
        for (int i = 0; i < 8; i++) {
            const int col = tid + i * 256;
            const float y = (v[i] - mean) * inv * gg[L * 2048 + col] + bb[L * 2048 + col];
            v[i] = (L == 0) ? 2.0f * y : y;
        }
    }
    float* o = out + (size_t)row * 2048;
    #pragma unroll
    for (int i = 0; i < 8; i++) o[tid + i * 256] = v[i];
}

// ---------------------------------------------------------------------------
// K4: fl1 split-K GEMM: (256 x 32768) @ (32768 x 512) -> partials
// ---------------------------------------------------------------------------
__global__ __launch_bounds__(256) void k_fl1(
    const float* __restrict__ A,
    const float* __restrict__ W,
    float* __restrict__ part)
{
    __shared__ float As[32][64];
    __shared__ float Bs[32][64];
    const int nb = blockIdx.x, mb = blockIdx.y, kb = blockIdx.z;
    const int tid = threadIdx.x;
    const int tx = tid & 15, ty = tid >> 4;

    float acc[4][4];
    #pragma unroll
    for (int i = 0; i < 4; i++)
        #pragma unroll
        for (int j = 0; j < 4; j++) acc[i][j] = 0.0f;

    const int k0base = kb * 4096;
    for (int k0 = k0base; k0 < k0base + 4096; k0 += 32) {
        for (int i = tid; i < 64 * 32; i += 256) {
            const int r = i >> 5, c = i & 31;
            As[c][r] = A[(size_t)(mb * 64 + r) * 32768 + k0 + c];
        }
        for (int i = tid; i < 32 * 64; i += 256) {
            const int r = i >> 6, c = i & 63;
            Bs[r][c] = W[(size_t)(k0 + r) * 512 + nb * 64 + c];
        }
        __syncthreads();
        #pragma unroll
        for (int k = 0; k < 32; k++) {
            float a0 = As[k][ty * 4 + 0], a1 = As[k][ty * 4 + 1],
                  a2 = As[k][ty * 4 + 2], a3 = As[k][ty * 4 + 3];
            float b0 = Bs[k][tx * 4 + 0], b1 = Bs[k][tx * 4 + 1],
                  b2 = Bs[k][tx * 4 + 2], b3 = Bs[k][tx * 4 + 3];
            acc[0][0] += a0 * b0; acc[0][1] += a0 * b1; acc[0][2] += a0 * b2; acc[0][3] += a0 * b3;
            acc[1][0] += a1 * b0; acc[1][1] += a1 * b1; acc[1][2] += a1 * b2; acc[1][3] += a1 * b3;
            acc[2][0] += a2 * b0; acc[2][1] += a2 * b1; acc[2][2] += a2 * b2; acc[2][3] += a2 * b3;
            acc[3][0] += a3 * b0; acc[3][1] += a3 * b1; acc[3][2] += a3 * b2; acc[3][3] += a3 * b3;
        }
        __syncthreads();
    }
    #pragma unroll
    for (int i = 0; i < 4; i++)
        #pragma unroll
        for (int j = 0; j < 4; j++)
            part[((size_t)kb * 256 + mb * 64 + ty * 4 + i) * 512 + nb * 64 + tx * 4 + j] = acc[i][j];
}

__global__ __launch_bounds__(256) void k_fl1red(
    const float* __restrict__ part, const float* __restrict__ bias,
    float* __restrict__ out1)
{
    const int i = blockIdx.x * 256 + threadIdx.x;
    const int n = i & 511;
    float s = bias[n];
    #pragma unroll
    for (int ks = 0; ks < 8; ks++) s += part[(size_t)ks * 131072 + i];
    out1[i] = fmaxf(s, 0.0f);
}

__global__ __launch_bounds__(128) void k_fl2(
    const float* __restrict__ u1, const float* __restrict__ w,
    const float* __restrict__ b, float* __restrict__ out2)
{
    __shared__ float s_u[512];
    const int r = blockIdx.x, tid = threadIdx.x;
    for (int i = tid; i < 512; i += 128) s_u[i] = u1[r * 512 + i];
    __syncthreads();
    float acc = b[tid];
    for (int k = 0; k < 512; k++) acc += s_u[k] * w[k * 128 + tid];
    out2[r * 128 + tid] = fmaxf(acc, 0.0f);
}

__global__ __launch_bounds__(128) void k_fl3(
    const float* __restrict__ u2_, const float* __restrict__ w,
    const float* __restrict__ b, float* __restrict__ out)
{
    __shared__ float s_u[128];
    const int r = blockIdx.x, tid = threadIdx.x;
    s_u[tid] = u2_[r * 128 + tid];
    __syncthreads();
    if (tid < 25) {
        float acc = b[tid];
        for (int k = 0; k < 128; k++) acc += s_u[k] * w[k * 25 + tid];
        out[r * 25 + tid] = acc;
    }
}

// ---------------------------------------------------------------------------
extern "C" void kernel_launch(void* const* d_in, const int* in_sizes, int n_in,
                              void* d_out, int out_size, void* d_ws, size_t ws_size,
                              hipStream_t stream)
{
    const float* t      = (const float*)d_in[0];
    const float* c1w    = (const float*)d_in[1];
    const float* c1b    = (const float*)d_in[2];
    const float* c2w    = (const float*)d_in[3];
    const float* c2b    = (const float*)d_in[4];
    const float* ew     = (const float*)d_in[5];
    const float* eb     = (const float*)d_in[6];
    const float* mh_wq  = (const float*)d_in[7];
    const float* mh_bq  = (const float*)d_in[8];
    const float* mh_wk  = (const float*)d_in[9];
    const float* mh_bk  = (const float*)d_in[10];
    const float* mh_wv  = (const float*)d_in[11];
    const float* mh_bv  = (const float*)d_in[12];
    const float* mh_wo  = (const float*)d_in[13];
    const float* mh_bo  = (const float*)d_in[14];
    const float* ln1_g  = (const float*)d_in[15];
    const float* ln1_b  = (const float*)d_in[16];
    // d_in[17..24]: XL attention weights -- dead code in the reference, unused
    const float* xln_g  = (const float*)d_in[25];
    const float* xln_b  = (const float*)d_in[26];
    const float* fl1_w  = (const float*)d_in[27];
    const float* fl1_b  = (const float*)d_in[28];
    const float* fl2_w  = (const float*)d_in[29];
    const float* fl2_b  = (const float*)d_in[30];
    const float* fl3_w  = (const float*)d_in[31];
    const float* fl3_b  = (const float*)d_in[32];
    (void)in_sizes; (void)n_in; (void)out_size; (void)ws_size;

    float* U    = (float*)d_ws;          // 4096 x 2048
    float* U2   = U + 8388608;           // 256 x 32768
    float* LN   = U;                     // reuse
    float* PART = U2;                    // reuse
    float* OUT1 = U2 + 1048576;
    float* OUT2 = OUT1 + 131072;
    float* out  = (float*)d_out;

    k_conv<<<4096, 256, 0, stream>>>(t, c1w, c1b, c2w, c2b, ew, eb, U);
    k_attn<<<4096, 256, 0, stream>>>(U, mh_wq, mh_bq, mh_wk, mh_bk, mh_wv, mh_bv,
                                     mh_wo, mh_bo, ln1_g, ln1_b, U2);
    k_xln<<<4096, 256, 0, stream>>>(U2, xln_g, xln_b, LN);
    k_fl1<<<dim3(8, 4, 8), 256, 0, stream>>>(LN, fl1_w, PART);
    k_fl1red<<<512, 256, 0, stream>>>(PART, fl1_b, OUT1);
    k_fl2<<<256, 128, 0, stream>>>(OUT1, fl2_w, fl2_b, OUT2);
    k_fl3<<<256, 128, 0, stream>>>(OUT2, fl3_w, fl3_b, out);
}

// Round 3
// 756.578 us; speedup vs baseline: 3.5093x; 1.4911x over previous
//
#include <hip/hip_runtime.h>
#include <hip/hip_bf16.h>
#include <math.h>

#define LN_EPS 1e-5f

typedef __attribute__((ext_vector_type(8))) short short8v;
typedef __attribute__((ext_vector_type(4))) float f32x4;

static __device__ __forceinline__ unsigned short f2bf(float x) {
    unsigned u = __float_as_uint(x);
    u += 0x7fffu + ((u >> 16) & 1u);
    return (unsigned short)(u >> 16);
}
static __device__ __forceinline__ float bf2f(unsigned short h) {
    return __uint_as_float(((unsigned)h) << 16);
}

// ---------------------------------------------------------------------------
// K1: per-patch conv1+pool -> conv2+pool -> expansion(36->64)+ReLU
// (unchanged from round 2)
// ---------------------------------------------------------------------------
__global__ __launch_bounds__(256, 2) void k_conv(
    const float* __restrict__ t,
    const float* __restrict__ c1w, const float* __restrict__ c1b,
    const float* __restrict__ c2w, const float* __restrict__ c2b,
    const float* __restrict__ ew,  const float* __restrict__ eb,
    float* __restrict__ u)
{
    __shared__ __align__(16) float s_R[16 * 32 * 12];
    __shared__ __align__(16) float s_p1[225 * 32];
    __shared__ __align__(16) float s_s2[32 * 36];
    __shared__ float s_c2b[32];

    float* s_x  = s_R;
    float* s_cw = s_R;
    float* s_ew = s_R;

    const int p   = blockIdx.x;
    const int tid = threadIdx.x;

    const int b = p >> 4, tile = p & 15, tr = tile >> 2, tc = tile & 3;
    const float* tp = t + (size_t)b * 128 * 128 + (size_t)tr * 32 * 128 + tc * 32;
    for (int i = tid; i < 1024; i += 256) {
        const int r = i >> 5, c = i & 31;
        s_x[r * 33 + c] = tp[r * 128 + c] * (1.0f / 255.0f);
    }
    if (tid < 32) s_c2b[tid] = c2b[tid];
    __syncthreads();

    if (tid < 225) {
        const int pi = tid / 15, pj = tid % 15;
        float xw[16];
        #pragma unroll
        for (int r = 0; r < 4; ++r)
            #pragma unroll
            for (int c = 0; c < 4; ++c)
                xw[r * 4 + c] = s_x[(2 * pi + r) * 33 + (2 * pj + c)];
        const int swz = (tid & 7) << 2;
        for (int oc0 = 0; oc0 < 32; oc0 += 4) {
            float4 pq;
            float* pqf = (float*)&pq;
            #pragma unroll
            for (int o = 0; o < 4; ++o) {
                const int oc = oc0 + o;
                float w[9];
                #pragma unroll
                for (int j = 0; j < 9; ++j) w[j] = c1w[oc * 9 + j];
                float mx = -3.0e38f;
                #pragma unroll
                for (int a = 0; a < 2; ++a)
                    #pragma unroll
                    for (int bb = 0; bb < 2; ++bb) {
                        float s = xw[(a + 0) * 4 + bb + 0] * w[0]
                                + xw[(a + 0) * 4 + bb + 1] * w[1]
                                + xw[(a + 0) * 4 + bb + 2] * w[2]
                                + xw[(a + 1) * 4 + bb + 0] * w[3]
                                + xw[(a + 1) * 4 + bb + 1] * w[4]
                                + xw[(a + 1) * 4 + bb + 2] * w[5]
                                + xw[(a + 2) * 4 + bb + 0] * w[6]
                                + xw[(a + 2) * 4 + bb + 1] * w[7]
                                + xw[(a + 2) * 4 + bb + 2] * w[8];
                        mx = fmaxf(mx, s);
                    }
                pqf[o] = mx + c1b[oc];
            }
            *(float4*)&s_p1[tid * 32 + (oc0 ^ swz)] = pq;
        }
    }
    __syncthreads();

    const int pos = (tid < 144) ? (tid % 36) : 0;
    const int ocg = (tid < 144) ? (tid / 36) : 0;
    const int ppi = pos / 6, ppj = pos % 6;
    int wbase[16];
    #pragma unroll
    for (int r = 0; r < 4; ++r)
        #pragma unroll
        for (int c = 0; c < 4; ++c) {
            const int wpos = (2 * ppi + r) * 15 + (2 * ppj + c);
            wbase[r * 4 + c] = wpos * 32 + ((wpos & 7) << 2);
        }

    for (int pass = 0; pass < 2; ++pass) {
        for (int i = tid; i < 16 * 32 * 12; i += 256) {
            const int ol  = i / 384;
            const int rem = i - ol * 384;
            const int ic  = rem / 12;
            const int j   = rem - ic * 12;
            s_cw[i] = (j < 9) ? c2w[((pass * 16 + ol) * 32 + ic) * 9 + j] : 0.0f;
        }
        __syncthreads();

        if (tid < 144) {
            float acc[16];
            #pragma unroll
            for (int i = 0; i < 16; ++i) acc[i] = 0.0f;

            for (int ic0 = 0; ic0 < 32; ic0 += 4) {
                float xv[64];
                #pragma unroll
                for (int w = 0; w < 16; ++w)
                    *(float4*)&xv[w * 4] = *(const float4*)&s_p1[wbase[w] ^ ic0];
                #pragma unroll
                for (int o = 0; o < 4; ++o) {
                    const float* wp = &s_cw[((ocg * 4 + o) * 32 + ic0) * 12];
                    #pragma unroll
                    for (int ic = 0; ic < 4; ++ic) {
                        const float4 wA = *(const float4*)&wp[ic * 12];
                        const float4 wB = *(const float4*)&wp[ic * 12 + 4];
                        const float  w8 = wp[ic * 12 + 8];
                        #pragma unroll
                        for (int a = 0; a < 2; ++a)
                            #pragma unroll
                            for (int bb = 0; bb < 2; ++bb) {
                                const float s =
                                    xv[((a + 0) * 4 + bb + 0) * 4 + ic] * wA.x +
                                    xv[((a + 0) * 4 + bb + 1) * 4 + ic] * wA.y +
                                    xv[((a + 0) * 4 + bb + 2) * 4 + ic] * wA.z +
                                    xv[((a + 1) * 4 + bb + 0) * 4 + ic] * wA.w +
                                    xv[((a + 1) * 4 + bb + 1) * 4 + ic] * wB.x +
                                    xv[((a + 1) * 4 + bb + 2) * 4 + ic] * wB.y +
                                    xv[((a + 2) * 4 + bb + 0) * 4 + ic] * wB.z +
                                    xv[((a + 2) * 4 + bb + 1) * 4 + ic] * wB.w +
                                    xv[((a + 2) * 4 + bb + 2) * 4 + ic] * w8;
                                acc[o * 4 + a * 2 + bb] += s;
                            }
                    }
                }
            }
            #pragma unroll
            for (int o = 0; o < 4; ++o) {
                const int oc = pass * 16 + ocg * 4 + o;
                const float mx = fmaxf(fmaxf(acc[o * 4 + 0], acc[o * 4 + 1]),
                                       fmaxf(acc[o * 4 + 2], acc[o * 4 + 3]));
                s_s2[oc * 36 + pos] = mx + s_c2b[oc];
            }
        }
        __syncthreads();
    }

    for (int i = tid; i < 36 * 64; i += 256) s_ew[i] = ew[i];
    __syncthreads();

    {
        const int s  = tid >> 3;
        const int e0 = (tid & 7) * 8;
        float acc8[8];
        *(float4*)&acc8[0] = *(const float4*)&eb[e0];
        *(float4*)&acc8[4] = *(const float4*)&eb[e0 + 4];
        for (int f = 0; f < 36; ++f) {
            const float sv = s_s2[s * 36 + f];
            const float4 w0 = *(const float4*)&s_ew[f * 64 + e0];
            const float4 w1 = *(const float4*)&s_ew[f * 64 + e0 + 4];
            acc8[0] += sv * w0.x; acc8[1] += sv * w0.y;
            acc8[2] += sv * w0.z; acc8[3] += sv * w0.w;
            acc8[4] += sv * w1.x; acc8[5] += sv * w1.y;
            acc8[6] += sv * w1.z; acc8[7] += sv * w1.w;
        }
        float4 o0, o1;
        o0.x = fmaxf(acc8[0], 0.0f); o0.y = fmaxf(acc8[1], 0.0f);
        o0.z = fmaxf(acc8[2], 0.0f); o0.w = fmaxf(acc8[3], 0.0f);
        o1.x = fmaxf(acc8[4], 0.0f); o1.y = fmaxf(acc8[5], 0.0f);
        o1.z = fmaxf(acc8[6], 0.0f); o1.w = fmaxf(acc8[7], 0.0f);
        float* up = u + (size_t)p * 2048 + s * 64 + e0;
        *(float4*)up       = o0;
        *(float4*)(up + 4) = o1;
    }
}

// ---------------------------------------------------------------------------
// K2: per-patch 4-head attention + o-proj + residual + LN(64) (unchanged)
// ---------------------------------------------------------------------------
#define FMA4(A, W) { A.x += xx * W.x; A.y += xx * W.y; A.z += xx * W.z; A.w += xx * W.w; }

__global__ __launch_bounds__(256, 2) void k_attn(
    const float* __restrict__ u,
    const float* __restrict__ wq, const float* __restrict__ bq,
    const float* __restrict__ wk, const float* __restrict__ bk,
    const float* __restrict__ wv, const float* __restrict__ bv,
    const float* __restrict__ wo, const float* __restrict__ bo,
    const float* __restrict__ g1, const float* __restrict__ b1,
    float* __restrict__ u2)
{
    __shared__ __align__(16) float s_u[32 * 65];
    __shared__ __align__(16) float s_q[4 * 32 * 20];
    __shared__ __align__(16) float s_k[4 * 32 * 20];
    __shared__ __align__(16) float s_v[4 * 32 * 20];
    __shared__ __align__(16) float s_sc[4 * 32 * 33];
    __shared__ __align__(16) float s_o[32 * 65];

    const int g   = blockIdx.x;
    const int m   = g >> 8;
    const int b2  = g & 255;
    const int tid = threadIdx.x;

    const float* up = u + (size_t)g * 2048;
    for (int i = tid; i < 2048; i += 256) {
        const int s = i >> 6, d = i & 63;
        s_u[s * 65 + d] = up[i];
    }
    __syncthreads();

    {
        const int f0 = (tid & 1) * 8;
        const int s  = (tid >> 1) & 31;
        const int h  = tid >> 6;
        const float* wqm = wq + (size_t)m * 4096 + h * 1024 + f0;
        const float* wkm = wk + (size_t)m * 4096 + h * 1024 + f0;
        const float* wvm = wv + (size_t)m * 4096 + h * 1024 + f0;
        float4 aq0 = *(const float4*)&bq[m * 64 + h * 16 + f0];
        float4 aq1 = *(const float4*)&bq[m * 64 + h * 16 + f0 + 4];
        float4 ak0 = *(const float4*)&bk[m * 64 + h * 16 + f0];
        float4 ak1 = *(const float4*)&bk[m * 64 + h * 16 + f0 + 4];
        float4 av0 = *(const float4*)&bv[m * 64 + h * 16 + f0];
        float4 av1 = *(const float4*)&bv[m * 64 + h * 16 + f0 + 4];
        for (int d = 0; d < 64; ++d) {
            const float xx = s_u[s * 65 + d];
            const float4 wq0 = *(const float4*)&wqm[d * 16];
            const float4 wq1 = *(const float4*)&wqm[d * 16 + 4];
            const float4 wk0 = *(const float4*)&wkm[d * 16];
            const float4 wk1 = *(const float4*)&wkm[d * 16 + 4];
            const float4 wv0 = *(const float4*)&wvm[d * 16];
            const float4 wv1 = *(const float4*)&wvm[d * 16 + 4];
            FMA4(aq0, wq0); FMA4(aq1, wq1);
            FMA4(ak0, wk0); FMA4(ak1, wk1);
            FMA4(av0, wv0); FMA4(av1, wv1);
        }
        const int base = (h * 32 + s) * 20 + f0;
        *(float4*)&s_q[base] = aq0; *(float4*)&s_q[base + 4] = aq1;
        *(float4*)&s_k[base] = ak0; *(float4*)&s_k[base + 4] = ak1;
        *(float4*)&s_v[base] = av0; *(float4*)&s_v[base + 4] = av1;
    }
    __syncthreads();

    if (tid < 128) {
        const int h = tid >> 5, s = tid & 31;
        const int qb = (h * 32 + s) * 20;
        const float4 q0 = *(const float4*)&s_q[qb];
        const float4 q1 = *(const float4*)&s_q[qb + 4];
        const float4 q2 = *(const float4*)&s_q[qb + 8];
        const float4 q3 = *(const float4*)&s_q[qb + 12];
        float row[32];
        float mx = -3.0e38f;
        for (int tt = 0; tt < 32; ++tt) {
            const int kb = (h * 32 + tt) * 20;
            const float4 k0 = *(const float4*)&s_k[kb];
            const float4 k1 = *(const float4*)&s_k[kb + 4];
            const float4 k2 = *(const float4*)&s_k[kb + 8];
            const float4 k3 = *(const float4*)&s_k[kb + 12];
            float acc = q0.x * k0.x + q0.y * k0.y + q0.z * k0.z + q0.w * k0.w
                      + q1.x * k1.x + q1.y * k1.y + q1.z * k1.z + q1.w * k1.w
                      + q2.x * k2.x + q2.y * k2.y + q2.z * k2.z + q2.w * k2.w
                      + q3.x * k3.x + q3.y * k3.y + q3.z * k3.z + q3.w * k3.w;
            acc *= 0.25f;
            row[tt] = acc;
            mx = fmaxf(mx, acc);
        }
        float sum = 0.0f;
        for (int tt = 0; tt < 32; ++tt) {
            const float e = expf(row[tt] - mx);
            row[tt] = e;
            sum += e;
        }
        const float inv = 1.0f / sum;
        const int sb = (h * 32 + s) * 33;
        for (int tt = 0; tt < 32; ++tt) s_sc[sb + tt] = row[tt] * inv;
    }
    __syncthreads();

    {
        const int s  = tid >> 3;
        const int d0 = (tid & 7) * 8;
        const int h  = d0 >> 4;
        const int f0 = d0 & 15;
        float4 a0 = {0, 0, 0, 0}, a1 = {0, 0, 0, 0};
        const int sb = (h * 32 + s) * 33;
        for (int tt = 0; tt < 32; ++tt) {
            const float xx = s_sc[sb + tt];
            const int vb = (h * 32 + tt) * 20 + f0;
            const float4 v0 = *(const float4*)&s_v[vb];
            const float4 v1 = *(const float4*)&s_v[vb + 4];
            FMA4(a0, v0); FMA4(a1, v1);
        }
        *(float4*)&s_o[s * 65 + d0]     = a0;
        *(float4*)&s_o[s * 65 + d0 + 4] = a1;
    }
    __syncthreads();

    {
        const float* wom = wo + (size_t)m * 4096;
        const float* bom = bo + m * 64;
        const int lane = tid & 63;
        const int wv_  = tid >> 6;
        float* outp = u2 + (size_t)b2 * 32768 + (size_t)m * 2048;
        for (int s = wv_; s < 32; s += 4) {
            float acc = bom[lane];
            for (int d = 0; d < 64; ++d)
                acc += s_o[s * 65 + d] * wom[d * 64 + lane];
            const float r = s_u[s * 65 + lane] + acc;
            float sum = r;
            #pragma unroll
            for (int off = 32; off; off >>= 1) sum += __shfl_xor(sum, off);
            const float mean = sum * (1.0f / 64.0f);
            const float dd = r - mean;
            float vs = dd * dd;
            #pragma unroll
            for (int off = 32; off; off >>= 1) vs += __shfl_xor(vs, off);
            const float var = vs * (1.0f / 64.0f);
            outp[s * 64 + lane] = dd * rsqrtf(var + LN_EPS) * g1[lane] + b1[lane];
        }
    }
}

// ---------------------------------------------------------------------------
// K3: XL double-LN(2x), now emitting bf16 hi/lo in MFMA-fragment-blocked
// layout: elem (row=b2, k=m*2048+idx) stored at [(k>>5)*256 + b2]*32 + (k&31)
// grid: 4096 rows (b2*16+m), 256 threads (thread t owns idx 8t..8t+7)
// ---------------------------------------------------------------------------
__global__ __launch_bounds__(256) void k_xln(
    const float* __restrict__ in,
    const float* __restrict__ gg, const float* __restrict__ bb,
    unsigned short* __restrict__ Ah, unsigned short* __restrict__ Al)
{
    __shared__ float ws4[4];
    const int row = blockIdx.x;
    const int b2 = row >> 4, m = row & 15;
    const int tid = threadIdx.x;
    const int lane = tid & 63, w = tid >> 6;
    const float* x = in + (size_t)row * 2048 + tid * 8;

    float v[8];
    {
        const float4 x0 = *(const float4*)x;
        const float4 x1 = *(const float4*)(x + 4);
        v[0] = 2.0f * x0.x; v[1] = 2.0f * x0.y; v[2] = 2.0f * x0.z; v[3] = 2.0f * x0.w;
        v[4] = 2.0f * x1.x; v[5] = 2.0f * x1.y; v[6] = 2.0f * x1.z; v[7] = 2.0f * x1.w;
    }

    #pragma unroll
    for (int L = 0; L < 2; L++) {
        float s = 0.0f;
        #pragma unroll
        for (int i = 0; i < 8; i++) s += v[i];
        #pragma unroll
        for (int off = 32; off; off >>= 1) s += __shfl_xor(s, off);
        if (lane == 0) ws4[w] = s;
        __syncthreads();
        const float mean = (ws4[0] + ws4[1] + ws4[2] + ws4[3]) * (1.0f / 2048.0f);
        __syncthreads();

        float q = 0.0f;
        #pragma unroll
        for (int i = 0; i < 8; i++) { const float d = v[i] - mean; q += d * d; }
        #pragma unroll
        for (int off = 32; off; off >>= 1) q += __shfl_xor(q, off);
        if (lane == 0) ws4[w] = q;
        __syncthreads();
        const float inv = rsqrtf((ws4[0] + ws4[1] + ws4[2] + ws4[3]) * (1.0f / 2048.0f) + LN_EPS);
        __syncthreads();

        const float4 g0 = *(const float4*)&gg[L * 2048 + tid * 8];
        const float4 g1v = *(const float4*)&gg[L * 2048 + tid * 8 + 4];
        const float4 b0 = *(const float4*)&bb[L * 2048 + tid * 8];
        const float4 b1v = *(const float4*)&bb[L * 2048 + tid * 8 + 4];
        const float gq[8] = {g0.x, g0.y, g0.z, g0.w, g1v.x, g1v.y, g1v.z, g1v.w};
        const float bq[8] = {b0.x, b0.y, b0.z, b0.w, b1v.x, b1v.y, b1v.z, b1v.w};
        #pragma unroll
        for (int i = 0; i < 8; i++) {
            const float y = (v[i] - mean) * inv * gq[i] + bq[i];
            v[i] = (L == 0) ? 2.0f * y : y;
        }
    }

    const int k = m * 2048 + tid * 8;
    const size_t addr = ((size_t)(k >> 5) * 256 + b2) * 32 + (k & 31);
    short8v hv, lv;
    #pragma unroll
    for (int i = 0; i < 8; i++) {
        const unsigned short h = f2bf(v[i]);
        hv[i] = (short)h;
        lv[i] = (short)f2bf(v[i] - bf2f(h));
    }
    *(short8v*)&Ah[addr] = hv;
    *(short8v*)&Al[addr] = lv;
}

// ---------------------------------------------------------------------------
// K4: fl1 MFMA GEMM, 3-term bf16 hi/lo split (ah*wh + al*wh + ah*wl).
// C(256x512) = A(256x32768) @ W(32768x512).
// grid: (4 nb, 64 kb), 512 threads (8 waves as 4M x 2N). BM=256 BN=128 BK=64.
// W converted f32->bf16 h/l in-kernel into transposed swizzled LDS.
// ---------------------------------------------------------------------------
__global__ __launch_bounds__(512) void k_fl1(
    const unsigned short* __restrict__ Ah,
    const unsigned short* __restrict__ Al,
    const float* __restrict__ W,
    float* __restrict__ part)
{
    __shared__ __align__(16) unsigned short s_wh[128 * 64];
    __shared__ __align__(16) unsigned short s_wl[128 * 64];

    const int nb  = blockIdx.x;        // 0..3
    const int kb  = blockIdx.y;        // 0..63
    const int tid = threadIdx.x;
    const int lane = tid & 63;
    const int wid  = tid >> 6;
    const int wm = wid >> 1;           // 0..3  (64-row block)
    const int wn = wid & 1;            // 0..1  (64-col block)

    // W staging role: one n-column, 16 consecutive kk
    const int sn = tid & 127;
    const int sq = tid >> 7;           // kk range 16*sq..+16
    const int k0 = kb * 512;

    f32x4 acc[4][4];
    #pragma unroll
    for (int i = 0; i < 4; ++i)
        #pragma unroll
        for (int j = 0; j < 4; ++j)
            acc[i][j] = (f32x4){0.0f, 0.0f, 0.0f, 0.0f};

    float wreg[16];
    {
        const float* wp = W + (size_t)(k0 + sq * 16) * 512 + nb * 128 + sn;
        #pragma unroll
        for (int j = 0; j < 16; ++j) wreg[j] = wp[(size_t)j * 512];
    }

    // swizzled write slots: oct q stored at q ^ (n&7)
    const int hsn = sn & 7;
    const int wbase = sn * 64;
    const int wo0 = (((sq * 2) ^ hsn) << 3);
    const int wo1 = (((sq * 2 + 1) ^ hsn) << 3);

    for (int t = 0; t < 8; ++t) {
        __syncthreads();   // previous tile's MFMA done reading LDS
        {
            short8v h0, h1, l0, l1;
            #pragma unroll
            for (int j = 0; j < 8; ++j) {
                const unsigned short ha = f2bf(wreg[j]);
                const unsigned short hb = f2bf(wreg[j + 8]);
                h0[j] = (short)ha;
                h1[j] = (short)hb;
                l0[j] = (short)f2bf(wreg[j] - bf2f(ha));
                l1[j] = (short)f2bf(wreg[j + 8] - bf2f(hb));
            }
            *(short8v*)&s_wh[wbase + wo0] = h0;
            *(short8v*)&s_wh[wbase + wo1] = h1;
            *(short8v*)&s_wl[wbase + wo0] = l0;
            *(short8v*)&s_wl[wbase + wo1] = l1;
        }
        if (t < 7) {
            const float* wp = W + (size_t)(k0 + (t + 1) * 64 + sq * 16) * 512 + nb * 128 + sn;
            #pragma unroll
            for (int j = 0; j < 16; ++j) wreg[j] = wp[(size_t)j * 512];
        }
        __syncthreads();

        #pragma unroll
        for (int ks = 0; ks < 2; ++ks) {
            const int ktile = (k0 >> 5) + t * 2 + ks;
            const size_t abase = ((size_t)ktile * 256 + wm * 64 + (lane & 15)) * 32
                               + (lane >> 4) * 8;
            short8v ahf[4], alf[4];
            #pragma unroll
            for (int mf = 0; mf < 4; ++mf) {
                ahf[mf] = *(const short8v*)&Ah[abase + (size_t)mf * 512];
                alf[mf] = *(const short8v*)&Al[abase + (size_t)mf * 512];
            }
            short8v bhf[4], blf[4];
            #pragma unroll
            for (int nf = 0; nf < 4; ++nf) {
                const int n = wn * 64 + nf * 16 + (lane & 15);
                const int q = ks * 4 + (lane >> 4);
                const int baddr = n * 64 + ((q ^ (n & 7)) << 3);
                bhf[nf] = *(const short8v*)&s_wh[baddr];
                blf[nf] = *(const short8v*)&s_wl[baddr];
            }
            #pragma unroll
            for (int mf = 0; mf < 4; ++mf)
                #pragma unroll
                for (int nf = 0; nf < 4; ++nf) {
                    acc[mf][nf] = __builtin_amdgcn_mfma_f32_16x16x32_bf16(
                        ahf[mf], bhf[nf], acc[mf][nf], 0, 0, 0);
                    acc[mf][nf] = __builtin_amdgcn_mfma_f32_16x16x32_bf16(
                        alf[mf], bhf[nf], acc[mf][nf], 0, 0, 0);
                    acc[mf][nf] = __builtin_amdgcn_mfma_f32_16x16x32_bf16(
                        ahf[mf], blf[nf], acc[mf][nf], 0, 0, 0);
                }
        }
    }

    // store partials: C/D frag layout col=lane&15, row=(lane>>4)*4+reg
    float* pp = part + (size_t)kb * 131072 + (size_t)nb * 128;
    const int r0 = (lane >> 4) * 4;
    const int c  = lane & 15;
    #pragma unroll
    for (int mf = 0; mf < 4; ++mf) {
        const int row = wm * 64 + mf * 16 + r0;
        #pragma unroll
        for (int nf = 0; nf < 4; ++nf) {
            const int col = wn * 64 + nf * 16 + c;
            #pragma unroll
            for (int r = 0; r < 4; ++r)
                pp[(size_t)(row + r) * 512 + col] = acc[mf][nf][r];
        }
    }
}

// K4b: reduce 64 partials + bias + relu -> out1 (256 x 512)
__global__ __launch_bounds__(256) void k_fl1red(
    const float* __restrict__ part, const float* __restrict__ bias,
    float* __restrict__ out1)
{
    const int i4 = (blockIdx.x * 256 + threadIdx.x) * 4;   // 128 blocks
    float4 s = *(const float4*)&bias[i4 & 511];
    for (int ks = 0; ks < 64; ++ks) {
        const float4 p = *(const float4*)&part[(size_t)ks * 131072 + i4];
        s.x += p.x; s.y += p.y; s.z += p.z; s.w += p.w;
    }
    s.x = fmaxf(s.x, 0.0f); s.y = fmaxf(s.y, 0.0f);
    s.z = fmaxf(s.z, 0.0f); s.w = fmaxf(s.w, 0.0f);
    *(float4*)&out1[i4] = s;
}

__global__ __launch_bounds__(128) void k_fl2(
    const float* __restrict__ u1, const float* __restrict__ w,
    const float* __restrict__ b, float* __restrict__ out2)
{
    __shared__ float s_u[512];
    const int r = blockIdx.x, tid = threadIdx.x;
    for (int i = tid; i < 512; i += 128) s_u[i] = u1[r * 512 + i];
    __syncthreads();
    float acc = b[tid];
    for (int k = 0; k < 512; k++) acc += s_u[k] * w[k * 128 + tid];
    out2[r * 128 + tid] = fmaxf(acc, 0.0f);
}

__global__ __launch_bounds__(128) void k_fl3(
    const float* __restrict__ u2_, const float* __restrict__ w,
    const float* __restrict__ b, float* __restrict__ out)
{
    __shared__ float s_u[128];
    const int r = blockIdx.x, tid = threadIdx.x;
    s_u[tid] = u2_[r * 128 + tid];
    __syncthreads();
    if (tid < 25) {
        float acc = b[tid];
        for (int k = 0; k < 128; k++) acc += s_u[k] * w[k * 25 + tid];
        out[r * 25 + tid] = acc;
    }
}

// ---------------------------------------------------------------------------
extern "C" void kernel_launch(void* const* d_in, const int* in_sizes, int n_in,
                              void* d_out, int out_size, void* d_ws, size_t ws_size,
                              hipStream_t stream)
{
    const float* t      = (const float*)d_in[0];
    const float* c1w    = (const float*)d_in[1];
    const float* c1b    = (const float*)d_in[2];
    const float* c2w    = (const float*)d_in[3];
    const float* c2b    = (const float*)d_in[4];
    const float* ew     = (const float*)d_in[5];
    const float* eb     = (const float*)d_in[6];
    const float* mh_wq  = (const float*)d_in[7];
    const float* mh_bq  = (const float*)d_in[8];
    const float* mh_wk  = (const float*)d_in[9];
    const float* mh_bk  = (const float*)d_in[10];
    const float* mh_wv  = (const float*)d_in[11];
    const float* mh_bv  = (const float*)d_in[12];
    const float* mh_wo  = (const float*)d_in[13];
    const float* mh_bo  = (const float*)d_in[14];
    const float* ln1_g  = (const float*)d_in[15];
    const float* ln1_b  = (const float*)d_in[16];
    // d_in[17..24]: XL attention weights -- dead code in the reference, unused
    const float* xln_g  = (const float*)d_in[25];
    const float* xln_b  = (const float*)d_in[26];
    const float* fl1_w  = (const float*)d_in[27];
    const float* fl1_b  = (const float*)d_in[28];
    const float* fl2_w  = (const float*)d_in[29];
    const float* fl2_b  = (const float*)d_in[30];
    const float* fl3_w  = (const float*)d_in[31];
    const float* fl3_b  = (const float*)d_in[32];
    (void)in_sizes; (void)n_in; (void)out_size; (void)ws_size;

    float* U   = (float*)d_ws;                    // 8.4M floats: conv out / attn in
    float* U2  = U + 8388608;                     // 8.4M floats: attn out / xln in
    unsigned short* Ah = (unsigned short*)U;      // reuse U: 8.4M ushort
    unsigned short* Al = Ah + 8388608;            // 8.4M ushort (fills U region)
    float* PART = U2;                             // reuse U2: 64 x 131072 floats
    float* OUT1 = U2;                             // alias slab 0 (per-thread RBW safe)
    float* OUT2 = U;                              // U region dead after k_fl1
    float* out  = (float*)d_out;

    k_conv<<<4096, 256, 0, stream>>>(t, c1w, c1b, c2w, c2b, ew, eb, U);
    k_attn<<<4096, 256, 0, stream>>>(U, mh_wq, mh_bq, mh_wk, mh_bk, mh_wv, mh_bv,
                                     mh_wo, mh_bo, ln1_g, ln1_b, U2);
    k_xln<<<4096, 256, 0, stream>>>(U2, xln_g, xln_b, Ah, Al);
    k_fl1<<<dim3(4, 64), 512, 0, stream>>>(Ah, Al, fl1_w, PART);
    k_fl1red<<<128, 256, 0, stream>>>(PART, fl1_b, OUT1);
    k_fl2<<<256, 128, 0, stream>>>(OUT1, fl2_w, fl2_b, OUT2);
    k_fl3<<<256, 128, 0, stream>>>(OUT2, fl3_w, fl3_b, out);
}

// Round 4
// 595.555 us; speedup vs baseline: 4.4581x; 1.2704x over previous
//
#include <hip/hip_runtime.h>
#include <hip/hip_bf16.h>
#include <math.h>

#define LN_EPS 1e-5f

typedef __attribute__((ext_vector_type(8))) short short8v;
typedef __attribute__((ext_vector_type(4))) float f32x4;

static __device__ __forceinline__ unsigned short f2bf(float x) {
    unsigned u = __float_as_uint(x);
    u += 0x7fffu + ((u >> 16) & 1u);
    return (unsigned short)(u >> 16);
}
static __device__ __forceinline__ float bf2f(unsigned short h) {
    return __uint_as_float(((unsigned)h) << 16);
}

// w2 window accessor: compile-time col c (0..7) into float2 w2[r][4]
#define W2C(r, c) (((c) & 1) ? w2[r][(c) >> 1].y : w2[r][(c) >> 1].x)

// ---------------------------------------------------------------------------
// K1: per-patch conv1+pool -> conv2+pool -> expansion(36->64)+ReLU
// Phase B rewritten: all 256 threads (oc = tid>>3, 3x6 conv block each),
// per-ic plane p1 layout, shfl-based pooling. 72.8 KB LDS -> 2 blocks/CU.
// ---------------------------------------------------------------------------
__global__ __launch_bounds__(256, 2) void k_conv(
    const float* __restrict__ t,
    const float* __restrict__ c1w, const float* __restrict__ c1b,
    const float* __restrict__ c2w, const float* __restrict__ c2b,
    const float* __restrict__ ew,  const float* __restrict__ eb,
    float* __restrict__ u)
{
    __shared__ __align__(16) float s_R[32 * 292];   // 37376 B: s_x | s_cw
    __shared__ __align__(16) float s_p1[32 * 240];  // 30720 B: p1 planes | s_ew
    __shared__ __align__(16) float s_s2[32 * 36];   // 4608 B
    __shared__ float s_c2b[32];

    float* s_x  = s_R;     // [32][33] during phase A
    float* s_cw = s_R;     // [32][292] during phase B (oc-stride 292: banks spread)
    float* s_ew = s_p1;    // [36*64] during phase C (p1 dead)

    const int p   = blockIdx.x;
    const int tid = threadIdx.x;

    // ---- prefetch c2w into regs (2304 float4 total, 9 per thread) ----
    float4 cwreg[9];
    #pragma unroll
    for (int j = 0; j < 9; ++j)
        cwreg[j] = *(const float4*)&c2w[(tid + j * 256) * 4];

    // ---- stage input patch (scaled) + c2b ----
    const int b = p >> 4, tile = p & 15, tr = tile >> 2, tc = tile & 3;
    const float* tp = t + (size_t)b * 128 * 128 + (size_t)tr * 32 * 128 + tc * 32;
    for (int i = tid; i < 1024; i += 256) {
        const int r = i >> 5, c = i & 31;
        s_x[r * 33 + c] = tp[r * 128 + c] * (1.0f / 255.0f);
    }
    if (tid < 32) s_c2b[tid] = c2b[tid];
    __syncthreads();

    // ---- phase A: conv1 (1->32, 3x3) + pool -> s_p1[oc][pi*16+pj] ----
    if (tid < 225) {
        const int pi = tid / 15, pj = tid % 15;
        float xw[16];
        #pragma unroll
        for (int r = 0; r < 4; ++r)
            #pragma unroll
            for (int c = 0; c < 4; ++c)
                xw[r * 4 + c] = s_x[(2 * pi + r) * 33 + (2 * pj + c)];
        const int pbase = pi * 16 + pj;
        for (int oc = 0; oc < 32; ++oc) {     // uniform -> scalar weight loads
            float w[9];
            #pragma unroll
            for (int j = 0; j < 9; ++j) w[j] = c1w[oc * 9 + j];
            float mx = -3.0e38f;
            #pragma unroll
            for (int a = 0; a < 2; ++a)
                #pragma unroll
                for (int bb = 0; bb < 2; ++bb) {
                    float s = xw[(a + 0) * 4 + bb + 0] * w[0]
                            + xw[(a + 0) * 4 + bb + 1] * w[1]
                            + xw[(a + 0) * 4 + bb + 2] * w[2]
                            + xw[(a + 1) * 4 + bb + 0] * w[3]
                            + xw[(a + 1) * 4 + bb + 1] * w[4]
                            + xw[(a + 1) * 4 + bb + 2] * w[5]
                            + xw[(a + 2) * 4 + bb + 0] * w[6]
                            + xw[(a + 2) * 4 + bb + 1] * w[7]
                            + xw[(a + 2) * 4 + bb + 2] * w[8];
                    mx = fmaxf(mx, s);
                }
            s_p1[oc * 240 + pbase] = mx + c1b[oc];
        }
    }
    __syncthreads();

    // ---- scatter prefetched c2w into s_cw[oc][292] (overwrites s_x) ----
    #pragma unroll
    for (int j = 0; j < 9; ++j) {
        const int f  = tid + j * 256;      // float4 id < 2304
        const int oc = f / 72;             // 72 float4 per oc row (288 floats)
        const int jj = (f - oc * 72) * 4;
        *(float4*)&s_cw[oc * 292 + jj] = cwreg[j];
    }
    // prefetch ew into regs (576 float4, 3 each for tid<192)
    float4 ewreg[3];
    if (tid < 192) {
        #pragma unroll
        for (int j = 0; j < 3; ++j)
            ewreg[j] = *(const float4*)&ew[(tid * 3 + j) * 4];
    }
    __syncthreads();

    // ---- phase B: conv2 (32->32, 3x3) at 12x12 + pool, 256 threads ----
    {
        const int oc  = tid >> 3;
        const int grp = tid & 7;
        const int gr  = grp >> 1;          // 0..3 -> conv rows gr*3..gr*3+2
        const int gc  = grp & 1;           // 0..1 -> conv cols gc*6..gc*6+5
        const int r0  = gr * 3;
        const int c0  = gc * 6;

        float acc[3][6];
        #pragma unroll
        for (int i = 0; i < 3; ++i)
            #pragma unroll
            for (int j = 0; j < 6; ++j) acc[i][j] = 0.0f;

        const float* wrow = &s_cw[oc * 292];
        for (int ic = 0; ic < 32; ++ic) {
            float2 w2[5][4];               // rows r0..r0+4, cols c0..c0+7
            const float* pb = &s_p1[ic * 240 + r0 * 16 + c0];
            #pragma unroll
            for (int r = 0; r < 5; ++r)
                #pragma unroll
                for (int k = 0; k < 4; ++k)
                    w2[r][k] = *(const float2*)&pb[r * 16 + 2 * k];
            float wv[9];
            const float* wt = &wrow[ic * 9];
            #pragma unroll
            for (int j = 0; j < 9; ++j) wv[j] = wt[j];
            #pragma unroll
            for (int i = 0; i < 3; ++i)
                #pragma unroll
                for (int dr = 0; dr < 3; ++dr) {
                    const int rr = i + dr;
                    #pragma unroll
                    for (int jj = 0; jj < 6; ++jj)
                        acc[i][jj] += W2C(rr, jj)     * wv[dr * 3 + 0]
                                    + W2C(rr, jj + 1) * wv[dr * 3 + 1]
                                    + W2C(rr, jj + 2) * wv[dr * 3 + 2];
                }
        }

        // pool columns (2:1), then rows via shfl partner exchange
        float pc0[3], pc1[3], pc2[3];
        #pragma unroll
        for (int q = 0; q < 3; ++q) {
            pc0[q] = fmaxf(acc[0][2 * q], acc[0][2 * q + 1]);
            pc1[q] = fmaxf(acc[1][2 * q], acc[1][2 * q + 1]);
            pc2[q] = fmaxf(acc[2][2 * q], acc[2][2 * q + 1]);
        }
        float nb0[3];
        #pragma unroll
        for (int q = 0; q < 3; ++q) nb0[q] = __shfl_down(pc0[q], 2);
        const float bias = s_c2b[oc];
        const int colb = oc * 36 + gc * 3;
        const int pr0  = (gr >> 1) * 3;
        if ((gr & 1) == 0) {
            #pragma unroll
            for (int q = 0; q < 3; ++q) {
                s_s2[colb + pr0 * 6 + q]       = fmaxf(pc0[q], pc1[q]) + bias;
                s_s2[colb + (pr0 + 1) * 6 + q] = fmaxf(pc2[q], nb0[q]) + bias;
            }
        } else {
            #pragma unroll
            for (int q = 0; q < 3; ++q)
                s_s2[colb + (pr0 + 2) * 6 + q] = fmaxf(pc1[q], pc2[q]) + bias;
        }
    }
    __syncthreads();

    // ---- stage ew into s_ew (aliases dead s_p1) ----
    if (tid < 192) {
        #pragma unroll
        for (int j = 0; j < 3; ++j)
            *(float4*)&s_ew[(tid * 3 + j) * 4] = ewreg[j];
    }
    __syncthreads();

    // ---- phase C: expansion relu(s2(32x36) @ ew(36x64) + eb) ----
    // note: s_s2 is [oc][36] = column-major vs math's s2[s][f]; here s = row
    // index of the 32x36 matrix = oc of conv2 output... s2[s][f]: s indexes
    // the 32 conv2 CHANNELS, f the 36 positions -> s_s2[s*36+f] matches.
    {
        const int s  = tid >> 3;
        const int e0 = (tid & 7) * 8;
        float acc8[8];
        *(float4*)&acc8[0] = *(const float4*)&eb[e0];
        *(float4*)&acc8[4] = *(const float4*)&eb[e0 + 4];
        for (int f = 0; f < 36; ++f) {
            const float sv = s_s2[s * 36 + f];
            const float4 w0 = *(const float4*)&s_ew[f * 64 + e0];
            const float4 w1 = *(const float4*)&s_ew[f * 64 + e0 + 4];
            acc8[0] += sv * w0.x; acc8[1] += sv * w0.y;
            acc8[2] += sv * w0.z; acc8[3] += sv * w0.w;
            acc8[4] += sv * w1.x; acc8[5] += sv * w1.y;
            acc8[6] += sv * w1.z; acc8[7] += sv * w1.w;
        }
        float4 o0, o1;
        o0.x = fmaxf(acc8[0], 0.0f); o0.y = fmaxf(acc8[1], 0.0f);
        o0.z = fmaxf(acc8[2], 0.0f); o0.w = fmaxf(acc8[3], 0.0f);
        o1.x = fmaxf(acc8[4], 0.0f); o1.y = fmaxf(acc8[5], 0.0f);
        o1.z = fmaxf(acc8[6], 0.0f); o1.w = fmaxf(acc8[7], 0.0f);
        float* up = u + (size_t)p * 2048 + s * 64 + e0;
        *(float4*)up       = o0;
        *(float4*)(up + 4) = o1;
    }
}

// ---------------------------------------------------------------------------
// K2: per-patch 4-head attention + o-proj + residual + LN(64) (unchanged)
// ---------------------------------------------------------------------------
#define FMA4(A, W) { A.x += xx * W.x; A.y += xx * W.y; A.z += xx * W.z; A.w += xx * W.w; }

__global__ __launch_bounds__(256, 2) void k_attn(
    const float* __restrict__ u,
    const float* __restrict__ wq, const float* __restrict__ bq,
    const float* __restrict__ wk, const float* __restrict__ bk,
    const float* __restrict__ wv, const float* __restrict__ bv,
    const float* __restrict__ wo, const float* __restrict__ bo,
    const float* __restrict__ g1, const float* __restrict__ b1,
    float* __restrict__ u2)
{
    __shared__ __align__(16) float s_u[32 * 65];
    __shared__ __align__(16) float s_q[4 * 32 * 20];
    __shared__ __align__(16) float s_k[4 * 32 * 20];
    __shared__ __align__(16) float s_v[4 * 32 * 20];
    __shared__ __align__(16) float s_sc[4 * 32 * 33];
    __shared__ __align__(16) float s_o[32 * 65];

    const int g   = blockIdx.x;
    const int m   = g >> 8;
    const int b2  = g & 255;
    const int tid = threadIdx.x;

    const float* up = u + (size_t)g * 2048;
    for (int i = tid; i < 2048; i += 256) {
        const int s = i >> 6, d = i & 63;
        s_u[s * 65 + d] = up[i];
    }
    __syncthreads();

    {
        const int f0 = (tid & 1) * 8;
        const int s  = (tid >> 1) & 31;
        const int h  = tid >> 6;
        const float* wqm = wq + (size_t)m * 4096 + h * 1024 + f0;
        const float* wkm = wk + (size_t)m * 4096 + h * 1024 + f0;
        const float* wvm = wv + (size_t)m * 4096 + h * 1024 + f0;
        float4 aq0 = *(const float4*)&bq[m * 64 + h * 16 + f0];
        float4 aq1 = *(const float4*)&bq[m * 64 + h * 16 + f0 + 4];
        float4 ak0 = *(const float4*)&bk[m * 64 + h * 16 + f0];
        float4 ak1 = *(const float4*)&bk[m * 64 + h * 16 + f0 + 4];
        float4 av0 = *(const float4*)&bv[m * 64 + h * 16 + f0];
        float4 av1 = *(const float4*)&bv[m * 64 + h * 16 + f0 + 4];
        for (int d = 0; d < 64; ++d) {
            const float xx = s_u[s * 65 + d];
            const float4 wq0 = *(const float4*)&wqm[d * 16];
            const float4 wq1 = *(const float4*)&wqm[d * 16 + 4];
            const float4 wk0 = *(const float4*)&wkm[d * 16];
            const float4 wk1 = *(const float4*)&wkm[d * 16 + 4];
            const float4 wv0 = *(const float4*)&wvm[d * 16];
            const float4 wv1 = *(const float4*)&wvm[d * 16 + 4];
            FMA4(aq0, wq0); FMA4(aq1, wq1);
            FMA4(ak0, wk0); FMA4(ak1, wk1);
            FMA4(av0, wv0); FMA4(av1, wv1);
        }
        const int base = (h * 32 + s) * 20 + f0;
        *(float4*)&s_q[base] = aq0; *(float4*)&s_q[base + 4] = aq1;
        *(float4*)&s_k[base] = ak0; *(float4*)&s_k[base + 4] = ak1;
        *(float4*)&s_v[base] = av0; *(float4*)&s_v[base + 4] = av1;
    }
    __syncthreads();

    if (tid < 128) {
        const int h = tid >> 5, s = tid & 31;
        const int qb = (h * 32 + s) * 20;
        const float4 q0 = *(const float4*)&s_q[qb];
        const float4 q1 = *(const float4*)&s_q[qb + 4];
        const float4 q2 = *(const float4*)&s_q[qb + 8];
        const float4 q3 = *(const float4*)&s_q[qb + 12];
        float row[32];
        float mx = -3.0e38f;
        for (int tt = 0; tt < 32; ++tt) {
            const int kb = (h * 32 + tt) * 20;
            const float4 k0 = *(const float4*)&s_k[kb];
            const float4 k1 = *(const float4*)&s_k[kb + 4];
            const float4 k2 = *(const float4*)&s_k[kb + 8];
            const float4 k3 = *(const float4*)&s_k[kb + 12];
            float acc = q0.x * k0.x + q0.y * k0.y + q0.z * k0.z + q0.w * k0.w
                      + q1.x * k1.x + q1.y * k1.y + q1.z * k1.z + q1.w * k1.w
                      + q2.x * k2.x + q2.y * k2.y + q2.z * k2.z + q2.w * k2.w
                      + q3.x * k3.x + q3.y * k3.y + q3.z * k3.z + q3.w * k3.w;
            acc *= 0.25f;
            row[tt] = acc;
            mx = fmaxf(mx, acc);
        }
        float sum = 0.0f;
        for (int tt = 0; tt < 32; ++tt) {
            const float e = expf(row[tt] - mx);
            row[tt] = e;
            sum += e;
        }
        const float inv = 1.0f / sum;
        const int sb = (h * 32 + s) * 33;
        for (int tt = 0; tt < 32; ++tt) s_sc[sb + tt] = row[tt] * inv;
    }
    __syncthreads();

    {
        const int s  = tid >> 3;
        const int d0 = (tid & 7) * 8;
        const int h  = d0 >> 4;
        const int f0 = d0 & 15;
        float4 a0 = {0, 0, 0, 0}, a1 = {0, 0, 0, 0};
        const int sb = (h * 32 + s) * 33;
        for (int tt = 0; tt < 32; ++tt) {
            const float xx = s_sc[sb + tt];
            const int vb = (h * 32 + tt) * 20 + f0;
            const float4 v0 = *(const float4*)&s_v[vb];
            const float4 v1 = *(const float4*)&s_v[vb + 4];
            FMA4(a0, v0); FMA4(a1, v1);
        }
        *(float4*)&s_o[s * 65 + d0]     = a0;
        *(float4*)&s_o[s * 65 + d0 + 4] = a1;
    }
    __syncthreads();

    {
        const float* wom = wo + (size_t)m * 4096;
        const float* bom = bo + m * 64;
        const int lane = tid & 63;
        const int wv_  = tid >> 6;
        float* outp = u2 + (size_t)b2 * 32768 + (size_t)m * 2048;
        for (int s = wv_; s < 32; s += 4) {
            float acc = bom[lane];
            for (int d = 0; d < 64; ++d)
                acc += s_o[s * 65 + d] * wom[d * 64 + lane];
            const float r = s_u[s * 65 + lane] + acc;
            float sum = r;
            #pragma unroll
            for (int off = 32; off; off >>= 1) sum += __shfl_xor(sum, off);
            const float mean = sum * (1.0f / 64.0f);
            const float dd = r - mean;
            float vs = dd * dd;
            #pragma unroll
            for (int off = 32; off; off >>= 1) vs += __shfl_xor(vs, off);
            const float var = vs * (1.0f / 64.0f);
            outp[s * 64 + lane] = dd * rsqrtf(var + LN_EPS) * g1[lane] + b1[lane];
        }
    }
}

// ---------------------------------------------------------------------------
// K3: XL double-LN(2x), emitting bf16 hi/lo in MFMA-fragment-blocked layout
// ---------------------------------------------------------------------------
__global__ __launch_bounds__(256) void k_xln(
    const float* __restrict__ in,
    const float* __restrict__ gg, const float* __restrict__ bb,
    unsigned short* __restrict__ Ah, unsigned short* __restrict__ Al)
{
    __shared__ float ws4[4];
    const int row = blockIdx.x;
    const int b2 = row >> 4, m = row & 15;
    const int tid = threadIdx.x;
    const int lane = tid & 63, w = tid >> 6;
    const float* x = in + (size_t)row * 2048 + tid * 8;

    float v[8];
    {
        const float4 x0 = *(const float4*)x;
        const float4 x1 = *(const float4*)(x + 4);
        v[0] = 2.0f * x0.x; v[1] = 2.0f * x0.y; v[2] = 2.0f * x0.z; v[3] = 2.0f * x0.w;
        v[4] = 2.0f * x1.x; v[5] = 2.0f * x1.y; v[6] = 2.0f * x1.z; v[7] = 2.0f * x1.w;
    }

    #pragma unroll
    for (int L = 0; L < 2; L++) {
        float s = 0.0f;
        #pragma unroll
        for (int i = 0; i < 8; i++) s += v[i];
        #pragma unroll
        for (int off = 32; off; off >>= 1) s += __shfl_xor(s, off);
        if (lane == 0) ws4[w] = s;
        __syncthreads();
        const float mean = (ws4[0] + ws4[1] + ws4[2] + ws4[3]) * (1.0f / 2048.0f);
        __syncthreads();

        float q = 0.0f;
        #pragma unroll
        for (int i = 0; i < 8; i++) { const float d = v[i] - mean; q += d * d; }
        #pragma unroll
        for (int off = 32; off; off >>= 1) q += __shfl_xor(q, off);
        if (lane == 0) ws4[w] = q;
        __syncthreads();
        const float inv = rsqrtf((ws4[0] + ws4[1] + ws4[2] + ws4[3]) * (1.0f / 2048.0f) + LN_EPS);
        __syncthreads();

        const float4 g0 = *(const float4*)&gg[L * 2048 + tid * 8];
        const float4 g1v = *(const float4*)&gg[L * 2048 + tid * 8 + 4];
        const float4 b0 = *(const float4*)&bb[L * 2048 + tid * 8];
        const float4 b1v = *(const float4*)&bb[L * 2048 + tid * 8 + 4];
        const float gq[8] = {g0.x, g0.y, g0.z, g0.w, g1v.x, g1v.y, g1v.z, g1v.w};
        const float bq[8] = {b0.x, b0.y, b0.z, b0.w, b1v.x, b1v.y, b1v.z, b1v.w};
        #pragma unroll
        for (int i = 0; i < 8; i++) {
            const float y = (v[i] - mean) * inv * gq[i] + bq[i];
            v[i] = (L == 0) ? 2.0f * y : y;
        }
    }

    const int k = m * 2048 + tid * 8;
    const size_t addr = ((size_t)(k >> 5) * 256 + b2) * 32 + (k & 31);
    short8v hv, lv;
    #pragma unroll
    for (int i = 0; i < 8; i++) {
        const unsigned short h = f2bf(v[i]);
        hv[i] = (short)h;
        lv[i] = (short)f2bf(v[i] - bf2f(h));
    }
    *(short8v*)&Ah[addr] = hv;
    *(short8v*)&Al[addr] = lv;
}

// ---------------------------------------------------------------------------
// K4: fl1 MFMA GEMM, 3-term bf16 hi/lo split (unchanged)
// ---------------------------------------------------------------------------
__global__ __launch_bounds__(512) void k_fl1(
    const unsigned short* __restrict__ Ah,
    const unsigned short* __restrict__ Al,
    const float* __restrict__ W,
    float* __restrict__ part)
{
    __shared__ __align__(16) unsigned short s_wh[128 * 64];
    __shared__ __align__(16) unsigned short s_wl[128 * 64];

    const int nb  = blockIdx.x;
    const int kb  = blockIdx.y;
    const int tid = threadIdx.x;
    const int lane = tid & 63;
    const int wid  = tid >> 6;
    const int wm = wid >> 1;
    const int wn = wid & 1;

    const int sn = tid & 127;
    const int sq = tid >> 7;
    const int k0 = kb * 512;

    f32x4 acc[4][4];
    #pragma unroll
    for (int i = 0; i < 4; ++i)
        #pragma unroll
        for (int j = 0; j < 4; ++j)
            acc[i][j] = (f32x4){0.0f, 0.0f, 0.0f, 0.0f};

    float wreg[16];
    {
        const float* wp = W + (size_t)(k0 + sq * 16) * 512 + nb * 128 + sn;
        #pragma unroll
        for (int j = 0; j < 16; ++j) wreg[j] = wp[(size_t)j * 512];
    }

    const int hsn = sn & 7;
    const int wbase = sn * 64;
    const int wo0 = (((sq * 2) ^ hsn) << 3);
    const int wo1 = (((sq * 2 + 1) ^ hsn) << 3);

    for (int tt = 0; tt < 8; ++tt) {
        __syncthreads();
        {
            short8v h0, h1, l0, l1;
            #pragma unroll
            for (int j = 0; j < 8; ++j) {
                const unsigned short ha = f2bf(wreg[j]);
                const unsigned short hb = f2bf(wreg[j + 8]);
                h0[j] = (short)ha;
                h1[j] = (short)hb;
                l0[j] = (short)f2bf(wreg[j] - bf2f(ha));
                l1[j] = (short)f2bf(wreg[j + 8] - bf2f(hb));
            }
            *(short8v*)&s_wh[wbase + wo0] = h0;
            *(short8v*)&s_wh[wbase + wo1] = h1;
            *(short8v*)&s_wl[wbase + wo0] = l0;
            *(short8v*)&s_wl[wbase + wo1] = l1;
        }
        if (tt < 7) {
            const float* wp = W + (size_t)(k0 + (tt + 1) * 64 + sq * 16) * 512 + nb * 128 + sn;
            #pragma unroll
            for (int j = 0; j < 16; ++j) wreg[j] = wp[(size_t)j * 512];
        }
        __syncthreads();

        #pragma unroll
        for (int ks = 0; ks < 2; ++ks) {
            const int ktile = (k0 >> 5) + tt * 2 + ks;
            const size_t abase = ((size_t)ktile * 256 + wm * 64 + (lane & 15)) * 32
                               + (lane >> 4) * 8;
            short8v ahf[4], alf[4];
            #pragma unroll
            for (int mf = 0; mf < 4; ++mf) {
                ahf[mf] = *(const short8v*)&Ah[abase + (size_t)mf * 512];
                alf[mf] = *(const short8v*)&Al[abase + (size_t)mf * 512];
            }
            short8v bhf[4], blf[4];
            #pragma unroll
            for (int nf = 0; nf < 4; ++nf) {
                const int n = wn * 64 + nf * 16 + (lane & 15);
                const int q = ks * 4 + (lane >> 4);
                const int baddr = n * 64 + ((q ^ (n & 7)) << 3);
                bhf[nf] = *(const short8v*)&s_wh[baddr];
                blf[nf] = *(const short8v*)&s_wl[baddr];
            }
            #pragma unroll
            for (int mf = 0; mf < 4; ++mf)
                #pragma unroll
                for (int nf = 0; nf < 4; ++nf) {
                    acc[mf][nf] = __builtin_amdgcn_mfma_f32_16x16x32_bf16(
                        ahf[mf], bhf[nf], acc[mf][nf], 0, 0, 0);
                    acc[mf][nf] = __builtin_amdgcn_mfma_f32_16x16x32_bf16(
                        alf[mf], bhf[nf], acc[mf][nf], 0, 0, 0);
                    acc[mf][nf] = __builtin_amdgcn_mfma_f32_16x16x32_bf16(
                        ahf[mf], blf[nf], acc[mf][nf], 0, 0, 0);
                }
        }
    }

    float* pp = part + (size_t)kb * 131072 + (size_t)nb * 128;
    const int r0 = (lane >> 4) * 4;
    const int c  = lane & 15;
    #pragma unroll
    for (int mf = 0; mf < 4; ++mf) {
        const int row = wm * 64 + mf * 16 + r0;
        #pragma unroll
        for (int nf = 0; nf < 4; ++nf) {
            const int col = wn * 64 + nf * 16 + c;
            #pragma unroll
            for (int r = 0; r < 4; ++r)
                pp[(size_t)(row + r) * 512 + col] = acc[mf][nf][r];
        }
    }
}

__global__ __launch_bounds__(256) void k_fl1red(
    const float* __restrict__ part, const float* __restrict__ bias,
    float* __restrict__ out1)
{
    const int i4 = (blockIdx.x * 256 + threadIdx.x) * 4;
    float4 s = *(const float4*)&bias[i4 & 511];
    for (int ks = 0; ks < 64; ++ks) {
        const float4 p = *(const float4*)&part[(size_t)ks * 131072 + i4];
        s.x += p.x; s.y += p.y; s.z += p.z; s.w += p.w;
    }
    s.x = fmaxf(s.x, 0.0f); s.y = fmaxf(s.y, 0.0f);
    s.z = fmaxf(s.z, 0.0f); s.w = fmaxf(s.w, 0.0f);
    *(float4*)&out1[i4] = s;
}

__global__ __launch_bounds__(128) void k_fl2(
    const float* __restrict__ u1, const float* __restrict__ w,
    const float* __restrict__ b, float* __restrict__ out2)
{
    __shared__ float s_u[512];
    const int r = blockIdx.x, tid = threadIdx.x;
    for (int i = tid; i < 512; i += 128) s_u[i] = u1[r * 512 + i];
    __syncthreads();
    float acc = b[tid];
    for (int k = 0; k < 512; k++) acc += s_u[k] * w[k * 128 + tid];
    out2[r * 128 + tid] = fmaxf(acc, 0.0f);
}

__global__ __launch_bounds__(128) void k_fl3(
    const float* __restrict__ u2_, const float* __restrict__ w,
    const float* __restrict__ b, float* __restrict__ out)
{
    __shared__ float s_u[128];
    const int r = blockIdx.x, tid = threadIdx.x;
    s_u[tid] = u2_[r * 128 + tid];
    __syncthreads();
    if (tid < 25) {
        float acc = b[tid];
        for (int k = 0; k < 128; k++) acc += s_u[k] * w[k * 25 + tid];
        out[r * 25 + tid] = acc;
    }
}

// ---------------------------------------------------------------------------
extern "C" void kernel_launch(void* const* d_in, const int* in_sizes, int n_in,
                              void* d_out, int out_size, void* d_ws, size_t ws_size,
                              hipStream_t stream)
{
    const float* t      = (const float*)d_in[0];
    const float* c1w    = (const float*)d_in[1];
    const float* c1b    = (const float*)d_in[2];
    const float* c2w    = (const float*)d_in[3];
    const float* c2b    = (const float*)d_in[4];
    const float* ew     = (const float*)d_in[5];
    const float* eb     = (const float*)d_in[6];
    const float* mh_wq  = (const float*)d_in[7];
    const float* mh_bq  = (const float*)d_in[8];
    const float* mh_wk  = (const float*)d_in[9];
    const float* mh_bk  = (const float*)d_in[10];
    const float* mh_wv  = (const float*)d_in[11];
    const float* mh_bv  = (const float*)d_in[12];
    const float* mh_wo  = (const float*)d_in[13];
    const float* mh_bo  = (const float*)d_in[14];
    const float* ln1_g  = (const float*)d_in[15];
    const float* ln1_b  = (const float*)d_in[16];
    // d_in[17..24]: XL attention weights -- dead code in the reference, unused
    const float* xln_g  = (const float*)d_in[25];
    const float* xln_b  = (const float*)d_in[26];
    const float* fl1_w  = (const float*)d_in[27];
    const float* fl1_b  = (const float*)d_in[28];
    const float* fl2_w  = (const float*)d_in[29];
    const float* fl2_b  = (const float*)d_in[30];
    const float* fl3_w  = (const float*)d_in[31];
    const float* fl3_b  = (const float*)d_in[32];
    (void)in_sizes; (void)n_in; (void)out_size; (void)ws_size;

    float* U   = (float*)d_ws;                    // conv out / attn in
    float* U2  = U + 8388608;                     // attn out / xln in
    unsigned short* Ah = (unsigned short*)U;      // reuse U after attn
    unsigned short* Al = Ah + 8388608;
    float* PART = U2;                             // reuse U2 after xln
    float* OUT1 = U2;
    float* OUT2 = U;
    float* out  = (float*)d_out;

    k_conv<<<4096, 256, 0, stream>>>(t, c1w, c1b, c2w, c2b, ew, eb, U);
    k_attn<<<4096, 256, 0, stream>>>(U, mh_wq, mh_bq, mh_wk, mh_bk, mh_wv, mh_bv,
                                     mh_wo, mh_bo, ln1_g, ln1_b, U2);
    k_xln<<<4096, 256, 0, stream>>>(U2, xln_g, xln_b, Ah, Al);
    k_fl1<<<dim3(4, 64), 512, 0, stream>>>(Ah, Al, fl1_w, PART);
    k_fl1red<<<128, 256, 0, stream>>>(PART, fl1_b, OUT1);
    k_fl2<<<256, 128, 0, stream>>>(OUT1, fl2_w, fl2_b, OUT2);
    k_fl3<<<256, 128, 0, stream>>>(OUT2, fl3_w, fl3_b, out);
}

// Round 5
// 466.928 us; speedup vs baseline: 5.6862x; 1.2755x over previous
//
#include <hip/hip_runtime.h>
#include <hip/hip_bf16.h>
#include <math.h>

#define LN_EPS 1e-5f

typedef __attribute__((ext_vector_type(8))) short short8v;
typedef __attribute__((ext_vector_type(4))) float f32x4;

static __device__ __forceinline__ unsigned short f2bf(float x) {
    unsigned u = __float_as_uint(x);
    u += 0x7fffu + ((u >> 16) & 1u);
    return (unsigned short)(u >> 16);
}
static __device__ __forceinline__ float bf2f(unsigned short h) {
    return __uint_as_float(((unsigned)h) << 16);
}

// ---------------------------------------------------------------------------
// K1: per-patch conv1+pool -> conv2 (MFMA im2col, bf16 hi/lo 3-term)
//     + shfl-pool -> expansion(36->64)+ReLU.
// grid: 4096 blocks, 256 threads (4 waves). LDS 78.6 KB -> 2 blocks/CU.
// conv2 GEMM: C[oc=32][n=144] = W[32][288] @ P1[288][144],
//   k = (dr*3+dc)*32 + ic;  n = pq*4 + (a*2+b), pq = pooled 6x6 idx.
// ---------------------------------------------------------------------------
__global__ __launch_bounds__(256, 2) void k_conv(
    const float* __restrict__ t,
    const float* __restrict__ c1w, const float* __restrict__ c1b,
    const float* __restrict__ c2w, const float* __restrict__ c2b,
    const float* __restrict__ ew,  const float* __restrict__ eb,
    float* __restrict__ u)
{
    __shared__ __align__(16) unsigned short s_W2[2][32 * 296];  // 37888 B (hi|lo)
    __shared__ __align__(16) unsigned short s_p1h[225 * 40];    // 18000 B
    __shared__ __align__(16) unsigned short s_p1l[225 * 40];    // 18000 B
    __shared__ __align__(16) float s_s2[32 * 36];               // 4608 B
    __shared__ float s_c2b[32];

    float* s_x  = (float*)s_W2;       // [32][33] during phase A (dead before W stage)
    float* s_ew = (float*)s_p1h;      // [36*64] during phase C (p1 dead)
    unsigned short* s_wh = s_W2[0];
    unsigned short* s_wl = s_W2[1];

    const int p   = blockIdx.x;
    const int tid = threadIdx.x;

    // ---- stage input patch (scaled) + c2b ----
    const int b = p >> 4, tile = p & 15, tr = tile >> 2, tc = tile & 3;
    const float* tp = t + (size_t)b * 128 * 128 + (size_t)tr * 32 * 128 + tc * 32;
    for (int i = tid; i < 1024; i += 256) {
        const int r = i >> 5, c = i & 31;
        s_x[r * 33 + c] = tp[r * 128 + c] * (1.0f / 255.0f);
    }
    if (tid < 32) s_c2b[tid] = c2b[tid];
    __syncthreads();

    // ---- phase A: conv1 (1->32, 3x3) + pool -> p1[pos15][ic] bf16 hi/lo ----
    if (tid < 225) {
        const int pi = tid / 15, pj = tid % 15;
        float xw[16];
        #pragma unroll
        for (int r = 0; r < 4; ++r)
            #pragma unroll
            for (int c = 0; c < 4; ++c)
                xw[r * 4 + c] = s_x[(2 * pi + r) * 33 + (2 * pj + c)];
        for (int og = 0; og < 4; ++og) {
            short8v hb, lb;
            #pragma unroll
            for (int o = 0; o < 8; ++o) {
                const int oc = og * 8 + o;           // uniform -> scalar loads
                float w[9];
                #pragma unroll
                for (int j = 0; j < 9; ++j) w[j] = c1w[oc * 9 + j];
                float mx = -3.0e38f;
                #pragma unroll
                for (int a = 0; a < 2; ++a)
                    #pragma unroll
                    for (int bb = 0; bb < 2; ++bb) {
                        float s = xw[(a + 0) * 4 + bb + 0] * w[0]
                                + xw[(a + 0) * 4 + bb + 1] * w[1]
                                + xw[(a + 0) * 4 + bb + 2] * w[2]
                                + xw[(a + 1) * 4 + bb + 0] * w[3]
                                + xw[(a + 1) * 4 + bb + 1] * w[4]
                                + xw[(a + 1) * 4 + bb + 2] * w[5]
                                + xw[(a + 2) * 4 + bb + 0] * w[6]
                                + xw[(a + 2) * 4 + bb + 1] * w[7]
                                + xw[(a + 2) * 4 + bb + 2] * w[8];
                        mx = fmaxf(mx, s);
                    }
                const float val = mx + c1b[oc];
                const unsigned short h = f2bf(val);
                hb[o] = (short)h;
                lb[o] = (short)f2bf(val - bf2f(h));
            }
            *(short8v*)&s_p1h[tid * 40 + og * 8] = hb;
            *(short8v*)&s_p1l[tid * 40 + og * 8] = lb;
        }
    }
    __syncthreads();

    // ---- stage c2w -> s_wh/s_wl [oc][296], k=(dr*3+dc)*32+ic (overwrites s_x) ----
    {
        const int oc  = tid >> 3;
        const int sub = tid & 7;
        const float* wp = c2w + oc * 288 + sub * 36;   // 4 ic x 9 taps
        float wf[36];
        #pragma unroll
        for (int j = 0; j < 9; ++j)
            *(float4*)&wf[j * 4] = *(const float4*)&wp[j * 4];
        #pragma unroll
        for (int qp = 0; qp < 2; ++qp) {
            #pragma unroll
            for (int ks = 0; ks < 9; ++ks) {
                const float v0 = wf[(2 * qp) * 9 + ks];
                const float v1 = wf[(2 * qp + 1) * 9 + ks];
                const unsigned short h0 = f2bf(v0), h1 = f2bf(v1);
                const unsigned short l0 = f2bf(v0 - bf2f(h0));
                const unsigned short l1 = f2bf(v1 - bf2f(h1));
                const int idx = oc * 296 + ks * 32 + sub * 4 + 2 * qp;
                *(unsigned*)&s_wh[idx] = (unsigned)h0 | ((unsigned)h1 << 16);
                *(unsigned*)&s_wl[idx] = (unsigned)l0 | ((unsigned)l1 << 16);
            }
        }
    }
    __syncthreads();

    // ---- phase B: conv2 via MFMA + in-register 2x2 pool ----
    {
        const int lane = tid & 63;
        const int wv   = tid >> 6;
        const int jcol = lane & 15;
        const int icg8 = (lane >> 4) * 8;
        const bool live2 = (wv == 0);      // slot 2 only for wave 0 (nt=8)

        int rb[3], cb[3];
        #pragma unroll
        for (int s = 0; s < 3; ++s) {
            const int nt = wv + s * 4;
            const int n = nt * 16 + jcol;
            const int pq = n >> 2, w4 = n & 3;
            const int pi = pq / 6, pj = pq - pi * 6;
            rb[s] = 2 * pi + (w4 >> 1);
            cb[s] = 2 * pj + (w4 & 1);
        }

        f32x4 acc[3][2];
        #pragma unroll
        for (int s = 0; s < 3; ++s)
            #pragma unroll
            for (int mt = 0; mt < 2; ++mt)
                acc[s][mt] = (f32x4){0.0f, 0.0f, 0.0f, 0.0f};

        #pragma unroll
        for (int ks = 0; ks < 9; ++ks) {
            const int dr = ks / 3, dc = ks - dr * 3;
            const int ab = jcol * 296 + ks * 32 + icg8;
            const short8v ah0 = *(const short8v*)&s_wh[ab];
            const short8v ah1 = *(const short8v*)&s_wh[ab + 16 * 296];
            const short8v al0 = *(const short8v*)&s_wl[ab];
            const short8v al1 = *(const short8v*)&s_wl[ab + 16 * 296];
            #pragma unroll
            for (int s = 0; s < 3; ++s) {
                if (s == 2 && !live2) continue;
                const int boff = ((rb[s] + dr) * 15 + (cb[s] + dc)) * 40 + icg8;
                const short8v bh = *(const short8v*)&s_p1h[boff];
                const short8v bl = *(const short8v*)&s_p1l[boff];
                acc[s][0] = __builtin_amdgcn_mfma_f32_16x16x32_bf16(ah0, bh, acc[s][0], 0, 0, 0);
                acc[s][0] = __builtin_amdgcn_mfma_f32_16x16x32_bf16(al0, bh, acc[s][0], 0, 0, 0);
                acc[s][0] = __builtin_amdgcn_mfma_f32_16x16x32_bf16(ah0, bl, acc[s][0], 0, 0, 0);
                acc[s][1] = __builtin_amdgcn_mfma_f32_16x16x32_bf16(ah1, bh, acc[s][1], 0, 0, 0);
                acc[s][1] = __builtin_amdgcn_mfma_f32_16x16x32_bf16(al1, bh, acc[s][1], 0, 0, 0);
                acc[s][1] = __builtin_amdgcn_mfma_f32_16x16x32_bf16(ah1, bl, acc[s][1], 0, 0, 0);
            }
        }

        // pool 4 adjacent cols (one 2x2 window) via shfl, + bias -> s_s2[oc][36]
        #pragma unroll
        for (int s = 0; s < 3; ++s) {
            if (s == 2 && !live2) continue;
            const int nt = wv + s * 4;
            #pragma unroll
            for (int mt = 0; mt < 2; ++mt)
                #pragma unroll
                for (int r = 0; r < 4; ++r) {
                    float v = acc[s][mt][r];
                    v = fmaxf(v, __shfl_xor(v, 1));
                    v = fmaxf(v, __shfl_xor(v, 2));
                    if ((lane & 3) == 0) {
                        const int oc = mt * 16 + (lane >> 4) * 4 + r;
                        const int pq = nt * 4 + ((lane & 15) >> 2);
                        s_s2[oc * 36 + pq] = v + s_c2b[oc];
                    }
                }
        }
    }
    __syncthreads();

    // ---- stage ew into s_ew (aliases dead p1) ----
    for (int i = tid; i < 576; i += 256)
        *(float4*)&s_ew[i * 4] = *(const float4*)&ew[i * 4];
    __syncthreads();

    // ---- phase C: expansion relu(s2(32x36) @ ew(36x64) + eb) ----
    {
        const int s  = tid >> 3;
        const int e0 = (tid & 7) * 8;
        float acc8[8];
        *(float4*)&acc8[0] = *(const float4*)&eb[e0];
        *(float4*)&acc8[4] = *(const float4*)&eb[e0 + 4];
        for (int f = 0; f < 36; ++f) {
            const float sv = s_s2[s * 36 + f];
            const float4 w0 = *(const float4*)&s_ew[f * 64 + e0];
            const float4 w1 = *(const float4*)&s_ew[f * 64 + e0 + 4];
            acc8[0] += sv * w0.x; acc8[1] += sv * w0.y;
            acc8[2] += sv * w0.z; acc8[3] += sv * w0.w;
            acc8[4] += sv * w1.x; acc8[5] += sv * w1.y;
            acc8[6] += sv * w1.z; acc8[7] += sv * w1.w;
        }
        float4 o0, o1;
        o0.x = fmaxf(acc8[0], 0.0f); o0.y = fmaxf(acc8[1], 0.0f);
        o0.z = fmaxf(acc8[2], 0.0f); o0.w = fmaxf(acc8[3], 0.0f);
        o1.x = fmaxf(acc8[4], 0.0f); o1.y = fmaxf(acc8[5], 0.0f);
        o1.z = fmaxf(acc8[6], 0.0f); o1.w = fmaxf(acc8[7], 0.0f);
        float* up = u + (size_t)p * 2048 + s * 64 + e0;
        *(float4*)up       = o0;
        *(float4*)(up + 4) = o1;
    }
}

// ---------------------------------------------------------------------------
// K2: per-patch 4-head attention + o-proj + residual + LN(64) (unchanged)
// ---------------------------------------------------------------------------
#define FMA4(A, W) { A.x += xx * W.x; A.y += xx * W.y; A.z += xx * W.z; A.w += xx * W.w; }

__global__ __launch_bounds__(256, 2) void k_attn(
    const float* __restrict__ u,
    const float* __restrict__ wq, const float* __restrict__ bq,
    const float* __restrict__ wk, const float* __restrict__ bk,
    const float* __restrict__ wv, const float* __restrict__ bv,
    const float* __restrict__ wo, const float* __restrict__ bo,
    const float* __restrict__ g1, const float* __restrict__ b1,
    float* __restrict__ u2)
{
    __shared__ __align__(16) float s_u[32 * 65];
    __shared__ __align__(16) float s_q[4 * 32 * 20];
    __shared__ __align__(16) float s_k[4 * 32 * 20];
    __shared__ __align__(16) float s_v[4 * 32 * 20];
    __shared__ __align__(16) float s_sc[4 * 32 * 33];
    __shared__ __align__(16) float s_o[32 * 65];

    const int g   = blockIdx.x;
    const int m   = g >> 8;
    const int b2  = g & 255;
    const int tid = threadIdx.x;

    const float* up = u + (size_t)g * 2048;
    for (int i = tid; i < 2048; i += 256) {
        const int s = i >> 6, d = i & 63;
        s_u[s * 65 + d] = up[i];
    }
    __syncthreads();

    {
        const int f0 = (tid & 1) * 8;
        const int s  = (tid >> 1) & 31;
        const int h  = tid >> 6;
        const float* wqm = wq + (size_t)m * 4096 + h * 1024 + f0;
        const float* wkm = wk + (size_t)m * 4096 + h * 1024 + f0;
        const float* wvm = wv + (size_t)m * 4096 + h * 1024 + f0;
        float4 aq0 = *(const float4*)&bq[m * 64 + h * 16 + f0];
        float4 aq1 = *(const float4*)&bq[m * 64 + h * 16 + f0 + 4];
        float4 ak0 = *(const float4*)&bk[m * 64 + h * 16 + f0];
        float4 ak1 = *(const float4*)&bk[m * 64 + h * 16 + f0 + 4];
        float4 av0 = *(const float4*)&bv[m * 64 + h * 16 + f0];
        float4 av1 = *(const float4*)&bv[m * 64 + h * 16 + f0 + 4];
        for (int d = 0; d < 64; ++d) {
            const float xx = s_u[s * 65 + d];
            const float4 wq0 = *(const float4*)&wqm[d * 16];
            const float4 wq1 = *(const float4*)&wqm[d * 16 + 4];
            const float4 wk0 = *(const float4*)&wkm[d * 16];
            const float4 wk1 = *(const float4*)&wkm[d * 16 + 4];
            const float4 wv0 = *(const float4*)&wvm[d * 16];
            const float4 wv1 = *(const float4*)&wvm[d * 16 + 4];
            FMA4(aq0, wq0); FMA4(aq1, wq1);
            FMA4(ak0, wk0); FMA4(ak1, wk1);
            FMA4(av0, wv0); FMA4(av1, wv1);
        }
        const int base = (h * 32 + s) * 20 + f0;
        *(float4*)&s_q[base] = aq0; *(float4*)&s_q[base + 4] = aq1;
        *(float4*)&s_k[base] = ak0; *(float4*)&s_k[base + 4] = ak1;
        *(float4*)&s_v[base] = av0; *(float4*)&s_v[base + 4] = av1;
    }
    __syncthreads();

    if (tid < 128) {
        const int h = tid >> 5, s = tid & 31;
        const int qb = (h * 32 + s) * 20;
        const float4 q0 = *(const float4*)&s_q[qb];
        const float4 q1 = *(const float4*)&s_q[qb + 4];
        const float4 q2 = *(const float4*)&s_q[qb + 8];
        const float4 q3 = *(const float4*)&s_q[qb + 12];
        float row[32];
        float mx = -3.0e38f;
        for (int tt = 0; tt < 32; ++tt) {
            const int kb = (h * 32 + tt) * 20;
            const float4 k0 = *(const float4*)&s_k[kb];
            const float4 k1 = *(const float4*)&s_k[kb + 4];
            const float4 k2 = *(const float4*)&s_k[kb + 8];
            const float4 k3 = *(const float4*)&s_k[kb + 12];
            float acc = q0.x * k0.x + q0.y * k0.y + q0.z * k0.z + q0.w * k0.w
                      + q1.x * k1.x + q1.y * k1.y + q1.z * k1.z + q1.w * k1.w
                      + q2.x * k2.x + q2.y * k2.y + q2.z * k2.z + q2.w * k2.w
                      + q3.x * k3.x + q3.y * k3.y + q3.z * k3.z + q3.w * k3.w;
            acc *= 0.25f;
            row[tt] = acc;
            mx = fmaxf(mx, acc);
        }
        float sum = 0.0f;
        for (int tt = 0; tt < 32; ++tt) {
            const float e = expf(row[tt] - mx);
            row[tt] = e;
            sum += e;
        }
        const float inv = 1.0f / sum;
        const int sb = (h * 32 + s) * 33;
        for (int tt = 0; tt < 32; ++tt) s_sc[sb + tt] = row[tt] * inv;
    }
    __syncthreads();

    {
        const int s  = tid >> 3;
        const int d0 = (tid & 7) * 8;
        const int h  = d0 >> 4;
        const int f0 = d0 & 15;
        float4 a0 = {0, 0, 0, 0}, a1 = {0, 0, 0, 0};
        const int sb = (h * 32 + s) * 33;
        for (int tt = 0; tt < 32; ++tt) {
            const float xx = s_sc[sb + tt];
            const int vb = (h * 32 + tt) * 20 + f0;
            const float4 v0 = *(const float4*)&s_v[vb];
            const float4 v1 = *(const float4*)&s_v[vb + 4];
            FMA4(a0, v0); FMA4(a1, v1);
        }
        *(float4*)&s_o[s * 65 + d0]     = a0;
        *(float4*)&s_o[s * 65 + d0 + 4] = a1;
    }
    __syncthreads();

    {
        const float* wom = wo + (size_t)m * 4096;
        const float* bom = bo + m * 64;
        const int lane = tid & 63;
        const int wv_  = tid >> 6;
        float* outp = u2 + (size_t)b2 * 32768 + (size_t)m * 2048;
        for (int s = wv_; s < 32; s += 4) {
            float acc = bom[lane];
            for (int d = 0; d < 64; ++d)
                acc += s_o[s * 65 + d] * wom[d * 64 + lane];
            const float r = s_u[s * 65 + lane] + acc;
            float sum = r;
            #pragma unroll
            for (int off = 32; off; off >>= 1) sum += __shfl_xor(sum, off);
            const float mean = sum * (1.0f / 64.0f);
            const float dd = r - mean;
            float vs = dd * dd;
            #pragma unroll
            for (int off = 32; off; off >>= 1) vs += __shfl_xor(vs, off);
            const float var = vs * (1.0f / 64.0f);
            outp[s * 64 + lane] = dd * rsqrtf(var + LN_EPS) * g1[lane] + b1[lane];
        }
    }
}

// ---------------------------------------------------------------------------
// K3: XL double-LN(2x), emitting bf16 hi/lo in MFMA-fragment-blocked layout
// ---------------------------------------------------------------------------
__global__ __launch_bounds__(256) void k_xln(
    const float* __restrict__ in,
    const float* __restrict__ gg, const float* __restrict__ bb,
    unsigned short* __restrict__ Ah, unsigned short* __restrict__ Al)
{
    __shared__ float ws4[4];
    const int row = blockIdx.x;
    const int b2 = row >> 4, m = row & 15;
    const int tid = threadIdx.x;
    const int lane = tid & 63, w = tid >> 6;
    const float* x = in + (size_t)row * 2048 + tid * 8;

    float v[8];
    {
        const float4 x0 = *(const float4*)x;
        const float4 x1 = *(const float4*)(x + 4);
        v[0] = 2.0f * x0.x; v[1] = 2.0f * x0.y; v[2] = 2.0f * x0.z; v[3] = 2.0f * x0.w;
        v[4] = 2.0f * x1.x; v[5] = 2.0f * x1.y; v[6] = 2.0f * x1.z; v[7] = 2.0f * x1.w;
    }

    #pragma unroll
    for (int L = 0; L < 2; L++) {
        float s = 0.0f;
        #pragma unroll
        for (int i = 0; i < 8; i++) s += v[i];
        #pragma unroll
        for (int off = 32; off; off >>= 1) s += __shfl_xor(s, off);
        if (lane == 0) ws4[w] = s;
        __syncthreads();
        const float mean = (ws4[0] + ws4[1] + ws4[2] + ws4[3]) * (1.0f / 2048.0f);
        __syncthreads();

        float q = 0.0f;
        #pragma unroll
        for (int i = 0; i < 8; i++) { const float d = v[i] - mean; q += d * d; }
        #pragma unroll
        for (int off = 32; off; off >>= 1) q += __shfl_xor(q, off);
        if (lane == 0) ws4[w] = q;
        __syncthreads();
        const float inv = rsqrtf((ws4[0] + ws4[1] + ws4[2] + ws4[3]) * (1.0f / 2048.0f) + LN_EPS);
        __syncthreads();

        const float4 g0 = *(const float4*)&gg[L * 2048 + tid * 8];
        const float4 g1v = *(const float4*)&gg[L * 2048 + tid * 8 + 4];
        const float4 b0 = *(const float4*)&bb[L * 2048 + tid * 8];
        const float4 b1v = *(const float4*)&bb[L * 2048 + tid * 8 + 4];
        const float gq[8] = {g0.x, g0.y, g0.z, g0.w, g1v.x, g1v.y, g1v.z, g1v.w};
        const float bq[8] = {b0.x, b0.y, b0.z, b0.w, b1v.x, b1v.y, b1v.z, b1v.w};
        #pragma unroll
        for (int i = 0; i < 8; i++) {
            const float y = (v[i] - mean) * inv * gq[i] + bq[i];
            v[i] = (L == 0) ? 2.0f * y : y;
        }
    }

    const int k = m * 2048 + tid * 8;
    const size_t addr = ((size_t)(k >> 5) * 256 + b2) * 32 + (k & 31);
    short8v hv, lv;
    #pragma unroll
    for (int i = 0; i < 8; i++) {
        const unsigned short h = f2bf(v[i]);
        hv[i] = (short)h;
        lv[i] = (short)f2bf(v[i] - bf2f(h));
    }
    *(short8v*)&Ah[addr] = hv;
    *(short8v*)&Al[addr] = lv;
}

// ---------------------------------------------------------------------------
// K4: fl1 MFMA GEMM, 3-term bf16 hi/lo split (unchanged)
// ---------------------------------------------------------------------------
__global__ __launch_bounds__(512) void k_fl1(
    const unsigned short* __restrict__ Ah,
    const unsigned short* __restrict__ Al,
    const float* __restrict__ W,
    float* __restrict__ part)
{
    __shared__ __align__(16) unsigned short s_wh[128 * 64];
    __shared__ __align__(16) unsigned short s_wl[128 * 64];

    const int nb  = blockIdx.x;
    const int kb  = blockIdx.y;
    const int tid = threadIdx.x;
    const int lane = tid & 63;
    const int wid  = tid >> 6;
    const int wm = wid >> 1;
    const int wn = wid & 1;

    const int sn = tid & 127;
    const int sq = tid >> 7;
    const int k0 = kb * 512;

    f32x4 acc[4][4];
    #pragma unroll
    for (int i = 0; i < 4; ++i)
        #pragma unroll
        for (int j = 0; j < 4; ++j)
            acc[i][j] = (f32x4){0.0f, 0.0f, 0.0f, 0.0f};

    float wreg[16];
    {
        const float* wp = W + (size_t)(k0 + sq * 16) * 512 + nb * 128 + sn;
        #pragma unroll
        for (int j = 0; j < 16; ++j) wreg[j] = wp[(size_t)j * 512];
    }

    const int hsn = sn & 7;
    const int wbase = sn * 64;
    const int wo0 = (((sq * 2) ^ hsn) << 3);
    const int wo1 = (((sq * 2 + 1) ^ hsn) << 3);

    for (int tt = 0; tt < 8; ++tt) {
        __syncthreads();
        {
            short8v h0, h1, l0, l1;
            #pragma unroll
            for (int j = 0; j < 8; ++j) {
                const unsigned short ha = f2bf(wreg[j]);
                const unsigned short hb = f2bf(wreg[j + 8]);
                h0[j] = (short)ha;
                h1[j] = (short)hb;
                l0[j] = (short)f2bf(wreg[j] - bf2f(ha));
                l1[j] = (short)f2bf(wreg[j + 8] - bf2f(hb));
            }
            *(short8v*)&s_wh[wbase + wo0] = h0;
            *(short8v*)&s_wh[wbase + wo1] = h1;
            *(short8v*)&s_wl[wbase + wo0] = l0;
            *(short8v*)&s_wl[wbase + wo1] = l1;
        }
        if (tt < 7) {
            const float* wp = W + (size_t)(k0 + (tt + 1) * 64 + sq * 16) * 512 + nb * 128 + sn;
            #pragma unroll
            for (int j = 0; j < 16; ++j) wreg[j] = wp[(size_t)j * 512];
        }
        __syncthreads();

        #pragma unroll
        for (int ks = 0; ks < 2; ++ks) {
            const int ktile = (k0 >> 5) + tt * 2 + ks;
            const size_t abase = ((size_t)ktile * 256 + wm * 64 + (lane & 15)) * 32
                               + (lane >> 4) * 8;
            short8v ahf[4], alf[4];
            #pragma unroll
            for (int mf = 0; mf < 4; ++mf) {
                ahf[mf] = *(const short8v*)&Ah[abase + (size_t)mf * 512];
                alf[mf] = *(const short8v*)&Al[abase + (size_t)mf * 512];
            }
            short8v bhf[4], blf[4];
            #pragma unroll
            for (int nf = 0; nf < 4; ++nf) {
                const int n = wn * 64 + nf * 16 + (lane & 15);
                const int q = ks * 4 + (lane >> 4);
                const int baddr = n * 64 + ((q ^ (n & 7)) << 3);
                bhf[nf] = *(const short8v*)&s_wh[baddr];
                blf[nf] = *(const short8v*)&s_wl[baddr];
            }
            #pragma unroll
            for (int mf = 0; mf < 4; ++mf)
                #pragma unroll
                for (int nf = 0; nf < 4; ++nf) {
                    acc[mf][nf] = __builtin_amdgcn_mfma_f32_16x16x32_bf16(
                        ahf[mf], bhf[nf], acc[mf][nf], 0, 0, 0);
                    acc[mf][nf] = __builtin_amdgcn_mfma_f32_16x16x32_bf16(
                        alf[mf], bhf[nf], acc[mf][nf], 0, 0, 0);
                    acc[mf][nf] = __builtin_amdgcn_mfma_f32_16x16x32_bf16(
                        ahf[mf], blf[nf], acc[mf][nf], 0, 0, 0);
                }
        }
    }

    float* pp = part + (size_t)kb * 131072 + (size_t)nb * 128;
    const int r0 = (lane >> 4) * 4;
    const int c  = lane & 15;
    #pragma unroll
    for (int mf = 0; mf < 4; ++mf) {
        const int row = wm * 64 + mf * 16 + r0;
        #pragma unroll
        for (int nf = 0; nf < 4; ++nf) {
            const int col = wn * 64 + nf * 16 + c;
            #pragma unroll
            for (int r = 0; r < 4; ++r)
                pp[(size_t)(row + r) * 512 + col] = acc[mf][nf][r];
        }
    }
}

__global__ __launch_bounds__(256) void k_fl1red(
    const float* __restrict__ part, const float* __restrict__ bias,
    float* __restrict__ out1)
{
    const int i4 = (blockIdx.x * 256 + threadIdx.x) * 4;
    float4 s = *(const float4*)&bias[i4 & 511];
    for (int ks = 0; ks < 64; ++ks) {
        const float4 p = *(const float4*)&part[(size_t)ks * 131072 + i4];
        s.x += p.x; s.y += p.y; s.z += p.z; s.w += p.w;
    }
    s.x = fmaxf(s.x, 0.0f); s.y = fmaxf(s.y, 0.0f);
    s.z = fmaxf(s.z, 0.0f); s.w = fmaxf(s.w, 0.0f);
    *(float4*)&out1[i4] = s;
}

__global__ __launch_bounds__(128) void k_fl2(
    const float* __restrict__ u1, const float* __restrict__ w,
    const float* __restrict__ b, float* __restrict__ out2)
{
    __shared__ float s_u[512];
    const int r = blockIdx.x, tid = threadIdx.x;
    for (int i = tid; i < 512; i += 128) s_u[i] = u1[r * 512 + i];
    __syncthreads();
    float acc = b[tid];
    for (int k = 0; k < 512; k++) acc += s_u[k] * w[k * 128 + tid];
    out2[r * 128 + tid] = fmaxf(acc, 0.0f);
}

__global__ __launch_bounds__(128) void k_fl3(
    const float* __restrict__ u2_, const float* __restrict__ w,
    const float* __restrict__ b, float* __restrict__ out)
{
    __shared__ float s_u[128];
    const int r = blockIdx.x, tid = threadIdx.x;
    s_u[tid] = u2_[r * 128 + tid];
    __syncthreads();
    if (tid < 25) {
        float acc = b[tid];
        for (int k = 0; k < 128; k++) acc += s_u[k] * w[k * 25 + tid];
        out[r * 25 + tid] = acc;
    }
}

// ---------------------------------------------------------------------------
extern "C" void kernel_launch(void* const* d_in, const int* in_sizes, int n_in,
                              void* d_out, int out_size, void* d_ws, size_t ws_size,
                              hipStream_t stream)
{
    const float* t      = (const float*)d_in[0];
    const float* c1w    = (const float*)d_in[1];
    const float* c1b    = (const float*)d_in[2];
    const float* c2w    = (const float*)d_in[3];
    const float* c2b    = (const float*)d_in[4];
    const float* ew     = (const float*)d_in[5];
    const float* eb     = (const float*)d_in[6];
    const float* mh_wq  = (const float*)d_in[7];
    const float* mh_bq  = (const float*)d_in[8];
    const float* mh_wk  = (const float*)d_in[9];
    const float* mh_bk  = (const float*)d_in[10];
    const float* mh_wv  = (const float*)d_in[11];
    const float* mh_bv  = (const float*)d_in[12];
    const float* mh_wo  = (const float*)d_in[13];
    const float* mh_bo  = (const float*)d_in[14];
    const float* ln1_g  = (const float*)d_in[15];
    const float* ln1_b  = (const float*)d_in[16];
    // d_in[17..24]: XL attention weights -- dead code in the reference, unused
    const float* xln_g  = (const float*)d_in[25];
    const float* xln_b  = (const float*)d_in[26];
    const float* fl1_w  = (const float*)d_in[27];
    const float* fl1_b  = (const float*)d_in[28];
    const float* fl2_w  = (const float*)d_in[29];
    const float* fl2_b  = (const float*)d_in[30];
    const float* fl3_w  = (const float*)d_in[31];
    const float* fl3_b  = (const float*)d_in[32];
    (void)in_sizes; (void)n_in; (void)out_size; (void)ws_size;

    float* U   = (float*)d_ws;                    // conv out / attn in
    float* U2  = U + 8388608;                     // attn out / xln in
    unsigned short* Ah = (unsigned short*)U;      // reuse U after attn
    unsigned short* Al = Ah + 8388608;
    float* PART = U2;                             // reuse U2 after xln
    float* OUT1 = U2;
    float* OUT2 = U;
    float* out  = (float*)d_out;

    k_conv<<<4096, 256, 0, stream>>>(t, c1w, c1b, c2w, c2b, ew, eb, U);
    k_attn<<<4096, 256, 0, stream>>>(U, mh_wq, mh_bq, mh_wk, mh_bk, mh_wv, mh_bv,
                                     mh_wo, mh_bo, ln1_g, ln1_b, U2);
    k_xln<<<4096, 256, 0, stream>>>(U2, xln_g, xln_b, Ah, Al);
    k_fl1<<<dim3(4, 64), 512, 0, stream>>>(Ah, Al, fl1_w, PART);
    k_fl1red<<<128, 256, 0, stream>>>(PART, fl1_b, OUT1);
    k_fl2<<<256, 128, 0, stream>>>(OUT1, fl2_w, fl2_b, OUT2);
    k_fl3<<<256, 128, 0, stream>>>(OUT2, fl3_w, fl3_b, out);
}

// Round 6
// 294.136 us; speedup vs baseline: 9.0266x; 1.5875x over previous
//
#include <hip/hip_runtime.h>
#include <hip/hip_bf16.h>
#include <math.h>

#define LN_EPS 1e-5f

typedef __attribute__((ext_vector_type(8))) short short8v;
typedef __attribute__((ext_vector_type(4))) float f32x4;

static __device__ __forceinline__ unsigned short f2bf(float x) {
    unsigned u = __float_as_uint(x);
    u += 0x7fffu + ((u >> 16) & 1u);
    return (unsigned short)(u >> 16);
}
static __device__ __forceinline__ float bf2f(unsigned short h) {
    return __uint_as_float(((unsigned)h) << 16);
}

#define MFMA3(ACC, AH, AL, BH, BL)                                          \
    ACC = __builtin_amdgcn_mfma_f32_16x16x32_bf16(AH, BH, ACC, 0, 0, 0);    \
    ACC = __builtin_amdgcn_mfma_f32_16x16x32_bf16(AL, BH, ACC, 0, 0, 0);    \
    ACC = __builtin_amdgcn_mfma_f32_16x16x32_bf16(AH, BL, ACC, 0, 0, 0);

// ---------------------------------------------------------------------------
// K1: per-patch conv1+pool -> conv2 (MFMA im2col) + shfl-pool -> expansion
// (unchanged from round 5)
// ---------------------------------------------------------------------------
__global__ __launch_bounds__(256, 2) void k_conv(
    const float* __restrict__ t,
    const float* __restrict__ c1w, const float* __restrict__ c1b,
    const float* __restrict__ c2w, const float* __restrict__ c2b,
    const float* __restrict__ ew,  const float* __restrict__ eb,
    float* __restrict__ u)
{
    __shared__ __align__(16) unsigned short s_W2[2][32 * 296];
    __shared__ __align__(16) unsigned short s_p1h[225 * 40];
    __shared__ __align__(16) unsigned short s_p1l[225 * 40];
    __shared__ __align__(16) float s_s2[32 * 36];
    __shared__ float s_c2b[32];

    float* s_x  = (float*)s_W2;
    float* s_ew = (float*)s_p1h;
    unsigned short* s_wh = s_W2[0];
    unsigned short* s_wl = s_W2[1];

    const int p   = blockIdx.x;
    const int tid = threadIdx.x;

    const int b = p >> 4, tile = p & 15, tr = tile >> 2, tc = tile & 3;
    const float* tp = t + (size_t)b * 128 * 128 + (size_t)tr * 32 * 128 + tc * 32;
    for (int i = tid; i < 1024; i += 256) {
        const int r = i >> 5, c = i & 31;
        s_x[r * 33 + c] = tp[r * 128 + c] * (1.0f / 255.0f);
    }
    if (tid < 32) s_c2b[tid] = c2b[tid];
    __syncthreads();

    if (tid < 225) {
        const int pi = tid / 15, pj = tid % 15;
        float xw[16];
        #pragma unroll
        for (int r = 0; r < 4; ++r)
            #pragma unroll
            for (int c = 0; c < 4; ++c)
                xw[r * 4 + c] = s_x[(2 * pi + r) * 33 + (2 * pj + c)];
        for (int og = 0; og < 4; ++og) {
            short8v hb, lb;
            #pragma unroll
            for (int o = 0; o < 8; ++o) {
                const int oc = og * 8 + o;
                float w[9];
                #pragma unroll
                for (int j = 0; j < 9; ++j) w[j] = c1w[oc * 9 + j];
                float mx = -3.0e38f;
                #pragma unroll
                for (int a = 0; a < 2; ++a)
                    #pragma unroll
                    for (int bb = 0; bb < 2; ++bb) {
                        float s = xw[(a + 0) * 4 + bb + 0] * w[0]
                                + xw[(a + 0) * 4 + bb + 1] * w[1]
                                + xw[(a + 0) * 4 + bb + 2] * w[2]
                                + xw[(a + 1) * 4 + bb + 0] * w[3]
                                + xw[(a + 1) * 4 + bb + 1] * w[4]
                                + xw[(a + 1) * 4 + bb + 2] * w[5]
                                + xw[(a + 2) * 4 + bb + 0] * w[6]
                                + xw[(a + 2) * 4 + bb + 1] * w[7]
                                + xw[(a + 2) * 4 + bb + 2] * w[8];
                        mx = fmaxf(mx, s);
                    }
                const float val = mx + c1b[oc];
                const unsigned short h = f2bf(val);
                hb[o] = (short)h;
                lb[o] = (short)f2bf(val - bf2f(h));
            }
            *(short8v*)&s_p1h[tid * 40 + og * 8] = hb;
            *(short8v*)&s_p1l[tid * 40 + og * 8] = lb;
        }
    }
    __syncthreads();

    {
        const int oc  = tid >> 3;
        const int sub = tid & 7;
        const float* wp = c2w + oc * 288 + sub * 36;
        float wf[36];
        #pragma unroll
        for (int j = 0; j < 9; ++j)
            *(float4*)&wf[j * 4] = *(const float4*)&wp[j * 4];
        #pragma unroll
        for (int qp = 0; qp < 2; ++qp) {
            #pragma unroll
            for (int ks = 0; ks < 9; ++ks) {
                const float v0 = wf[(2 * qp) * 9 + ks];
                const float v1 = wf[(2 * qp + 1) * 9 + ks];
                const unsigned short h0 = f2bf(v0), h1 = f2bf(v1);
                const unsigned short l0 = f2bf(v0 - bf2f(h0));
                const unsigned short l1 = f2bf(v1 - bf2f(h1));
                const int idx = oc * 296 + ks * 32 + sub * 4 + 2 * qp;
                *(unsigned*)&s_wh[idx] = (unsigned)h0 | ((unsigned)h1 << 16);
                *(unsigned*)&s_wl[idx] = (unsigned)l0 | ((unsigned)l1 << 16);
            }
        }
    }
    __syncthreads();

    {
        const int lane = tid & 63;
        const int wv   = tid >> 6;
        const int jcol = lane & 15;
        const int icg8 = (lane >> 4) * 8;
        const bool live2 = (wv == 0);

        int rb[3], cb[3];
        #pragma unroll
        for (int s = 0; s < 3; ++s) {
            const int nt = wv + s * 4;
            const int n = nt * 16 + jcol;
            const int pq = n >> 2, w4 = n & 3;
            const int pi = pq / 6, pj = pq - pi * 6;
            rb[s] = 2 * pi + (w4 >> 1);
            cb[s] = 2 * pj + (w4 & 1);
        }

        f32x4 acc[3][2];
        #pragma unroll
        for (int s = 0; s < 3; ++s)
            #pragma unroll
            for (int mt = 0; mt < 2; ++mt)
                acc[s][mt] = (f32x4){0.0f, 0.0f, 0.0f, 0.0f};

        #pragma unroll
        for (int ks = 0; ks < 9; ++ks) {
            const int dr = ks / 3, dc = ks - dr * 3;
            const int ab = jcol * 296 + ks * 32 + icg8;
            const short8v ah0 = *(const short8v*)&s_wh[ab];
            const short8v ah1 = *(const short8v*)&s_wh[ab + 16 * 296];
            const short8v al0 = *(const short8v*)&s_wl[ab];
            const short8v al1 = *(const short8v*)&s_wl[ab + 16 * 296];
            #pragma unroll
            for (int s = 0; s < 3; ++s) {
                if (s == 2 && !live2) continue;
                const int boff = ((rb[s] + dr) * 15 + (cb[s] + dc)) * 40 + icg8;
                const short8v bh = *(const short8v*)&s_p1h[boff];
                const short8v bl = *(const short8v*)&s_p1l[boff];
                acc[s][0] = __builtin_amdgcn_mfma_f32_16x16x32_bf16(ah0, bh, acc[s][0], 0, 0, 0);
                acc[s][0] = __builtin_amdgcn_mfma_f32_16x16x32_bf16(al0, bh, acc[s][0], 0, 0, 0);
                acc[s][0] = __builtin_amdgcn_mfma_f32_16x16x32_bf16(ah0, bl, acc[s][0], 0, 0, 0);
                acc[s][1] = __builtin_amdgcn_mfma_f32_16x16x32_bf16(ah1, bh, acc[s][1], 0, 0, 0);
                acc[s][1] = __builtin_amdgcn_mfma_f32_16x16x32_bf16(al1, bh, acc[s][1], 0, 0, 0);
                acc[s][1] = __builtin_amdgcn_mfma_f32_16x16x32_bf16(ah1, bl, acc[s][1], 0, 0, 0);
            }
        }

        #pragma unroll
        for (int s = 0; s < 3; ++s) {
            if (s == 2 && !live2) continue;
            const int nt = wv + s * 4;
            #pragma unroll
            for (int mt = 0; mt < 2; ++mt)
                #pragma unroll
                for (int r = 0; r < 4; ++r) {
                    float v = acc[s][mt][r];
                    v = fmaxf(v, __shfl_xor(v, 1));
                    v = fmaxf(v, __shfl_xor(v, 2));
                    if ((lane & 3) == 0) {
                        const int oc = mt * 16 + (lane >> 4) * 4 + r;
                        const int pq = nt * 4 + ((lane & 15) >> 2);
                        s_s2[oc * 36 + pq] = v + s_c2b[oc];
                    }
                }
        }
    }
    __syncthreads();

    for (int i = tid; i < 576; i += 256)
        *(float4*)&s_ew[i * 4] = *(const float4*)&ew[i * 4];
    __syncthreads();

    {
        const int s  = tid >> 3;
        const int e0 = (tid & 7) * 8;
        float acc8[8];
        *(float4*)&acc8[0] = *(const float4*)&eb[e0];
        *(float4*)&acc8[4] = *(const float4*)&eb[e0 + 4];
        for (int f = 0; f < 36; ++f) {
            const float sv = s_s2[s * 36 + f];
            const float4 w0 = *(const float4*)&s_ew[f * 64 + e0];
            const float4 w1 = *(const float4*)&s_ew[f * 64 + e0 + 4];
            acc8[0] += sv * w0.x; acc8[1] += sv * w0.y;
            acc8[2] += sv * w0.z; acc8[3] += sv * w0.w;
            acc8[4] += sv * w1.x; acc8[5] += sv * w1.y;
            acc8[6] += sv * w1.z; acc8[7] += sv * w1.w;
        }
        float4 o0, o1;
        o0.x = fmaxf(acc8[0], 0.0f); o0.y = fmaxf(acc8[1], 0.0f);
        o0.z = fmaxf(acc8[2], 0.0f); o0.w = fmaxf(acc8[3], 0.0f);
        o1.x = fmaxf(acc8[4], 0.0f); o1.y = fmaxf(acc8[5], 0.0f);
        o1.z = fmaxf(acc8[6], 0.0f); o1.w = fmaxf(acc8[7], 0.0f);
        float* up = u + (size_t)p * 2048 + s * 64 + e0;
        *(float4*)up       = o0;
        *(float4*)(up + 4) = o1;
    }
}

// ---------------------------------------------------------------------------
// K2: full-MFMA attention block + LN(64) + fused XL double-LN(2048).
// Block = (m, b2). grid 4096, 256 threads (4 waves, wave = head h).
// Emits Ah/Al (bf16 hi/lo) in k_fl1's blocked fragment layout.
// MFMA convention (validated in k_fl1): D[arow][bcol] = sum_k A[arow][k]*B[bcol][k]
//   a/b frags: outdim = lane&15, k = (lane>>4)*8 + j
//   D: arow = (lane>>4)*4 + reg, bcol = lane&15
// ---------------------------------------------------------------------------
__global__ __launch_bounds__(256, 2) void k_attn(
    const float* __restrict__ u,
    const float* __restrict__ wq, const float* __restrict__ bq,
    const float* __restrict__ wk, const float* __restrict__ bk,
    const float* __restrict__ wv, const float* __restrict__ bv,
    const float* __restrict__ wo, const float* __restrict__ bo,
    const float* __restrict__ g1, const float* __restrict__ b1,
    const float* __restrict__ xg, const float* __restrict__ xb,
    unsigned short* __restrict__ Ah, unsigned short* __restrict__ Al)
{
    __shared__ __align__(16) unsigned short s_w[2][64 * 64];  // weight B-frags (swizzled)
    __shared__ __align__(16) float s_uf[32 * 68];             // residual f32
    __shared__ __align__(16) unsigned short R1[12288];        // qA|kB, then P
    __shared__ __align__(16) unsigned short R2[5632];         // vT, then O
    __shared__ float s_red[2][32][2];
    __shared__ float s_red2[2][4][2];

    unsigned short* qA_h = R1;             // [4][32][24]
    unsigned short* qA_l = R1 + 3072;
    unsigned short* kB_h = R1 + 6144;
    unsigned short* kB_l = R1 + 9216;
    unsigned short* p_h  = R1;             // [4][32][40] (aliases qA/kB)
    unsigned short* p_l  = R1 + 5120;
    unsigned short* vT_h = R2;             // [4][16][40]
    unsigned short* vT_l = R2 + 2560;
    unsigned short* oA_h = R2;             // [32][88] (aliases vT)
    unsigned short* oA_l = R2 + 2816;

    const int g   = blockIdx.x;
    const int m   = g >> 8;
    const int b2  = g & 255;
    const int tid = threadIdx.x;
    const int l   = tid & 63;
    const int w   = tid >> 6;       // wave = head for attention phases
    const int l15 = l & 15;
    const int lg  = l >> 4;

    // ---- P0: stage u (f32) ----
    {
        const int s = tid >> 3, dq = (tid & 7) * 8;
        const float* up = u + (size_t)g * 2048 + s * 64 + dq;
        *(float4*)&s_uf[s * 68 + dq]     = *(const float4*)up;
        *(float4*)&s_uf[s * 68 + dq + 4] = *(const float4*)(up + 4);
    }

    // weight staging roles
    const int wn  = tid & 63;   // output col n
    const int wkq = tid >> 6;   // k quarter (16 d each)
    float wreg[16];

    #define LOADQKV(SRC)                                                          \
        {                                                                         \
            const float* sp = (SRC) + (size_t)m * 4096 + (wn >> 4) * 1024 + (wn & 15); \
            _Pragma("unroll")                                                     \
            for (int j = 0; j < 16; ++j) wreg[j] = sp[(wkq * 16 + j) * 16];       \
        }
    #define LOADO(SRC)                                                            \
        {                                                                         \
            const float* sp = (SRC) + (size_t)m * 4096 + wn;                      \
            _Pragma("unroll")                                                     \
            for (int j = 0; j < 16; ++j) wreg[j] = sp[(wkq * 16 + j) * 64];       \
        }
    #define WRITEW()                                                              \
        {                                                                         \
            _Pragma("unroll")                                                     \
            for (int j2 = 0; j2 < 8; ++j2) {                                      \
                const int d = wkq * 16 + j2 * 2;                                  \
                const float v0 = wreg[j2 * 2], v1 = wreg[j2 * 2 + 1];             \
                const unsigned short h0 = f2bf(v0), h1 = f2bf(v1);                \
                const unsigned short q0 = f2bf(v0 - bf2f(h0));                    \
                const unsigned short q1 = f2bf(v1 - bf2f(h1));                    \
                const int idx = wn * 64 + (((d >> 3) ^ (wn & 7)) << 3) + (d & 7); \
                *(unsigned*)&s_w[0][idx] = (unsigned)h0 | ((unsigned)h1 << 16);   \
                *(unsigned*)&s_w[1][idx] = (unsigned)q0 | ((unsigned)q1 << 16);   \
            }                                                                     \
        }

    LOADQKV(wq);
    __syncthreads();                 // u staged
    WRITEW();                        // Wq -> s_w

    // U A-frags (reused for q,k,v projections)
    short8v uh[2][2], ul[2][2];
    #pragma unroll
    for (int mf = 0; mf < 2; ++mf)
        #pragma unroll
        for (int ks = 0; ks < 2; ++ks) {
            const float* pb = &s_uf[(mf * 16 + l15) * 68 + (ks * 4 + lg) * 8];
            float xv[8];
            *(float4*)&xv[0] = *(const float4*)pb;
            *(float4*)&xv[4] = *(const float4*)(pb + 4);
            short8v hh, ll;
            #pragma unroll
            for (int j = 0; j < 8; ++j) {
                const unsigned short h = f2bf(xv[j]);
                hh[j] = (short)h;
                ll[j] = (short)f2bf(xv[j] - bf2f(h));
            }
            uh[mf][ks] = hh; ul[mf][ks] = ll;
        }
    __syncthreads();                 // Wq in LDS

    // ---- projection phase: mode 0=Q, 1=K, 2=V ----
    #define PROJ(BIAS, MODE)                                                      \
        {                                                                         \
            short8v wbh[2], wbl[2];                                               \
            const int bn = w * 16 + l15;                                          \
            _Pragma("unroll")                                                     \
            for (int ks = 0; ks < 2; ++ks) {                                      \
                const int off = bn * 64 + (((ks * 4 + lg) ^ (bn & 7)) << 3);      \
                wbh[ks] = *(const short8v*)&s_w[0][off];                          \
                wbl[ks] = *(const short8v*)&s_w[1][off];                          \
            }                                                                     \
            const float bias_v = (BIAS)[m * 64 + bn];                             \
            f32x4 a0 = {0,0,0,0}, a1 = {0,0,0,0};                                 \
            _Pragma("unroll")                                                     \
            for (int ks = 0; ks < 2; ++ks) {                                      \
                MFMA3(a0, uh[0][ks], ul[0][ks], wbh[ks], wbl[ks]);                \
                MFMA3(a1, uh[1][ks], ul[1][ks], wbh[ks], wbl[ks]);                \
            }                                                                     \
            _Pragma("unroll")                                                     \
            for (int mf = 0; mf < 2; ++mf) {                                      \
                const f32x4 av = mf ? a1 : a0;                                    \
                _Pragma("unroll")                                                 \
                for (int r = 0; r < 4; ++r) {                                     \
                    const float val = av[r] + bias_v;                             \
                    const unsigned short hh = f2bf(val);                          \
                    const unsigned short lo = f2bf(val - bf2f(hh));               \
                    const int srow = mf * 16 + lg * 4 + r;                        \
                    if ((MODE) == 0) { const int ix = w * 768 + srow * 24 + l15;  \
                        qA_h[ix] = hh; qA_l[ix] = lo; }                           \
                    else if ((MODE) == 1) { const int ix = w * 768 + srow * 24 + l15; \
                        kB_h[ix] = hh; kB_l[ix] = lo; }                           \
                    else { const int ix = w * 640 + l15 * 40 + srow;              \
                        vT_h[ix] = hh; vT_l[ix] = lo; }                           \
                }                                                                 \
            }                                                                     \
        }

    PROJ(bq, 0);
    LOADQKV(wk);
    __syncthreads();
    WRITEW();
    __syncthreads();

    PROJ(bk, 1);
    LOADQKV(wv);
    __syncthreads();
    WRITEW();
    __syncthreads();

    PROJ(bv, 2);
    LOADO(wo);
    __syncthreads();
    WRITEW();                        // Wo -> s_w (read in o-proj)
    __syncthreads();

    // ---- scores + in-register softmax (wave = head w) ----
    float pvreg[2][2][4];
    {
        const short8v zz = {0,0,0,0,0,0,0,0};
        short8v qh[2], ql[2], kh[2], kl[2];
        const bool kreal = (lg < 2);
        #pragma unroll
        for (int mf = 0; mf < 2; ++mf) {
            if (kreal) {
                const int ia = w * 768 + (mf * 16 + l15) * 24 + lg * 8;
                qh[mf] = *(const short8v*)&qA_h[ia];
                ql[mf] = *(const short8v*)&qA_l[ia];
                kh[mf] = *(const short8v*)&kB_h[ia];
                kl[mf] = *(const short8v*)&kB_l[ia];
            } else { qh[mf] = zz; ql[mf] = zz; kh[mf] = zz; kl[mf] = zz; }
        }
        f32x4 sc[2][2];
        #pragma unroll
        for (int mf = 0; mf < 2; ++mf)
            #pragma unroll
            for (int nf = 0; nf < 2; ++nf) {
                sc[mf][nf] = (f32x4){0,0,0,0};
                MFMA3(sc[mf][nf], qh[mf], ql[mf], kh[nf], kl[nf]);
            }
        #pragma unroll
        for (int mf = 0; mf < 2; ++mf)
            #pragma unroll
            for (int r = 0; r < 4; ++r) {
                const float v0 = sc[mf][0][r] * 0.25f;
                const float v1 = sc[mf][1][r] * 0.25f;
                float mx = fmaxf(v0, v1);
                mx = fmaxf(mx, __shfl_xor(mx, 1));
                mx = fmaxf(mx, __shfl_xor(mx, 2));
                mx = fmaxf(mx, __shfl_xor(mx, 4));
                mx = fmaxf(mx, __shfl_xor(mx, 8));
                const float e0 = expf(v0 - mx), e1 = expf(v1 - mx);
                float sm = e0 + e1;
                sm += __shfl_xor(sm, 1);
                sm += __shfl_xor(sm, 2);
                sm += __shfl_xor(sm, 4);
                sm += __shfl_xor(sm, 8);
                const float inv = 1.0f / sm;
                pvreg[mf][0][r] = e0 * inv;
                pvreg[mf][1][r] = e1 * inv;
            }
    }
    __syncthreads();                 // all reads of qA/kB complete

    // write P (hi/lo) into aliased region
    #pragma unroll
    for (int mf = 0; mf < 2; ++mf)
        #pragma unroll
        for (int nf = 0; nf < 2; ++nf)
            #pragma unroll
            for (int r = 0; r < 4; ++r) {
                const int srow = mf * 16 + lg * 4 + r;
                const int tt = nf * 16 + l15;
                const int ix = w * 1280 + srow * 40 + tt;
                const float val = pvreg[mf][nf][r];
                const unsigned short hh = f2bf(val);
                p_h[ix] = hh;
                p_l[ix] = f2bf(val - bf2f(hh));
            }
    __syncthreads();

    // ---- PV ----
    f32x4 ov[2];
    {
        short8v ph[2], pl[2], vh_, vl_;
        #pragma unroll
        for (int mf = 0; mf < 2; ++mf) {
            const int ix = w * 1280 + (mf * 16 + l15) * 40 + lg * 8;
            ph[mf] = *(const short8v*)&p_h[ix];
            pl[mf] = *(const short8v*)&p_l[ix];
        }
        const int iv = w * 640 + l15 * 40 + lg * 8;
        vh_ = *(const short8v*)&vT_h[iv];
        vl_ = *(const short8v*)&vT_l[iv];
        #pragma unroll
        for (int mf = 0; mf < 2; ++mf) {
            ov[mf] = (f32x4){0,0,0,0};
            MFMA3(ov[mf], ph[mf], pl[mf], vh_, vl_);
        }
    }
    __syncthreads();                 // vT reads complete

    // write O (hi/lo) [32][88] into aliased region
    #pragma unroll
    for (int mf = 0; mf < 2; ++mf)
        #pragma unroll
        for (int r = 0; r < 4; ++r) {
            const int srow = mf * 16 + lg * 4 + r;
            const int dd = w * 16 + l15;
            const int ix = srow * 88 + dd;
            const float val = ov[mf][r];
            const unsigned short hh = f2bf(val);
            oA_h[ix] = hh;
            oA_l[ix] = f2bf(val - bf2f(hh));
        }
    __syncthreads();

    // ---- o-proj + bias + residual + LN(64) ----
    const int mfA = w >> 1;
    const int nfb = (w & 1) * 2;
    float x[2][4];
    {
        short8v oh[2], ol[2];
        #pragma unroll
        for (int ks = 0; ks < 2; ++ks) {
            const int ix = (mfA * 16 + l15) * 88 + (ks * 4 + lg) * 8;
            oh[ks] = *(const short8v*)&oA_h[ix];
            ol[ks] = *(const short8v*)&oA_l[ix];
        }
        #pragma unroll
        for (int nfi = 0; nfi < 2; ++nfi) {
            const int n = (nfb + nfi) * 16 + l15;
            f32x4 xe = {0,0,0,0};
            #pragma unroll
            for (int ks = 0; ks < 2; ++ks) {
                const int off = n * 64 + (((ks * 4 + lg) ^ (n & 7)) << 3);
                const short8v wbh = *(const short8v*)&s_w[0][off];
                const short8v wbl = *(const short8v*)&s_w[1][off];
                MFMA3(xe, oh[ks], ol[ks], wbh, wbl);
            }
            const int e = n;
            const float bo_v = bo[m * 64 + e];
            #pragma unroll
            for (int r = 0; r < 4; ++r) {
                const int srow = mfA * 16 + lg * 4 + r;
                x[nfi][r] = xe[r] + bo_v + s_uf[srow * 68 + e];
            }
        }
    }
    // LN64 partials (this wave covers e-half (w&1) of rows mfA*16..+15)
    #pragma unroll
    for (int r = 0; r < 4; ++r) {
        float s1 = x[0][r] + x[1][r];
        float s2 = x[0][r] * x[0][r] + x[1][r] * x[1][r];
        s1 += __shfl_xor(s1, 1); s2 += __shfl_xor(s2, 1);
        s1 += __shfl_xor(s1, 2); s2 += __shfl_xor(s2, 2);
        s1 += __shfl_xor(s1, 4); s2 += __shfl_xor(s2, 4);
        s1 += __shfl_xor(s1, 8); s2 += __shfl_xor(s2, 8);
        if (l15 == 0) {
            const int srow = mfA * 16 + lg * 4 + r;
            s_red[w & 1][srow][0] = s1;
            s_red[w & 1][srow][1] = s2;
        }
    }
    __syncthreads();

    float q2[2][4];
    #pragma unroll
    for (int r = 0; r < 4; ++r) {
        const int srow = mfA * 16 + lg * 4 + r;
        const float sum = s_red[0][srow][0] + s_red[1][srow][0];
        const float ssq = s_red[0][srow][1] + s_red[1][srow][1];
        const float mean = sum * (1.0f / 64.0f);
        const float var = fmaxf(ssq * (1.0f / 64.0f) - mean * mean, 0.0f);
        const float inv = rsqrtf(var + LN_EPS);
        #pragma unroll
        for (int nfi = 0; nfi < 2; ++nfi) {
            const int e = (nfb + nfi) * 16 + l15;
            const float y = (x[nfi][r] - mean) * inv * g1[e] + b1[e];
            q2[nfi][r] = 2.0f * y;     // u = u + u before first XL LN
        }
    }

    // ---- fused XL double-LN over the full 2048 row ----
    #pragma unroll
    for (int L = 0; L < 2; ++L) {
        float ls = 0.0f, lq = 0.0f;
        #pragma unroll
        for (int nfi = 0; nfi < 2; ++nfi)
            #pragma unroll
            for (int r = 0; r < 4; ++r) { ls += q2[nfi][r]; lq += q2[nfi][r] * q2[nfi][r]; }
        ls += __shfl_xor(ls, 1);  lq += __shfl_xor(lq, 1);
        ls += __shfl_xor(ls, 2);  lq += __shfl_xor(lq, 2);
        ls += __shfl_xor(ls, 4);  lq += __shfl_xor(lq, 4);
        ls += __shfl_xor(ls, 8);  lq += __shfl_xor(lq, 8);
        ls += __shfl_xor(ls, 16); lq += __shfl_xor(lq, 16);
        ls += __shfl_xor(ls, 32); lq += __shfl_xor(lq, 32);
        if (l == 0) { s_red2[L][w][0] = ls; s_red2[L][w][1] = lq; }
        __syncthreads();
        const float sum = s_red2[L][0][0] + s_red2[L][1][0] + s_red2[L][2][0] + s_red2[L][3][0];
        const float ssq = s_red2[L][0][1] + s_red2[L][1][1] + s_red2[L][2][1] + s_red2[L][3][1];
        const float mean = sum * (1.0f / 2048.0f);
        const float var = fmaxf(ssq * (1.0f / 2048.0f) - mean * mean, 0.0f);
        const float inv = rsqrtf(var + LN_EPS);
        #pragma unroll
        for (int nfi = 0; nfi < 2; ++nfi)
            #pragma unroll
            for (int r = 0; r < 4; ++r) {
                const int srow = mfA * 16 + lg * 4 + r;
                const int e = (nfb + nfi) * 16 + l15;
                const int col = srow * 64 + e;
                const float z = (q2[nfi][r] - mean) * inv * xg[L * 2048 + col] + xb[L * 2048 + col];
                q2[nfi][r] = (L == 0) ? 2.0f * z : z;
            }
    }

    // ---- emit bf16 hi/lo in fl1's blocked layout ----
    #pragma unroll
    for (int nfi = 0; nfi < 2; ++nfi)
        #pragma unroll
        for (int r = 0; r < 4; ++r) {
            const int srow = mfA * 16 + lg * 4 + r;
            const int e = (nfb + nfi) * 16 + l15;
            const int col = srow * 64 + e;
            const float val = q2[nfi][r];
            const unsigned short hh = f2bf(val);
            const size_t addr = ((size_t)(m * 64 + (col >> 5)) * 256 + b2) * 32 + (col & 31);
            Ah[addr] = hh;
            Al[addr] = f2bf(val - bf2f(hh));
        }
}

// ---------------------------------------------------------------------------
// K4: fl1 MFMA GEMM, 3-term bf16 hi/lo split (unchanged)
// ---------------------------------------------------------------------------
__global__ __launch_bounds__(512) void k_fl1(
    const unsigned short* __restrict__ Ah,
    const unsigned short* __restrict__ Al,
    const float* __restrict__ W,
    float* __restrict__ part)
{
    __shared__ __align__(16) unsigned short s_wh[128 * 64];
    __shared__ __align__(16) unsigned short s_wl[128 * 64];

    const int nb  = blockIdx.x;
    const int kb  = blockIdx.y;
    const int tid = threadIdx.x;
    const int lane = tid & 63;
    const int wid  = tid >> 6;
    const int wm = wid >> 1;
    const int wn = wid & 1;

    const int sn = tid & 127;
    const int sq = tid >> 7;
    const int k0 = kb * 512;

    f32x4 acc[4][4];
    #pragma unroll
    for (int i = 0; i < 4; ++i)
        #pragma unroll
        for (int j = 0; j < 4; ++j)
            acc[i][j] = (f32x4){0.0f, 0.0f, 0.0f, 0.0f};

    float wreg[16];
    {
        const float* wp = W + (size_t)(k0 + sq * 16) * 512 + nb * 128 + sn;
        #pragma unroll
        for (int j = 0; j < 16; ++j) wreg[j] = wp[(size_t)j * 512];
    }

    const int hsn = sn & 7;
    const int wbase = sn * 64;
    const int wo0 = (((sq * 2) ^ hsn) << 3);
    const int wo1 = (((sq * 2 + 1) ^ hsn) << 3);

    for (int tt = 0; tt < 8; ++tt) {
        __syncthreads();
        {
            short8v h0, h1, l0, l1;
            #pragma unroll
            for (int j = 0; j < 8; ++j) {
                const unsigned short ha = f2bf(wreg[j]);
                const unsigned short hb = f2bf(wreg[j + 8]);
                h0[j] = (short)ha;
                h1[j] = (short)hb;
                l0[j] = (short)f2bf(wreg[j] - bf2f(ha));
                l1[j] = (short)f2bf(wreg[j + 8] - bf2f(hb));
            }
            *(short8v*)&s_wh[wbase + wo0] = h0;
            *(short8v*)&s_wh[wbase + wo1] = h1;
            *(short8v*)&s_wl[wbase + wo0] = l0;
            *(short8v*)&s_wl[wbase + wo1] = l1;
        }
        if (tt < 7) {
            const float* wp = W + (size_t)(k0 + (tt + 1) * 64 + sq * 16) * 512 + nb * 128 + sn;
            #pragma unroll
            for (int j = 0; j < 16; ++j) wreg[j] = wp[(size_t)j * 512];
        }
        __syncthreads();

        #pragma unroll
        for (int ks = 0; ks < 2; ++ks) {
            const int ktile = (k0 >> 5) + tt * 2 + ks;
            const size_t abase = ((size_t)ktile * 256 + wm * 64 + (lane & 15)) * 32
                               + (lane >> 4) * 8;
            short8v ahf[4], alf[4];
            #pragma unroll
            for (int mf = 0; mf < 4; ++mf) {
                ahf[mf] = *(const short8v*)&Ah[abase + (size_t)mf * 512];
                alf[mf] = *(const short8v*)&Al[abase + (size_t)mf * 512];
            }
            short8v bhf[4], blf[4];
            #pragma unroll
            for (int nf = 0; nf < 4; ++nf) {
                const int n = wn * 64 + nf * 16 + (lane & 15);
                const int q = ks * 4 + (lane >> 4);
                const int baddr = n * 64 + ((q ^ (n & 7)) << 3);
                bhf[nf] = *(const short8v*)&s_wh[baddr];
                blf[nf] = *(const short8v*)&s_wl[baddr];
            }
            #pragma unroll
            for (int mf = 0; mf < 4; ++mf)
                #pragma unroll
                for (int nf = 0; nf < 4; ++nf) {
                    MFMA3(acc[mf][nf], ahf[mf], alf[mf], bhf[nf], blf[nf]);
                }
        }
    }

    float* pp = part + (size_t)kb * 131072 + (size_t)nb * 128;
    const int r0 = (lane >> 4) * 4;
    const int c  = lane & 15;
    #pragma unroll
    for (int mf = 0; mf < 4; ++mf) {
        const int row = wm * 64 + mf * 16 + r0;
        #pragma unroll
        for (int nf = 0; nf < 4; ++nf) {
            const int col = wn * 64 + nf * 16 + c;
            #pragma unroll
            for (int r = 0; r < 4; ++r)
                pp[(size_t)(row + r) * 512 + col] = acc[mf][nf][r];
        }
    }
}

__global__ __launch_bounds__(256) void k_fl1red(
    const float* __restrict__ part, const float* __restrict__ bias,
    float* __restrict__ out1)
{
    const int i4 = (blockIdx.x * 256 + threadIdx.x) * 4;
    float4 s = *(const float4*)&bias[i4 & 511];
    for (int ks = 0; ks < 64; ++ks) {
        const float4 p = *(const float4*)&part[(size_t)ks * 131072 + i4];
        s.x += p.x; s.y += p.y; s.z += p.z; s.w += p.w;
    }
    s.x = fmaxf(s.x, 0.0f); s.y = fmaxf(s.y, 0.0f);
    s.z = fmaxf(s.z, 0.0f); s.w = fmaxf(s.w, 0.0f);
    *(float4*)&out1[i4] = s;
}

__global__ __launch_bounds__(128) void k_fl2(
    const float* __restrict__ u1, const float* __restrict__ w,
    const float* __restrict__ b, float* __restrict__ out2)
{
    __shared__ float s_u[512];
    const int r = blockIdx.x, tid = threadIdx.x;
    for (int i = tid; i < 512; i += 128) s_u[i] = u1[r * 512 + i];
    __syncthreads();
    float acc = b[tid];
    for (int k = 0; k < 512; k++) acc += s_u[k] * w[k * 128 + tid];
    out2[r * 128 + tid] = fmaxf(acc, 0.0f);
}

__global__ __launch_bounds__(128) void k_fl3(
    const float* __restrict__ u2_, const float* __restrict__ w,
    const float* __restrict__ b, float* __restrict__ out)
{
    __shared__ float s_u[128];
    const int r = blockIdx.x, tid = threadIdx.x;
    s_u[tid] = u2_[r * 128 + tid];
    __syncthreads();
    if (tid < 25) {
        float acc = b[tid];
        for (int k = 0; k < 128; k++) acc += s_u[k] * w[k * 25 + tid];
        out[r * 25 + tid] = acc;
    }
}

// ---------------------------------------------------------------------------
extern "C" void kernel_launch(void* const* d_in, const int* in_sizes, int n_in,
                              void* d_out, int out_size, void* d_ws, size_t ws_size,
                              hipStream_t stream)
{
    const float* t      = (const float*)d_in[0];
    const float* c1w    = (const float*)d_in[1];
    const float* c1b    = (const float*)d_in[2];
    const float* c2w    = (const float*)d_in[3];
    const float* c2b    = (const float*)d_in[4];
    const float* ew     = (const float*)d_in[5];
    const float* eb     = (const float*)d_in[6];
    const float* mh_wq  = (const float*)d_in[7];
    const float* mh_bq  = (const float*)d_in[8];
    const float* mh_wk  = (const float*)d_in[9];
    const float* mh_bk  = (const float*)d_in[10];
    const float* mh_wv  = (const float*)d_in[11];
    const float* mh_bv  = (const float*)d_in[12];
    const float* mh_wo  = (const float*)d_in[13];
    const float* mh_bo  = (const float*)d_in[14];
    const float* ln1_g  = (const float*)d_in[15];
    const float* ln1_b  = (const float*)d_in[16];
    // d_in[17..24]: XL attention weights -- dead code in the reference, unused
    const float* xln_g  = (const float*)d_in[25];
    const float* xln_b  = (const float*)d_in[26];
    const float* fl1_w  = (const float*)d_in[27];
    const float* fl1_b  = (const float*)d_in[28];
    const float* fl2_w  = (const float*)d_in[29];
    const float* fl2_b  = (const float*)d_in[30];
    const float* fl3_w  = (const float*)d_in[31];
    const float* fl3_b  = (const float*)d_in[32];
    (void)in_sizes; (void)n_in; (void)out_size; (void)ws_size;

    float* U   = (float*)d_ws;                 // conv u (f32); later PART, OUT2
    float* U2  = U + 8388608;                  // Ah/Al; later OUT1
    unsigned short* Ah = (unsigned short*)U2;
    unsigned short* Al = Ah + 8388608;
    float* PART = U;                           // u dead after k_attn
    float* OUT1 = U2;                          // Ah/Al dead after k_fl1
    float* OUT2 = U;                           // PART dead after k_fl1red
    float* out  = (float*)d_out;

    k_conv<<<4096, 256, 0, stream>>>(t, c1w, c1b, c2w, c2b, ew, eb, U);
    k_attn<<<4096, 256, 0, stream>>>(U, mh_wq, mh_bq, mh_wk, mh_bk, mh_wv, mh_bv,
                                     mh_wo, mh_bo, ln1_g, ln1_b, xln_g, xln_b,
                                     Ah, Al);
    k_fl1<<<dim3(4, 64), 512, 0, stream>>>(Ah, Al, fl1_w, PART);
    k_fl1red<<<128, 256, 0, stream>>>(PART, fl1_b, OUT1);
    k_fl2<<<256, 128, 0, stream>>>(OUT1, fl2_w, fl2_b, OUT2);
    k_fl3<<<256, 128, 0, stream>>>(OUT2, fl3_w, fl3_b, out);
}

// Round 7
// 286.724 us; speedup vs baseline: 9.2600x; 1.0259x over previous
//
#include <hip/hip_runtime.h>
#include <hip/hip_bf16.h>
#include <math.h>

#define LN_EPS 1e-5f

typedef __attribute__((ext_vector_type(8))) short short8v;
typedef __attribute__((ext_vector_type(4))) float f32x4;

static __device__ __forceinline__ unsigned short f2bf(float x) {
    unsigned u = __float_as_uint(x);
    u += 0x7fffu + ((u >> 16) & 1u);
    return (unsigned short)(u >> 16);
}
static __device__ __forceinline__ float bf2f(unsigned short h) {
    return __uint_as_float(((unsigned)h) << 16);
}

#define MFMA3(ACC, AH, AL, BH, BL)                                          \
    ACC = __builtin_amdgcn_mfma_f32_16x16x32_bf16(AH, BH, ACC, 0, 0, 0);    \
    ACC = __builtin_amdgcn_mfma_f32_16x16x32_bf16(AL, BH, ACC, 0, 0, 0);    \
    ACC = __builtin_amdgcn_mfma_f32_16x16x32_bf16(AH, BL, ACC, 0, 0, 0);

// ---------------------------------------------------------------------------
// K1: per-patch conv1+pool -> conv2 (MFMA im2col) + shfl-pool -> expansion.
// 512 threads (8 waves), 2 blocks/CU -> 4 waves/SIMD. Numerics bit-identical
// to the 256-thread round-5 version (same per-output op order everywhere).
// ---------------------------------------------------------------------------
__global__ __launch_bounds__(512, 4) void k_conv(
    const float* __restrict__ t,
    const float* __restrict__ c1w, const float* __restrict__ c1b,
    const float* __restrict__ c2w, const float* __restrict__ c2b,
    const float* __restrict__ ew,  const float* __restrict__ eb,
    float* __restrict__ u)
{
    __shared__ __align__(16) unsigned short s_W2[2][32 * 296];  // 37888 B
    __shared__ __align__(16) unsigned short s_p1h[225 * 40];    // 18000 B
    __shared__ __align__(16) unsigned short s_p1l[225 * 40];    // 18000 B
    __shared__ __align__(16) float s_s2[32 * 36];               // 4608 B
    __shared__ float s_c2b[32];

    float* s_x  = (float*)s_W2;       // [32][33] during phase A
    float* s_ew = (float*)s_p1h;      // [36*64] during phase C (p1 dead)
    unsigned short* s_wh = s_W2[0];
    unsigned short* s_wl = s_W2[1];

    const int p   = blockIdx.x;
    const int tid = threadIdx.x;      // 0..511

    // ---- stage input patch (scaled) + c2b ----
    const int b = p >> 4, tile = p & 15, tr = tile >> 2, tc = tile & 3;
    const float* tp = t + (size_t)b * 128 * 128 + (size_t)tr * 32 * 128 + tc * 32;
    for (int i = tid; i < 1024; i += 512) {
        const int r = i >> 5, c = i & 31;
        s_x[r * 33 + c] = tp[r * 128 + c] * (1.0f / 255.0f);
    }
    if (tid < 32) s_c2b[tid] = c2b[tid];
    __syncthreads();

    // ---- phase A: conv1 (1->32, 3x3) + pool -> p1[pos15][ic] bf16 hi/lo ----
    // 450 threads: 2 per position, 16 ocs each (2 og groups of 8).
    if (tid < 450) {
        const int pos  = tid >> 1;
        const int half = tid & 1;
        const int pi = pos / 15, pj = pos % 15;
        float xw[16];
        #pragma unroll
        for (int r = 0; r < 4; ++r)
            #pragma unroll
            for (int c = 0; c < 4; ++c)
                xw[r * 4 + c] = s_x[(2 * pi + r) * 33 + (2 * pj + c)];
        #pragma unroll
        for (int og2 = 0; og2 < 2; ++og2) {
            const int og = half * 2 + og2;
            short8v hb, lb;
            #pragma unroll
            for (int o = 0; o < 8; ++o) {
                const int oc = og * 8 + o;
                float w[9];
                #pragma unroll
                for (int j = 0; j < 9; ++j) w[j] = c1w[oc * 9 + j];
                float mx = -3.0e38f;
                #pragma unroll
                for (int a = 0; a < 2; ++a)
                    #pragma unroll
                    for (int bb = 0; bb < 2; ++bb) {
                        float s = xw[(a + 0) * 4 + bb + 0] * w[0]
                                + xw[(a + 0) * 4 + bb + 1] * w[1]
                                + xw[(a + 0) * 4 + bb + 2] * w[2]
                                + xw[(a + 1) * 4 + bb + 0] * w[3]
                                + xw[(a + 1) * 4 + bb + 1] * w[4]
                                + xw[(a + 1) * 4 + bb + 2] * w[5]
                                + xw[(a + 2) * 4 + bb + 0] * w[6]
                                + xw[(a + 2) * 4 + bb + 1] * w[7]
                                + xw[(a + 2) * 4 + bb + 2] * w[8];
                        mx = fmaxf(mx, s);
                    }
                const float val = mx + c1b[oc];
                const unsigned short h = f2bf(val);
                hb[o] = (short)h;
                lb[o] = (short)f2bf(val - bf2f(h));
            }
            *(short8v*)&s_p1h[pos * 40 + og * 8] = hb;
            *(short8v*)&s_p1l[pos * 40 + og * 8] = lb;
        }
    }
    __syncthreads();

    // ---- stage c2w -> s_wh/s_wl [oc][296], k=(dr*3+dc)*32+ic (overwrites s_x) ----
    // 512 threads: (oc, sub) with sub owning 2 ic.
    {
        const int oc  = tid >> 4;
        const int sub = tid & 15;
        const float* wp = c2w + oc * 288 + sub * 18;
        float wf[18];
        #pragma unroll
        for (int j = 0; j < 9; ++j)
            *(float2*)&wf[j * 2] = *(const float2*)&wp[j * 2];
        #pragma unroll
        for (int ks = 0; ks < 9; ++ks) {
            const float v0 = wf[ks];          // ic = sub*2
            const float v1 = wf[9 + ks];      // ic = sub*2+1
            const unsigned short h0 = f2bf(v0), h1 = f2bf(v1);
            const unsigned short l0 = f2bf(v0 - bf2f(h0));
            const unsigned short l1 = f2bf(v1 - bf2f(h1));
            const int idx = oc * 296 + ks * 32 + sub * 2;
            *(unsigned*)&s_wh[idx] = (unsigned)h0 | ((unsigned)h1 << 16);
            *(unsigned*)&s_wl[idx] = (unsigned)l0 | ((unsigned)l1 << 16);
        }
    }
    __syncthreads();

    // ---- phase B: conv2 via MFMA + in-register 2x2 pool ----
    // 9 col-tiles: wave w owns tile w (both oc-halves); tile 8 split: wave0
    // takes mt=0, wave1 takes mt=1. MFMA chain order per output unchanged.
    {
        const int lane = tid & 63;
        const int w8   = tid >> 6;        // 0..7
        const int jcol = lane & 15;
        const int icg8 = (lane >> 4) * 8;

        // primary tile
        {
            const int nt = w8;
            const int n = nt * 16 + jcol;
            const int pq = n >> 2, w4 = n & 3;
            const int pi = pq / 6, pj = pq - pi * 6;
            const int rbase = 2 * pi + (w4 >> 1);
            const int cbase = 2 * pj + (w4 & 1);

            f32x4 acc0 = {0,0,0,0}, acc1 = {0,0,0,0};
            #pragma unroll
            for (int ks = 0; ks < 9; ++ks) {
                const int dr = ks / 3, dc = ks - dr * 3;
                const int ab = jcol * 296 + ks * 32 + icg8;
                const short8v ah0 = *(const short8v*)&s_wh[ab];
                const short8v ah1 = *(const short8v*)&s_wh[ab + 16 * 296];
                const short8v al0 = *(const short8v*)&s_wl[ab];
                const short8v al1 = *(const short8v*)&s_wl[ab + 16 * 296];
                const int boff = ((rbase + dr) * 15 + (cbase + dc)) * 40 + icg8;
                const short8v bh = *(const short8v*)&s_p1h[boff];
                const short8v bl = *(const short8v*)&s_p1l[boff];
                acc0 = __builtin_amdgcn_mfma_f32_16x16x32_bf16(ah0, bh, acc0, 0, 0, 0);
                acc0 = __builtin_amdgcn_mfma_f32_16x16x32_bf16(al0, bh, acc0, 0, 0, 0);
                acc0 = __builtin_amdgcn_mfma_f32_16x16x32_bf16(ah0, bl, acc0, 0, 0, 0);
                acc1 = __builtin_amdgcn_mfma_f32_16x16x32_bf16(ah1, bh, acc1, 0, 0, 0);
                acc1 = __builtin_amdgcn_mfma_f32_16x16x32_bf16(al1, bh, acc1, 0, 0, 0);
                acc1 = __builtin_amdgcn_mfma_f32_16x16x32_bf16(ah1, bl, acc1, 0, 0, 0);
            }
            #pragma unroll
            for (int mt = 0; mt < 2; ++mt)
                #pragma unroll
                for (int r = 0; r < 4; ++r) {
                    float v = (mt == 0) ? acc0[r] : acc1[r];
                    v = fmaxf(v, __shfl_xor(v, 1));
                    v = fmaxf(v, __shfl_xor(v, 2));
                    if ((lane & 3) == 0) {
                        const int oc = mt * 16 + (lane >> 4) * 4 + r;
                        const int pq2 = nt * 4 + (jcol >> 2);
                        s_s2[oc * 36 + pq2] = v + s_c2b[oc];
                    }
                }
        }

        // extra tile 8 for waves 0,1 (mt = w8)
        if (w8 < 2) {
            const int nt = 8;
            const int mt = w8;
            const int n = nt * 16 + jcol;
            const int pq = n >> 2, w4 = n & 3;
            const int pi = pq / 6, pj = pq - pi * 6;
            const int rbase = 2 * pi + (w4 >> 1);
            const int cbase = 2 * pj + (w4 & 1);

            f32x4 accX = {0,0,0,0};
            #pragma unroll
            for (int ks = 0; ks < 9; ++ks) {
                const int dr = ks / 3, dc = ks - dr * 3;
                const int ab = jcol * 296 + ks * 32 + icg8 + mt * 16 * 296;
                const short8v ah = *(const short8v*)&s_wh[ab];
                const short8v al = *(const short8v*)&s_wl[ab];
                const int boff = ((rbase + dr) * 15 + (cbase + dc)) * 40 + icg8;
                const short8v bh = *(const short8v*)&s_p1h[boff];
                const short8v bl = *(const short8v*)&s_p1l[boff];
                accX = __builtin_amdgcn_mfma_f32_16x16x32_bf16(ah, bh, accX, 0, 0, 0);
                accX = __builtin_amdgcn_mfma_f32_16x16x32_bf16(al, bh, accX, 0, 0, 0);
                accX = __builtin_amdgcn_mfma_f32_16x16x32_bf16(ah, bl, accX, 0, 0, 0);
            }
            #pragma unroll
            for (int r = 0; r < 4; ++r) {
                float v = accX[r];
                v = fmaxf(v, __shfl_xor(v, 1));
                v = fmaxf(v, __shfl_xor(v, 2));
                if ((lane & 3) == 0) {
                    const int oc = mt * 16 + (lane >> 4) * 4 + r;
                    const int pq2 = nt * 4 + (jcol >> 2);
                    s_s2[oc * 36 + pq2] = v + s_c2b[oc];
                }
            }
        }
    }
    __syncthreads();

    // ---- stage ew into s_ew (aliases dead p1) ----
    for (int i = tid; i < 576; i += 512)
        *(float4*)&s_ew[i * 4] = *(const float4*)&ew[i * 4];
    __syncthreads();

    // ---- phase C: expansion relu(s2(32x36) @ ew(36x64) + eb), 4 out/thread ----
    {
        const int s  = tid >> 4;
        const int e0 = (tid & 15) * 4;
        float acc4[4];
        *(float4*)&acc4[0] = *(const float4*)&eb[e0];
        for (int f = 0; f < 36; ++f) {
            const float sv = s_s2[s * 36 + f];
            const float4 w0 = *(const float4*)&s_ew[f * 64 + e0];
            acc4[0] += sv * w0.x; acc4[1] += sv * w0.y;
            acc4[2] += sv * w0.z; acc4[3] += sv * w0.w;
        }
        float4 o0;
        o0.x = fmaxf(acc4[0], 0.0f); o0.y = fmaxf(acc4[1], 0.0f);
        o0.z = fmaxf(acc4[2], 0.0f); o0.w = fmaxf(acc4[3], 0.0f);
        *(float4*)&u[(size_t)p * 2048 + s * 64 + e0] = o0;
    }
}

// ---------------------------------------------------------------------------
// K2: full-MFMA attention block + LN(64) + fused XL double-LN (unchanged)
// ---------------------------------------------------------------------------
__global__ __launch_bounds__(256, 2) void k_attn(
    const float* __restrict__ u,
    const float* __restrict__ wq, const float* __restrict__ bq,
    const float* __restrict__ wk, const float* __restrict__ bk,
    const float* __restrict__ wv, const float* __restrict__ bv,
    const float* __restrict__ wo, const float* __restrict__ bo,
    const float* __restrict__ g1, const float* __restrict__ b1,
    const float* __restrict__ xg, const float* __restrict__ xb,
    unsigned short* __restrict__ Ah, unsigned short* __restrict__ Al)
{
    __shared__ __align__(16) unsigned short s_w[2][64 * 64];
    __shared__ __align__(16) float s_uf[32 * 68];
    __shared__ __align__(16) unsigned short R1[12288];
    __shared__ __align__(16) unsigned short R2[5632];
    __shared__ float s_red[2][32][2];
    __shared__ float s_red2[2][4][2];

    unsigned short* qA_h = R1;
    unsigned short* qA_l = R1 + 3072;
    unsigned short* kB_h = R1 + 6144;
    unsigned short* kB_l = R1 + 9216;
    unsigned short* p_h  = R1;
    unsigned short* p_l  = R1 + 5120;
    unsigned short* vT_h = R2;
    unsigned short* vT_l = R2 + 2560;
    unsigned short* oA_h = R2;
    unsigned short* oA_l = R2 + 2816;

    const int g   = blockIdx.x;
    const int m   = g >> 8;
    const int b2  = g & 255;
    const int tid = threadIdx.x;
    const int l   = tid & 63;
    const int w   = tid >> 6;
    const int l15 = l & 15;
    const int lg  = l >> 4;

    {
        const int s = tid >> 3, dq = (tid & 7) * 8;
        const float* up = u + (size_t)g * 2048 + s * 64 + dq;
        *(float4*)&s_uf[s * 68 + dq]     = *(const float4*)up;
        *(float4*)&s_uf[s * 68 + dq + 4] = *(const float4*)(up + 4);
    }

    const int wn  = tid & 63;
    const int wkq = tid >> 6;
    float wreg[16];

    #define LOADQKV(SRC)                                                          \
        {                                                                         \
            const float* sp = (SRC) + (size_t)m * 4096 + (wn >> 4) * 1024 + (wn & 15); \
            _Pragma("unroll")                                                     \
            for (int j = 0; j < 16; ++j) wreg[j] = sp[(wkq * 16 + j) * 16];       \
        }
    #define LOADO(SRC)                                                            \
        {                                                                         \
            const float* sp = (SRC) + (size_t)m * 4096 + wn;                      \
            _Pragma("unroll")                                                     \
            for (int j = 0; j < 16; ++j) wreg[j] = sp[(wkq * 16 + j) * 64];       \
        }
    #define WRITEW()                                                              \
        {                                                                         \
            _Pragma("unroll")                                                     \
            for (int j2 = 0; j2 < 8; ++j2) {                                      \
                const int d = wkq * 16 + j2 * 2;                                  \
                const float v0 = wreg[j2 * 2], v1 = wreg[j2 * 2 + 1];             \
                const unsigned short h0 = f2bf(v0), h1 = f2bf(v1);                \
                const unsigned short q0 = f2bf(v0 - bf2f(h0));                    \
                const unsigned short q1 = f2bf(v1 - bf2f(h1));                    \
                const int idx = wn * 64 + (((d >> 3) ^ (wn & 7)) << 3) + (d & 7); \
                *(unsigned*)&s_w[0][idx] = (unsigned)h0 | ((unsigned)h1 << 16);   \
                *(unsigned*)&s_w[1][idx] = (unsigned)q0 | ((unsigned)q1 << 16);   \
            }                                                                     \
        }

    LOADQKV(wq);
    __syncthreads();
    WRITEW();

    short8v uh[2][2], ul[2][2];
    #pragma unroll
    for (int mf = 0; mf < 2; ++mf)
        #pragma unroll
        for (int ks = 0; ks < 2; ++ks) {
            const float* pb = &s_uf[(mf * 16 + l15) * 68 + (ks * 4 + lg) * 8];
            float xv[8];
            *(float4*)&xv[0] = *(const float4*)pb;
            *(float4*)&xv[4] = *(const float4*)(pb + 4);
            short8v hh, ll;
            #pragma unroll
            for (int j = 0; j < 8; ++j) {
                const unsigned short h = f2bf(xv[j]);
                hh[j] = (short)h;
                ll[j] = (short)f2bf(xv[j] - bf2f(h));
            }
            uh[mf][ks] = hh; ul[mf][ks] = ll;
        }
    __syncthreads();

    #define PROJ(BIAS, MODE)                                                      \
        {                                                                         \
            short8v wbh[2], wbl[2];                                               \
            const int bn = w * 16 + l15;                                          \
            _Pragma("unroll")                                                     \
            for (int ks = 0; ks < 2; ++ks) {                                      \
                const int off = bn * 64 + (((ks * 4 + lg) ^ (bn & 7)) << 3);      \
                wbh[ks] = *(const short8v*)&s_w[0][off];                          \
                wbl[ks] = *(const short8v*)&s_w[1][off];                          \
            }                                                                     \
            const float bias_v = (BIAS)[m * 64 + bn];                             \
            f32x4 a0 = {0,0,0,0}, a1 = {0,0,0,0};                                 \
            _Pragma("unroll")                                                     \
            for (int ks = 0; ks < 2; ++ks) {                                      \
                MFMA3(a0, uh[0][ks], ul[0][ks], wbh[ks], wbl[ks]);                \
                MFMA3(a1, uh[1][ks], ul[1][ks], wbh[ks], wbl[ks]);                \
            }                                                                     \
            _Pragma("unroll")                                                     \
            for (int mf = 0; mf < 2; ++mf) {                                      \
                const f32x4 av = mf ? a1 : a0;                                    \
                _Pragma("unroll")                                                 \
                for (int r = 0; r < 4; ++r) {                                     \
                    const float val = av[r] + bias_v;                             \
                    const unsigned short hh = f2bf(val);                          \
                    const unsigned short lo = f2bf(val - bf2f(hh));               \
                    const int srow = mf * 16 + lg * 4 + r;                        \
                    if ((MODE) == 0) { const int ix = w * 768 + srow * 24 + l15;  \
                        qA_h[ix] = hh; qA_l[ix] = lo; }                           \
                    else if ((MODE) == 1) { const int ix = w * 768 + srow * 24 + l15; \
                        kB_h[ix] = hh; kB_l[ix] = lo; }                           \
                    else { const int ix = w * 640 + l15 * 40 + srow;              \
                        vT_h[ix] = hh; vT_l[ix] = lo; }                           \
                }                                                                 \
            }                                                                     \
        }

    PROJ(bq, 0);
    LOADQKV(wk);
    __syncthreads();
    WRITEW();
    __syncthreads();

    PROJ(bk, 1);
    LOADQKV(wv);
    __syncthreads();
    WRITEW();
    __syncthreads();

    PROJ(bv, 2);
    LOADO(wo);
    __syncthreads();
    WRITEW();
    __syncthreads();

    float pvreg[2][2][4];
    {
        const short8v zz = {0,0,0,0,0,0,0,0};
        short8v qh[2], ql[2], kh[2], kl[2];
        const bool kreal = (lg < 2);
        #pragma unroll
        for (int mf = 0; mf < 2; ++mf) {
            if (kreal) {
                const int ia = w * 768 + (mf * 16 + l15) * 24 + lg * 8;
                qh[mf] = *(const short8v*)&qA_h[ia];
                ql[mf] = *(const short8v*)&qA_l[ia];
                kh[mf] = *(const short8v*)&kB_h[ia];
                kl[mf] = *(const short8v*)&kB_l[ia];
            } else { qh[mf] = zz; ql[mf] = zz; kh[mf] = zz; kl[mf] = zz; }
        }
        f32x4 sc[2][2];
        #pragma unroll
        for (int mf = 0; mf < 2; ++mf)
            #pragma unroll
            for (int nf = 0; nf < 2; ++nf) {
                sc[mf][nf] = (f32x4){0,0,0,0};
                MFMA3(sc[mf][nf], qh[mf], ql[mf], kh[nf], kl[nf]);
            }
        #pragma unroll
        for (int mf = 0; mf < 2; ++mf)
            #pragma unroll
            for (int r = 0; r < 4; ++r) {
                const float v0 = sc[mf][0][r] * 0.25f;
                const float v1 = sc[mf][1][r] * 0.25f;
                float mx = fmaxf(v0, v1);
                mx = fmaxf(mx, __shfl_xor(mx, 1));
                mx = fmaxf(mx, __shfl_xor(mx, 2));
                mx = fmaxf(mx, __shfl_xor(mx, 4));
                mx = fmaxf(mx, __shfl_xor(mx, 8));
                const float e0 = expf(v0 - mx), e1 = expf(v1 - mx);
                float sm = e0 + e1;
                sm += __shfl_xor(sm, 1);
                sm += __shfl_xor(sm, 2);
                sm += __shfl_xor(sm, 4);
                sm += __shfl_xor(sm, 8);
                const float inv = 1.0f / sm;
                pvreg[mf][0][r] = e0 * inv;
                pvreg[mf][1][r] = e1 * inv;
            }
    }
    __syncthreads();

    #pragma unroll
    for (int mf = 0; mf < 2; ++mf)
        #pragma unroll
        for (int nf = 0; nf < 2; ++nf)
            #pragma unroll
            for (int r = 0; r < 4; ++r) {
                const int srow = mf * 16 + lg * 4 + r;
                const int tt = nf * 16 + l15;
                const int ix = w * 1280 + srow * 40 + tt;
                const float val = pvreg[mf][nf][r];
                const unsigned short hh = f2bf(val);
                p_h[ix] = hh;
                p_l[ix] = f2bf(val - bf2f(hh));
            }
    __syncthreads();

    f32x4 ov[2];
    {
        short8v ph[2], pl[2], vh_, vl_;
        #pragma unroll
        for (int mf = 0; mf < 2; ++mf) {
            const int ix = w * 1280 + (mf * 16 + l15) * 40 + lg * 8;
            ph[mf] = *(const short8v*)&p_h[ix];
            pl[mf] = *(const short8v*)&p_l[ix];
        }
        const int iv = w * 640 + l15 * 40 + lg * 8;
        vh_ = *(const short8v*)&vT_h[iv];
        vl_ = *(const short8v*)&vT_l[iv];
        #pragma unroll
        for (int mf = 0; mf < 2; ++mf) {
            ov[mf] = (f32x4){0,0,0,0};
            MFMA3(ov[mf], ph[mf], pl[mf], vh_, vl_);
        }
    }
    __syncthreads();

    #pragma unroll
    for (int mf = 0; mf < 2; ++mf)
        #pragma unroll
        for (int r = 0; r < 4; ++r) {
            const int srow = mf * 16 + lg * 4 + r;
            const int dd = w * 16 + l15;
            const int ix = srow * 88 + dd;
            const float val = ov[mf][r];
            const unsigned short hh = f2bf(val);
            oA_h[ix] = hh;
            oA_l[ix] = f2bf(val - bf2f(hh));
        }
    __syncthreads();

    const int mfA = w >> 1;
    const int nfb = (w & 1) * 2;
    float x[2][4];
    {
        short8v oh[2], ol[2];
        #pragma unroll
        for (int ks = 0; ks < 2; ++ks) {
            const int ix = (mfA * 16 + l15) * 88 + (ks * 4 + lg) * 8;
            oh[ks] = *(const short8v*)&oA_h[ix];
            ol[ks] = *(const short8v*)&oA_l[ix];
        }
        #pragma unroll
        for (int nfi = 0; nfi < 2; ++nfi) {
            const int n = (nfb + nfi) * 16 + l15;
            f32x4 xe = {0,0,0,0};
            #pragma unroll
            for (int ks = 0; ks < 2; ++ks) {
                const int off = n * 64 + (((ks * 4 + lg) ^ (n & 7)) << 3);
                const short8v wbh = *(const short8v*)&s_w[0][off];
                const short8v wbl = *(const short8v*)&s_w[1][off];
                MFMA3(xe, oh[ks], ol[ks], wbh, wbl);
            }
            const int e = n;
            const float bo_v = bo[m * 64 + e];
            #pragma unroll
            for (int r = 0; r < 4; ++r) {
                const int srow = mfA * 16 + lg * 4 + r;
                x[nfi][r] = xe[r] + bo_v + s_uf[srow * 68 + e];
            }
        }
    }
    #pragma unroll
    for (int r = 0; r < 4; ++r) {
        float s1 = x[0][r] + x[1][r];
        float s2 = x[0][r] * x[0][r] + x[1][r] * x[1][r];
        s1 += __shfl_xor(s1, 1); s2 += __shfl_xor(s2, 1);
        s1 += __shfl_xor(s1, 2); s2 += __shfl_xor(s2, 2);
        s1 += __shfl_xor(s1, 4); s2 += __shfl_xor(s2, 4);
        s1 += __shfl_xor(s1, 8); s2 += __shfl_xor(s2, 8);
        if (l15 == 0) {
            const int srow = mfA * 16 + lg * 4 + r;
            s_red[w & 1][srow][0] = s1;
            s_red[w & 1][srow][1] = s2;
        }
    }
    __syncthreads();

    float q2[2][4];
    #pragma unroll
    for (int r = 0; r < 4; ++r) {
        const int srow = mfA * 16 + lg * 4 + r;
        const float sum = s_red[0][srow][0] + s_red[1][srow][0];
        const float ssq = s_red[0][srow][1] + s_red[1][srow][1];
        const float mean = sum * (1.0f / 64.0f);
        const float var = fmaxf(ssq * (1.0f / 64.0f) - mean * mean, 0.0f);
        const float inv = rsqrtf(var + LN_EPS);
        #pragma unroll
        for (int nfi = 0; nfi < 2; ++nfi) {
            const int e = (nfb + nfi) * 16 + l15;
            const float y = (x[nfi][r] - mean) * inv * g1[e] + b1[e];
            q2[nfi][r] = 2.0f * y;
        }
    }

    #pragma unroll
    for (int L = 0; L < 2; ++L) {
        float ls = 0.0f, lq = 0.0f;
        #pragma unroll
        for (int nfi = 0; nfi < 2; ++nfi)
            #pragma unroll
            for (int r = 0; r < 4; ++r) { ls += q2[nfi][r]; lq += q2[nfi][r] * q2[nfi][r]; }
        ls += __shfl_xor(ls, 1);  lq += __shfl_xor(lq, 1);
        ls += __shfl_xor(ls, 2);  lq += __shfl_xor(lq, 2);
        ls += __shfl_xor(ls, 4);  lq += __shfl_xor(lq, 4);
        ls += __shfl_xor(ls, 8);  lq += __shfl_xor(lq, 8);
        ls += __shfl_xor(ls, 16); lq += __shfl_xor(lq, 16);
        ls += __shfl_xor(ls, 32); lq += __shfl_xor(lq, 32);
        if (l == 0) { s_red2[L][w][0] = ls; s_red2[L][w][1] = lq; }
        __syncthreads();
        const float sum = s_red2[L][0][0] + s_red2[L][1][0] + s_red2[L][2][0] + s_red2[L][3][0];
        const float ssq = s_red2[L][0][1] + s_red2[L][1][1] + s_red2[L][2][1] + s_red2[L][3][1];
        const float mean = sum * (1.0f / 2048.0f);
        const float var = fmaxf(ssq * (1.0f / 2048.0f) - mean * mean, 0.0f);
        const float inv = rsqrtf(var + LN_EPS);
        #pragma unroll
        for (int nfi = 0; nfi < 2; ++nfi)
            #pragma unroll
            for (int r = 0; r < 4; ++r) {
                const int srow = mfA * 16 + lg * 4 + r;
                const int e = (nfb + nfi) * 16 + l15;
                const int col = srow * 64 + e;
                const float z = (q2[nfi][r] - mean) * inv * xg[L * 2048 + col] + xb[L * 2048 + col];
                q2[nfi][r] = (L == 0) ? 2.0f * z : z;
            }
    }

    #pragma unroll
    for (int nfi = 0; nfi < 2; ++nfi)
        #pragma unroll
        for (int r = 0; r < 4; ++r) {
            const int srow = mfA * 16 + lg * 4 + r;
            const int e = (nfb + nfi) * 16 + l15;
            const int col = srow * 64 + e;
            const float val = q2[nfi][r];
            const unsigned short hh = f2bf(val);
            const size_t addr = ((size_t)(m * 64 + (col >> 5)) * 256 + b2) * 32 + (col & 31);
            Ah[addr] = hh;
            Al[addr] = f2bf(val - bf2f(hh));
        }
}

// ---------------------------------------------------------------------------
// K4: fl1 MFMA GEMM, 3-term bf16 hi/lo split (unchanged)
// ---------------------------------------------------------------------------
__global__ __launch_bounds__(512) void k_fl1(
    const unsigned short* __restrict__ Ah,
    const unsigned short* __restrict__ Al,
    const float* __restrict__ W,
    float* __restrict__ part)
{
    __shared__ __align__(16) unsigned short s_wh[128 * 64];
    __shared__ __align__(16) unsigned short s_wl[128 * 64];

    const int nb  = blockIdx.x;
    const int kb  = blockIdx.y;
    const int tid = threadIdx.x;
    const int lane = tid & 63;
    const int wid  = tid >> 6;
    const int wm = wid >> 1;
    const int wn = wid & 1;

    const int sn = tid & 127;
    const int sq = tid >> 7;
    const int k0 = kb * 512;

    f32x4 acc[4][4];
    #pragma unroll
    for (int i = 0; i < 4; ++i)
        #pragma unroll
        for (int j = 0; j < 4; ++j)
            acc[i][j] = (f32x4){0.0f, 0.0f, 0.0f, 0.0f};

    float wreg[16];
    {
        const float* wp = W + (size_t)(k0 + sq * 16) * 512 + nb * 128 + sn;
        #pragma unroll
        for (int j = 0; j < 16; ++j) wreg[j] = wp[(size_t)j * 512];
    }

    const int hsn = sn & 7;
    const int wbase = sn * 64;
    const int wo0 = (((sq * 2) ^ hsn) << 3);
    const int wo1 = (((sq * 2 + 1) ^ hsn) << 3);

    for (int tt = 0; tt < 8; ++tt) {
        __syncthreads();
        {
            short8v h0, h1, l0, l1;
            #pragma unroll
            for (int j = 0; j < 8; ++j) {
                const unsigned short ha = f2bf(wreg[j]);
                const unsigned short hb = f2bf(wreg[j + 8]);
                h0[j] = (short)ha;
                h1[j] = (short)hb;
                l0[j] = (short)f2bf(wreg[j] - bf2f(ha));
                l1[j] = (short)f2bf(wreg[j + 8] - bf2f(hb));
            }
            *(short8v*)&s_wh[wbase + wo0] = h0;
            *(short8v*)&s_wh[wbase + wo1] = h1;
            *(short8v*)&s_wl[wbase + wo0] = l0;
            *(short8v*)&s_wl[wbase + wo1] = l1;
        }
        if (tt < 7) {
            const float* wp = W + (size_t)(k0 + (tt + 1) * 64 + sq * 16) * 512 + nb * 128 + sn;
            #pragma unroll
            for (int j = 0; j < 16; ++j) wreg[j] = wp[(size_t)j * 512];
        }
        __syncthreads();

        #pragma unroll
        for (int ks = 0; ks < 2; ++ks) {
            const int ktile = (k0 >> 5) + tt * 2 + ks;
            const size_t abase = ((size_t)ktile * 256 + wm * 64 + (lane & 15)) * 32
                               + (lane >> 4) * 8;
            short8v ahf[4], alf[4];
            #pragma unroll
            for (int mf = 0; mf < 4; ++mf) {
                ahf[mf] = *(const short8v*)&Ah[abase + (size_t)mf * 512];
                alf[mf] = *(const short8v*)&Al[abase + (size_t)mf * 512];
            }
            short8v bhf[4], blf[4];
            #pragma unroll
            for (int nf = 0; nf < 4; ++nf) {
                const int n = wn * 64 + nf * 16 + (lane & 15);
                const int q = ks * 4 + (lane >> 4);
                const int baddr = n * 64 + ((q ^ (n & 7)) << 3);
                bhf[nf] = *(const short8v*)&s_wh[baddr];
                blf[nf] = *(const short8v*)&s_wl[baddr];
            }
            #pragma unroll
            for (int mf = 0; mf < 4; ++mf)
                #pragma unroll
                for (int nf = 0; nf < 4; ++nf) {
                    MFMA3(acc[mf][nf], ahf[mf], alf[mf], bhf[nf], blf[nf]);
                }
        }
    }

    float* pp = part + (size_t)kb * 131072 + (size_t)nb * 128;
    const int r0 = (lane >> 4) * 4;
    const int c  = lane & 15;
    #pragma unroll
    for (int mf = 0; mf < 4; ++mf) {
        const int row = wm * 64 + mf * 16 + r0;
        #pragma unroll
        for (int nf = 0; nf < 4; ++nf) {
            const int col = wn * 64 + nf * 16 + c;
            #pragma unroll
            for (int r = 0; r < 4; ++r)
                pp[(size_t)(row + r) * 512 + col] = acc[mf][nf][r];
        }
    }
}

__global__ __launch_bounds__(256) void k_fl1red(
    const float* __restrict__ part, const float* __restrict__ bias,
    float* __restrict__ out1)
{
    const int i4 = (blockIdx.x * 256 + threadIdx.x) * 4;
    float4 s = *(const float4*)&bias[i4 & 511];
    for (int ks = 0; ks < 64; ++ks) {
        const float4 p = *(const float4*)&part[(size_t)ks * 131072 + i4];
        s.x += p.x; s.y += p.y; s.z += p.z; s.w += p.w;
    }
    s.x = fmaxf(s.x, 0.0f); s.y = fmaxf(s.y, 0.0f);
    s.z = fmaxf(s.z, 0.0f); s.w = fmaxf(s.w, 0.0f);
    *(float4*)&out1[i4] = s;
}

__global__ __launch_bounds__(128) void k_fl2(
    const float* __restrict__ u1, const float* __restrict__ w,
    const float* __restrict__ b, float* __restrict__ out2)
{
    __shared__ float s_u[512];
    const int r = blockIdx.x, tid = threadIdx.x;
    for (int i = tid; i < 512; i += 128) s_u[i] = u1[r * 512 + i];
    __syncthreads();
    float acc = b[tid];
    for (int k = 0; k < 512; k++) acc += s_u[k] * w[k * 128 + tid];
    out2[r * 128 + tid] = fmaxf(acc, 0.0f);
}

__global__ __launch_bounds__(128) void k_fl3(
    const float* __restrict__ u2_, const float* __restrict__ w,
    const float* __restrict__ b, float* __restrict__ out)
{
    __shared__ float s_u[128];
    const int r = blockIdx.x, tid = threadIdx.x;
    s_u[tid] = u2_[r * 128 + tid];
    __syncthreads();
    if (tid < 25) {
        float acc = b[tid];
        for (int k = 0; k < 128; k++) acc += s_u[k] * w[k * 25 + tid];
        out[r * 25 + tid] = acc;
    }
}

// ---------------------------------------------------------------------------
extern "C" void kernel_launch(void* const* d_in, const int* in_sizes, int n_in,
                              void* d_out, int out_size, void* d_ws, size_t ws_size,
                              hipStream_t stream)
{
    const float* t      = (const float*)d_in[0];
    const float* c1w    = (const float*)d_in[1];
    const float* c1b    = (const float*)d_in[2];
    const float* c2w    = (const float*)d_in[3];
    const float* c2b    = (const float*)d_in[4];
    const float* ew     = (const float*)d_in[5];
    const float* eb     = (const float*)d_in[6];
    const float* mh_wq  = (const float*)d_in[7];
    const float* mh_bq  = (const float*)d_in[8];
    const float* mh_wk  = (const float*)d_in[9];
    const float* mh_bk  = (const float*)d_in[10];
    const float* mh_wv  = (const float*)d_in[11];
    const float* mh_bv  = (const float*)d_in[12];
    const float* mh_wo  = (const float*)d_in[13];
    const float* mh_bo  = (const float*)d_in[14];
    const float* ln1_g  = (const float*)d_in[15];
    const float* ln1_b  = (const float*)d_in[16];
    // d_in[17..24]: XL attention weights -- dead code in the reference, unused
    const float* xln_g  = (const float*)d_in[25];
    const float* xln_b  = (const float*)d_in[26];
    const float* fl1_w  = (const float*)d_in[27];
    const float* fl1_b  = (const float*)d_in[28];
    const float* fl2_w  = (const float*)d_in[29];
    const float* fl2_b  = (const float*)d_in[30];
    const float* fl3_w  = (const float*)d_in[31];
    const float* fl3_b  = (const float*)d_in[32];
    (void)in_sizes; (void)n_in; (void)out_size; (void)ws_size;

    float* U   = (float*)d_ws;                 // conv u (f32); later PART, OUT2
    float* U2  = U + 8388608;                  // Ah/Al; later OUT1
    unsigned short* Ah = (unsigned short*)U2;
    unsigned short* Al = Ah + 8388608;
    float* PART = U;                           // u dead after k_attn
    float* OUT1 = U2;                          // Ah/Al dead after k_fl1
    float* OUT2 = U;                           // PART dead after k_fl1red
    float* out  = (float*)d_out;

    k_conv<<<4096, 512, 0, stream>>>(t, c1w, c1b, c2w, c2b, ew, eb, U);
    k_attn<<<4096, 256, 0, stream>>>(U, mh_wq, mh_bq, mh_wk, mh_bk, mh_wv, mh_bv,
                                     mh_wo, mh_bo, ln1_g, ln1_b, xln_g, xln_b,
                                     Ah, Al);
    k_fl1<<<dim3(4, 64), 512, 0, stream>>>(Ah, Al, fl1_w, PART);
    k_fl1red<<<128, 256, 0, stream>>>(PART, fl1_b, OUT1);
    k_fl2<<<256, 128, 0, stream>>>(OUT1, fl2_w, fl2_b, OUT2);
    k_fl3<<<256, 128, 0, stream>>>(OUT2, fl3_w, fl3_b, out);
}